// Round 2
// baseline (14791.168 us; speedup 1.0000x reference)
//
#include <hip/hip_runtime.h>

#define NNODES 50000
#define NEDGES 800000
#define NGRAPHS 32
#define NSPEC 10
#define CC 32
#define RH 64
#define NB 8

#define EBLK 128

// ---------------- species: recover species id from one-hot attrs ----------------
__global__ __launch_bounds__(256) void species_kernel(const float* __restrict__ attrs,
                                                      int* __restrict__ species) {
    int n = blockIdx.x * 256 + threadIdx.x;
    if (n >= NNODES) return;
    float acc = 0.f;
#pragma unroll
    for (int s = 0; s < NSPEC; ++s) acc += attrs[n * NSPEC + s] * (float)s;
    species[n] = (int)(acc + 0.5f);
}

// ---------------- CSR build: histogram -> scan -> scatter ----------------
__global__ __launch_bounds__(256) void hist_kernel(const int* __restrict__ eidx,
                                                   int* __restrict__ counts) {
    int e = blockIdx.x * 256 + threadIdx.x;
    if (e >= NEDGES) return;
    atomicAdd(&counts[eidx[NEDGES + e]], 1);
}

__global__ __launch_bounds__(1024) void scan_kernel(const int* __restrict__ counts,
                                                    int* __restrict__ offsets) {
    __shared__ int sums[1024];
    const int t = threadIdx.x;
    const int CH = (NNODES + 1023) / 1024;  // 49
    const int base = t * CH;
    int s = 0;
    for (int i = 0; i < CH; ++i) {
        int idx = base + i;
        if (idx < NNODES) s += counts[idx];
    }
    sums[t] = s;
    __syncthreads();
    for (int off = 1; off < 1024; off <<= 1) {
        int add = (t >= off) ? sums[t - off] : 0;
        __syncthreads();
        sums[t] += add;
        __syncthreads();
    }
    int run = sums[t] - s;  // exclusive prefix for this thread's chunk
    for (int i = 0; i < CH; ++i) {
        int idx = base + i;
        if (idx < NNODES) { offsets[idx] = run; run += counts[idx]; }
    }
}

__global__ __launch_bounds__(256) void scatter_kernel(const int* __restrict__ eidx,
                                                      const int* __restrict__ offsets,
                                                      int* __restrict__ cursor,
                                                      int* __restrict__ perm) {
    int e = blockIdx.x * 256 + threadIdx.x;
    if (e >= NEDGES) return;
    int rcv = eidx[NEDGES + e];
    int pos = atomicAdd(&cursor[rcv], 1);
    perm[offsets[rcv] + pos] = e;
}

// ---------------- edge kernel: receiver-sorted; geometry + MLP + SH + scatter ----------------
__global__ __launch_bounds__(EBLK) void edge_kernel(
    const float* __restrict__ pos, const float* __restrict__ shifts,
    const int* __restrict__ eidx, const int* __restrict__ perm,
    const float* __restrict__ rW1, const float* __restrict__ rb1,
    const float* __restrict__ rW2, const float* __restrict__ rb2,
    const float* __restrict__ rW3,
    const int* __restrict__ species, const float* __restrict__ Wemb,
    float* __restrict__ A) {
    __shared__ float act[RH * EBLK];  // per-thread private columns: act[k*EBLK+tid]
    const int tid = threadIdx.x;
    const int slot = blockIdx.x * EBLK + tid;
    const int e = perm[slot];

    const int snd = eidx[e];
    const int rcv = eidx[NEDGES + e];

    const float vx = pos[rcv * 3 + 0] - pos[snd * 3 + 0] + shifts[e * 3 + 0];
    const float vy = pos[rcv * 3 + 1] - pos[snd * 3 + 1] + shifts[e * 3 + 1];
    const float vz = pos[rcv * 3 + 2] - pos[snd * 3 + 2] + shifts[e * 3 + 2];
    const float r = sqrtf(vx * vx + vy * vy + vz * vz);
    const float safe_r = fmaxf(r, 1e-9f);
    const float rinv = 1.f / safe_r;
    const float ux = vx * rinv, uy = vy * rinv, uz = vz * rinv;

    // radial basis: sqrt(2/5)*sin(n*pi*r/5)/r * fcut(u)
    const float u = r * 0.2f;
    const float u2 = u * u;
    const float u6 = u2 * u2 * u2;
    const float u7 = u6 * u;
    const float u8 = u7 * u;
    float fcut = 1.f - 28.f * u6 + 48.f * u7 - 21.f * u8;
    fcut = (u < 1.f) ? fcut : 0.f;
    const float pref = 0.632455532f * rinv * fcut;
    float rb[NB];
#pragma unroll
    for (int k = 0; k < NB; ++k) {
        const float fk = (float)(k + 1) * 0.628318530718f;  // n*pi/RMAX
        rb[k] = __sinf(fk * safe_r) * pref;
    }

    // ---- layer 1: h1 = silu(rb @ rW1 + rb1), rW1 uniform -> s_load
    {
        float h1[RH];
#pragma unroll
        for (int j = 0; j < RH; ++j) h1[j] = rb1[j];
#pragma unroll
        for (int k = 0; k < NB; ++k) {
            const float* w = rW1 + k * RH;
#pragma unroll
            for (int j = 0; j < RH; ++j) h1[j] = fmaf(rb[k], w[j], h1[j]);
        }
#pragma unroll
        for (int j = 0; j < RH; ++j) {
            const float x = h1[j];
            act[j * EBLK + tid] = x / (1.f + __expf(-x));
        }
    }

    // ---- layer 2: h2 = silu(h1 @ rW2 + rb2)
    {
        float h2[RH];
#pragma unroll
        for (int j = 0; j < RH; ++j) h2[j] = rb2[j];
        for (int k = 0; k < RH; ++k) {
            const float hk = act[k * EBLK + tid];
            const float* w = rW2 + k * RH;
#pragma unroll
            for (int j = 0; j < RH; ++j) h2[j] = fmaf(hk, w[j], h2[j]);
        }
#pragma unroll
        for (int j = 0; j < RH; ++j) {
            const float x = h2[j];
            act[j * EBLK + tid] = x / (1.f + __expf(-x));  // private slot, no barrier
        }
    }

    // spherical harmonics (component norm)
    float Y[9];
    {
        const float s3 = 1.7320508075688772f;
        const float s15 = 3.872983346207417f;
        const float s15h = 1.9364916731037085f;
        const float s5h = 1.118033988749895f;
        Y[0] = 1.f;
        Y[1] = s3 * ux; Y[2] = s3 * uy; Y[3] = s3 * uz;
        Y[4] = s15 * ux * uy; Y[5] = s15 * uy * uz;
        Y[6] = s5h * (3.f * uz * uz - 1.f);
        Y[7] = s15 * ux * uz;
        Y[8] = s15h * (ux * ux - uy * uy);
    }

    // ---- layer 3 (R = h2 @ rW3 -> [32][3]) + message + scatter (sorted -> L2-resident)
    float* Abase = A + (size_t)rcv * (CC * 9);
    const int sp = species[snd];
    const float* hrow = Wemb + sp * CC;  // 1.25KB table, L1-resident
    for (int cc = 0; cc < 4; ++cc) {  // 4 chunks of 8 channels
        const float4 hsA = *(const float4*)(hrow + cc * 8);
        const float4 hsB = *(const float4*)(hrow + cc * 8 + 4);
        const float hsv[8] = {hsA.x, hsA.y, hsA.z, hsA.w, hsB.x, hsB.y, hsB.z, hsB.w};
        float acc[8][3];
#pragma unroll
        for (int c = 0; c < 8; ++c)
#pragma unroll
            for (int l = 0; l < 3; ++l) acc[c][l] = 0.f;
        for (int k = 0; k < RH; ++k) {
            const float hk = act[k * EBLK + tid];
            const float* w = rW3 + k * 96 + cc * 24;  // uniform -> s_load
#pragma unroll
            for (int c = 0; c < 8; ++c) {
#pragma unroll
                for (int l = 0; l < 3; ++l) acc[c][l] = fmaf(hk, w[c * 3 + l], acc[c][l]);
            }
        }
#pragma unroll
        for (int c = 0; c < 8; ++c) {
            const float g0 = acc[c][0] * hsv[c];
            const float g1 = acc[c][1] * hsv[c];
            const float g2 = acc[c][2] * hsv[c];
            float* Ap = Abase + (cc * 8 + c) * 9;
            atomicAdd(Ap + 0, g0 * Y[0]);
            atomicAdd(Ap + 1, g1 * Y[1]);
            atomicAdd(Ap + 2, g1 * Y[2]);
            atomicAdd(Ap + 3, g1 * Y[3]);
            atomicAdd(Ap + 4, g2 * Y[4]);
            atomicAdd(Ap + 5, g2 * Y[5]);
            atomicAdd(Ap + 6, g2 * Y[6]);
            atomicAdd(Ap + 7, g2 * Y[7]);
            atomicAdd(Ap + 8, g2 * Y[8]);
        }
    }
}

// ---------------- node kernel: A -> A2 -> B -> node_e -> graph_e ----------------
__global__ __launch_bounds__(256) void node_kernel(
    const float* __restrict__ A, const float* __restrict__ Wmix,
    const float* __restrict__ wquad, const float* __restrict__ Wread,
    const float* __restrict__ attrs, const float* __restrict__ ae,
    const int* __restrict__ batch, float* __restrict__ out) {
    __shared__ float Ald[8][CC * 9];
    const int t = threadIdx.x;
    const int ln = t >> 5;   // local node 0..7
    const int d = t & 31;    // channel
    const int n = blockIdx.x * 8 + ln;

    const float* Arow = A + (size_t)n * (CC * 9);
#pragma unroll
    for (int i = 0; i < 9; ++i) Ald[ln][d + 32 * i] = Arow[d + 32 * i] * (1.f / 16.f);
    __syncthreads();

    float A2[9];
#pragma unroll
    for (int m = 0; m < 9; ++m) {
        const int l = (m == 0) ? 0 : ((m < 4) ? 1 : 2);
        float acc = 0.f;
#pragma unroll
        for (int c = 0; c < CC; ++c)
            acc = fmaf(Wmix[(l * CC + c) * CC + d], Ald[ln][c * 9 + m], acc);
        A2[m] = acc;
    }

    const float q0 = wquad[0], q1 = wquad[1], q2 = wquad[2];
    const float n0 = A2[0] * A2[0];
    const float n1 = A2[1] * A2[1] + A2[2] * A2[2] + A2[3] * A2[3];
    const float n2 = A2[4] * A2[4] + A2[5] * A2[5] + A2[6] * A2[6] + A2[7] * A2[7] + A2[8] * A2[8];
    const float B = A2[0] + n0 * q0 + n1 * q1 + n2 * q2;

    float v = B * Wread[d];
#pragma unroll
    for (int off = 16; off; off >>= 1) v += __shfl_xor(v, off, 32);

    if (d == 0) {
        float ne = v;
#pragma unroll
        for (int s = 0; s < NSPEC; ++s) ne += attrs[n * NSPEC + s] * ae[s];
        atomicAdd(&out[batch[n]], ne);
    }
}

extern "C" void kernel_launch(void* const* d_in, const int* in_sizes, int n_in,
                              void* d_out, int out_size, void* d_ws, size_t ws_size,
                              hipStream_t stream) {
    const float* attrs  = (const float*)d_in[0];
    const float* pos    = (const float*)d_in[1];
    const float* shifts = (const float*)d_in[2];
    const float* Wemb   = (const float*)d_in[3];
    const float* rW1    = (const float*)d_in[4];
    const float* rb1    = (const float*)d_in[5];
    const float* rW2    = (const float*)d_in[6];
    const float* rb2    = (const float*)d_in[7];
    const float* rW3    = (const float*)d_in[8];
    const float* Wmix   = (const float*)d_in[9];
    const float* wquad  = (const float*)d_in[10];
    const float* Wread  = (const float*)d_in[11];
    const float* ae     = (const float*)d_in[12];
    const int* eidx     = (const int*)d_in[13];
    const int* batch    = (const int*)d_in[14];
    float* out = (float*)d_out;

    // workspace layout (all 64B aligned); total 61.6 MB
    char* wsp = (char*)d_ws;
    float* A      = (float*)wsp;                 wsp += (size_t)NNODES * CC * 9 * 4;  // 57.6 MB
    int* perm     = (int*)wsp;                   wsp += (size_t)NEDGES * 4;           // 3.2 MB
    int* offsets  = (int*)wsp;                   wsp += (size_t)NNODES * 4;           // 0.2 MB
    int* counts   = (int*)wsp;                   wsp += (size_t)NNODES * 4;           // 0.2 MB
    int* cursor   = (int*)wsp;                   wsp += (size_t)NNODES * 4;           // 0.2 MB
    int* species  = (int*)wsp;                   wsp += (size_t)NNODES * 4;           // 0.2 MB

    hipMemsetAsync(A, 0, (size_t)NNODES * CC * 9 * sizeof(float), stream);
    hipMemsetAsync(counts, 0, NNODES * sizeof(int), stream);
    hipMemsetAsync(cursor, 0, NNODES * sizeof(int), stream);
    hipMemsetAsync(out, 0, NGRAPHS * sizeof(float), stream);

    species_kernel<<<(NNODES + 255) / 256, 256, 0, stream>>>(attrs, species);
    hist_kernel<<<NEDGES / 256, 256, 0, stream>>>(eidx, counts);
    scan_kernel<<<1, 1024, 0, stream>>>(counts, offsets);
    scatter_kernel<<<NEDGES / 256, 256, 0, stream>>>(eidx, offsets, cursor, perm);

    edge_kernel<<<NEDGES / EBLK, EBLK, 0, stream>>>(pos, shifts, eidx, perm,
                                                    rW1, rb1, rW2, rb2, rW3,
                                                    species, Wemb, A);
    node_kernel<<<NNODES / 8, 256, 0, stream>>>(A, Wmix, wquad, Wread, attrs, ae, batch, out);
}

// Round 3
// 1903.925 us; speedup vs baseline: 7.7688x; 7.7688x over previous
//
#include <hip/hip_runtime.h>

#define NNODES 50000
#define NEDGES 800000
#define NGRAPHS 32
#define NSPEC 10
#define CC 32
#define RH 64
#define NB 8

#define EBLK 128
#define NCHUNK (NEDGES / EBLK)

// ---------------- species: recover species id from one-hot attrs ----------------
__global__ __launch_bounds__(256) void species_kernel(const float* __restrict__ attrs,
                                                      int* __restrict__ species) {
    int n = blockIdx.x * 256 + threadIdx.x;
    if (n >= NNODES) return;
    float acc = 0.f;
#pragma unroll
    for (int s = 0; s < NSPEC; ++s) acc += attrs[n * NSPEC + s] * (float)s;
    species[n] = (int)(acc + 0.5f);
}

// ---------------- CSR build: histogram -> scan -> scatter ----------------
__global__ __launch_bounds__(256) void hist_kernel(const int* __restrict__ eidx,
                                                   int* __restrict__ counts) {
    int e = blockIdx.x * 256 + threadIdx.x;
    if (e >= NEDGES) return;
    atomicAdd(&counts[eidx[NEDGES + e]], 1);
}

__global__ __launch_bounds__(1024) void scan_kernel(const int* __restrict__ counts,
                                                    int* __restrict__ offsets) {
    __shared__ int sums[1024];
    const int t = threadIdx.x;
    const int CH = (NNODES + 1023) / 1024;  // 49
    const int base = t * CH;
    int s = 0;
    for (int i = 0; i < CH; ++i) {
        int idx = base + i;
        if (idx < NNODES) s += counts[idx];
    }
    sums[t] = s;
    __syncthreads();
    for (int off = 1; off < 1024; off <<= 1) {
        int add = (t >= off) ? sums[t - off] : 0;
        __syncthreads();
        sums[t] += add;
        __syncthreads();
    }
    int run = sums[t] - s;
    for (int i = 0; i < CH; ++i) {
        int idx = base + i;
        if (idx < NNODES) { offsets[idx] = run; run += counts[idx]; }
    }
}

__global__ __launch_bounds__(256) void scatter_kernel(const int* __restrict__ eidx,
                                                      const int* __restrict__ offsets,
                                                      int* __restrict__ cursor,
                                                      int* __restrict__ perm) {
    int e = blockIdx.x * 256 + threadIdx.x;
    if (e >= NEDGES) return;
    int rcv = eidx[NEDGES + e];
    int pos = atomicAdd(&cursor[rcv], 1);
    perm[offsets[rcv] + pos] = e;
}

// ---------------- edge kernel: phase1 MLP (thread=edge) -> LDS, phase2 segmented reduce ----------------
__global__ __launch_bounds__(EBLK) void edge_kernel(
    const float* __restrict__ pos, const float* __restrict__ shifts,
    const int* __restrict__ eidx, const int* __restrict__ perm,
    const float* __restrict__ rW1, const float* __restrict__ rb1,
    const float* __restrict__ rW2, const float* __restrict__ rb2,
    const float* __restrict__ rW3,
    const int* __restrict__ species, const float* __restrict__ Wemb,
    float* __restrict__ A) {
    __shared__ float Gt[96 * EBLK];          // Gt[s][e ^ (s&31)] : R[c][l]*h_snd[c]
    __shared__ float Yt[9 * (EBLK + 1)];     // Yt[m][e], rows padded to 129 dwords
    __shared__ unsigned short rcv_s[EBLK];

    const int tid = threadIdx.x;
    const int slot = blockIdx.x * EBLK + tid;
    const int eid = perm[slot];

    const int snd = eidx[eid];
    const int rcv = eidx[NEDGES + eid];

    const float vx = pos[rcv * 3 + 0] - pos[snd * 3 + 0] + shifts[eid * 3 + 0];
    const float vy = pos[rcv * 3 + 1] - pos[snd * 3 + 1] + shifts[eid * 3 + 1];
    const float vz = pos[rcv * 3 + 2] - pos[snd * 3 + 2] + shifts[eid * 3 + 2];
    const float r = sqrtf(vx * vx + vy * vy + vz * vz);
    const float safe_r = fmaxf(r, 1e-9f);
    const float rinv = 1.f / safe_r;
    const float ux = vx * rinv, uy = vy * rinv, uz = vz * rinv;

    // ---- spherical harmonics -> LDS (component norm)
    {
        const float s3 = 1.7320508075688772f;
        const float s15 = 3.872983346207417f;
        const float s15h = 1.9364916731037085f;
        const float s5h = 1.118033988749895f;
        Yt[0 * 129 + tid] = 1.f;
        Yt[1 * 129 + tid] = s3 * ux;
        Yt[2 * 129 + tid] = s3 * uy;
        Yt[3 * 129 + tid] = s3 * uz;
        Yt[4 * 129 + tid] = s15 * ux * uy;
        Yt[5 * 129 + tid] = s15 * uy * uz;
        Yt[6 * 129 + tid] = s5h * (3.f * uz * uz - 1.f);
        Yt[7 * 129 + tid] = s15 * ux * uz;
        Yt[8 * 129 + tid] = s15h * (ux * ux - uy * uy);
        rcv_s[tid] = (unsigned short)rcv;
    }

    // ---- radial basis
    const float u = r * 0.2f;
    const float u2 = u * u;
    const float u6 = u2 * u2 * u2;
    const float u7 = u6 * u;
    const float u8 = u7 * u;
    float fcut = 1.f - 28.f * u6 + 48.f * u7 - 21.f * u8;
    fcut = (u < 1.f) ? fcut : 0.f;
    const float pref = 0.632455532f * rinv * fcut;
    float rb[NB];
#pragma unroll
    for (int k = 0; k < NB; ++k) {
        const float fk = (float)(k + 1) * 0.628318530718f;  // n*pi/RMAX
        rb[k] = __sinf(fk * safe_r) * pref;
    }

    // ---- layer 1 (registers, fully unrolled -> static indexing)
    float h1[RH];
#pragma unroll
    for (int j = 0; j < RH; ++j) h1[j] = rb1[j];
#pragma unroll
    for (int k = 0; k < NB; ++k) {
#pragma unroll
        for (int j = 0; j < RH; ++j) h1[j] = fmaf(rb[k], rW1[k * RH + j], h1[j]);
    }
#pragma unroll
    for (int j = 0; j < RH; ++j) h1[j] = h1[j] / (1.f + __expf(-h1[j]));

    // ---- layer 2 (registers, fully unrolled)
    float h2[RH];
#pragma unroll
    for (int j = 0; j < RH; ++j) h2[j] = rb2[j];
#pragma unroll
    for (int k = 0; k < RH; ++k) {
        const float hk = h1[k];
#pragma unroll
        for (int j = 0; j < RH; ++j) h2[j] = fmaf(hk, rW2[k * RH + j], h2[j]);
    }
#pragma unroll
    for (int j = 0; j < RH; ++j) h2[j] = h2[j] / (1.f + __expf(-h2[j]));

    // ---- layer 3: G[c*3+l] = (h2 @ rW3)[c][l] * h_snd[c] -> LDS (swizzled)
    const float* hrow = Wemb + species[snd] * CC;
#pragma unroll
    for (int cc = 0; cc < 4; ++cc) {
        const float4 hsA = *(const float4*)(hrow + cc * 8);
        const float4 hsB = *(const float4*)(hrow + cc * 8 + 4);
        const float hs[8] = {hsA.x, hsA.y, hsA.z, hsA.w, hsB.x, hsB.y, hsB.z, hsB.w};
        float acc[24];
#pragma unroll
        for (int t = 0; t < 24; ++t) acc[t] = 0.f;
#pragma unroll
        for (int k = 0; k < RH; ++k) {
            const float hk = h2[k];
            const float* w = rW3 + k * 96 + cc * 24;
#pragma unroll
            for (int t = 0; t < 24; ++t) acc[t] = fmaf(hk, w[t], acc[t]);
        }
#pragma unroll
        for (int c8 = 0; c8 < 8; ++c8) {
#pragma unroll
            for (int l = 0; l < 3; ++l) {
                const int s = cc * 24 + c8 * 3 + l;
                Gt[s * EBLK + (tid ^ (s & 31))] = acc[c8 * 3 + l] * hs[c8];
            }
        }
    }

    __syncthreads();

    // ---- phase 2: segmented reduction over sorted edges; thread = (c, mg)
    const int c = tid >> 2;
    const int mg = tid & 3;
    const int m0 = mg, m1 = mg + 4;
    const bool has2 = (mg == 0);  // m=8
    const int sa = 3 * c + ((mg == 0) ? 0 : 1);
    const int sb = 3 * c + 2;
    const int sa_base = sa * EBLK, sa_x = sa & 31;
    const int sb_base = sb * EBLK, sb_x = sb & 31;

    const int first_r = rcv_s[0];
    const int last_r = rcv_s[EBLK - 1];
    float a0 = 0.f, a1 = 0.f, a2 = 0.f;
    int prev = first_r;

    for (int e2 = 0; e2 < EBLK; ++e2) {
        const int rr = rcv_s[e2];
        if (rr != prev) {  // wave-uniform branch
            float* Ap = A + (size_t)prev * (CC * 9) + c * 9;
            if (prev == first_r || prev == last_r) {
                atomicAdd(Ap + m0, a0);
                atomicAdd(Ap + m1, a1);
                if (has2) atomicAdd(Ap + 8, a2);
            } else {
                Ap[m0] = a0;
                Ap[m1] = a1;
                if (has2) Ap[8] = a2;
            }
            a0 = a1 = a2 = 0.f;
            prev = rr;
        }
        const float y0 = Yt[m0 * 129 + e2];
        const float y1 = Yt[m1 * 129 + e2];
        const float ga = Gt[sa_base + (e2 ^ sa_x)];
        const float gb = Gt[sb_base + (e2 ^ sb_x)];
        a0 = fmaf(ga, y0, a0);
        a1 = fmaf(gb, y1, a1);
        if (has2) {
            const float y2 = Yt[8 * 129 + e2];
            a2 = fmaf(gb, y2, a2);
        }
    }
    // final segment is always a (potential) boundary: atomic
    float* Ap = A + (size_t)prev * (CC * 9) + c * 9;
    atomicAdd(Ap + m0, a0);
    atomicAdd(Ap + m1, a1);
    if (has2) atomicAdd(Ap + 8, a2);
}

// ---------------- node kernel: A -> A2 -> B -> node_e -> graph_e ----------------
__global__ __launch_bounds__(256) void node_kernel(
    const float* __restrict__ A, const float* __restrict__ Wmix,
    const float* __restrict__ wquad, const float* __restrict__ Wread,
    const float* __restrict__ attrs, const float* __restrict__ ae,
    const int* __restrict__ batch, float* __restrict__ out) {
    __shared__ float Ald[8][CC * 9];
    const int t = threadIdx.x;
    const int ln = t >> 5;
    const int d = t & 31;
    const int n = blockIdx.x * 8 + ln;

    const float* Arow = A + (size_t)n * (CC * 9);
#pragma unroll
    for (int i = 0; i < 9; ++i) Ald[ln][d + 32 * i] = Arow[d + 32 * i] * (1.f / 16.f);
    __syncthreads();

    float A2[9];
#pragma unroll
    for (int m = 0; m < 9; ++m) {
        const int l = (m == 0) ? 0 : ((m < 4) ? 1 : 2);
        float acc = 0.f;
#pragma unroll
        for (int cch = 0; cch < CC; ++cch)
            acc = fmaf(Wmix[(l * CC + cch) * CC + d], Ald[ln][cch * 9 + m], acc);
        A2[m] = acc;
    }

    const float q0 = wquad[0], q1 = wquad[1], q2 = wquad[2];
    const float n0 = A2[0] * A2[0];
    const float n1 = A2[1] * A2[1] + A2[2] * A2[2] + A2[3] * A2[3];
    const float n2 = A2[4] * A2[4] + A2[5] * A2[5] + A2[6] * A2[6] + A2[7] * A2[7] + A2[8] * A2[8];
    const float B = A2[0] + n0 * q0 + n1 * q1 + n2 * q2;

    float v = B * Wread[d];
#pragma unroll
    for (int off = 16; off; off >>= 1) v += __shfl_xor(v, off, 32);

    if (d == 0) {
        float ne = v;
#pragma unroll
        for (int s = 0; s < NSPEC; ++s) ne += attrs[n * NSPEC + s] * ae[s];
        atomicAdd(&out[batch[n]], ne);
    }
}

extern "C" void kernel_launch(void* const* d_in, const int* in_sizes, int n_in,
                              void* d_out, int out_size, void* d_ws, size_t ws_size,
                              hipStream_t stream) {
    const float* attrs  = (const float*)d_in[0];
    const float* pos    = (const float*)d_in[1];
    const float* shifts = (const float*)d_in[2];
    const float* Wemb   = (const float*)d_in[3];
    const float* rW1    = (const float*)d_in[4];
    const float* rb1    = (const float*)d_in[5];
    const float* rW2    = (const float*)d_in[6];
    const float* rb2    = (const float*)d_in[7];
    const float* rW3    = (const float*)d_in[8];
    const float* Wmix   = (const float*)d_in[9];
    const float* wquad  = (const float*)d_in[10];
    const float* Wread  = (const float*)d_in[11];
    const float* ae     = (const float*)d_in[12];
    const int* eidx     = (const int*)d_in[13];
    const int* batch    = (const int*)d_in[14];
    float* out = (float*)d_out;

    // workspace layout; total ~61.6 MB (proven available)
    char* wsp = (char*)d_ws;
    float* A      = (float*)wsp;  wsp += (size_t)NNODES * CC * 9 * 4;  // 57.6 MB
    int* perm     = (int*)wsp;    wsp += (size_t)NEDGES * 4;           // 3.2 MB
    int* offsets  = (int*)wsp;    wsp += (size_t)NNODES * 4;
    int* counts   = (int*)wsp;    wsp += (size_t)NNODES * 4;
    int* cursor   = (int*)wsp;    wsp += (size_t)NNODES * 4;
    int* species  = (int*)wsp;    wsp += (size_t)NNODES * 4;

    hipMemsetAsync(A, 0, (size_t)NNODES * CC * 9 * sizeof(float), stream);
    hipMemsetAsync(counts, 0, NNODES * sizeof(int), stream);
    hipMemsetAsync(cursor, 0, NNODES * sizeof(int), stream);
    hipMemsetAsync(out, 0, NGRAPHS * sizeof(float), stream);

    species_kernel<<<(NNODES + 255) / 256, 256, 0, stream>>>(attrs, species);
    hist_kernel<<<NEDGES / 256, 256, 0, stream>>>(eidx, counts);
    scan_kernel<<<1, 1024, 0, stream>>>(counts, offsets);
    scatter_kernel<<<NEDGES / 256, 256, 0, stream>>>(eidx, offsets, cursor, perm);

    edge_kernel<<<NCHUNK, EBLK, 0, stream>>>(pos, shifts, eidx, perm,
                                             rW1, rb1, rW2, rb2, rW3,
                                             species, Wemb, A);
    node_kernel<<<NNODES / 8, 256, 0, stream>>>(A, Wmix, wquad, Wread, attrs, ae, batch, out);
}

// Round 4
// 944.448 us; speedup vs baseline: 15.6612x; 2.0159x over previous
//
#include <hip/hip_runtime.h>

#define NNODES 50000
#define NEDGES 800000
#define NGRAPHS 32
#define NSPEC 10
#define CC 32
#define RH 64
#define NB 8

#define EBLK 128
#define NCHUNK (NEDGES / EBLK)

// ---------------- species: recover species id from one-hot attrs ----------------
__global__ __launch_bounds__(256) void species_kernel(const float* __restrict__ attrs,
                                                      int* __restrict__ species) {
    int n = blockIdx.x * 256 + threadIdx.x;
    if (n >= NNODES) return;
    float acc = 0.f;
#pragma unroll
    for (int s = 0; s < NSPEC; ++s) acc += attrs[n * NSPEC + s] * (float)s;
    species[n] = (int)(acc + 0.5f);
}

// ---------------- CSR build: histogram -> scan -> scatter ----------------
__global__ __launch_bounds__(256) void hist_kernel(const int* __restrict__ eidx,
                                                   int* __restrict__ counts) {
    int e = blockIdx.x * 256 + threadIdx.x;
    if (e >= NEDGES) return;
    atomicAdd(&counts[eidx[NEDGES + e]], 1);
}

__global__ __launch_bounds__(1024) void scan_kernel(const int* __restrict__ counts,
                                                    int* __restrict__ offsets) {
    __shared__ int sums[1024];
    const int t = threadIdx.x;
    const int CH = (NNODES + 1023) / 1024;  // 49
    const int base = t * CH;
    int s = 0;
    for (int i = 0; i < CH; ++i) {
        int idx = base + i;
        if (idx < NNODES) s += counts[idx];
    }
    sums[t] = s;
    __syncthreads();
    for (int off = 1; off < 1024; off <<= 1) {
        int add = (t >= off) ? sums[t - off] : 0;
        __syncthreads();
        sums[t] += add;
        __syncthreads();
    }
    int run = sums[t] - s;
    for (int i = 0; i < CH; ++i) {
        int idx = base + i;
        if (idx < NNODES) { offsets[idx] = run; run += counts[idx]; }
    }
}

__global__ __launch_bounds__(256) void scatter_kernel(const int* __restrict__ eidx,
                                                      const int* __restrict__ offsets,
                                                      int* __restrict__ cursor,
                                                      int* __restrict__ perm) {
    int e = blockIdx.x * 256 + threadIdx.x;
    if (e >= NEDGES) return;
    int rcv = eidx[NEDGES + e];
    int pos = atomicAdd(&cursor[rcv], 1);
    perm[offsets[rcv] + pos] = e;
}

// ---------------- edge kernel ----------------
// Phase1 (thread=edge): geometry + register MLP; layer3 done in 2 channel-halves.
// Phase2 (per half): segmented reduce over the 128 sorted edges via LDS.
// LDS: Gt 48x129 fp32 (24.77KB) + Yt 9x129 (4.64KB) + rcv (0.26KB) = 29.7KB -> 5 blocks/CU.
__global__ __launch_bounds__(EBLK, 3) void edge_kernel(
    const float* __restrict__ pos, const float* __restrict__ shifts,
    const int* __restrict__ eidx, const int* __restrict__ perm,
    const float* __restrict__ rW1, const float* __restrict__ rb1,
    const float* __restrict__ rW2, const float* __restrict__ rb2,
    const float* __restrict__ rW3,
    const int* __restrict__ species, const float* __restrict__ Wemb,
    float* __restrict__ A) {
    __shared__ float Gt[48 * 129];        // Gt[s][e], row stride 129 -> bank (s+e)&31
    __shared__ float Yt[9 * 129];
    __shared__ unsigned short rcv_s[EBLK];

    const int tid = threadIdx.x;
    const int slot = blockIdx.x * EBLK + tid;
    const int eid = perm[slot];

    const int snd = eidx[eid];
    const int rcv = eidx[NEDGES + eid];

    const float vx = pos[rcv * 3 + 0] - pos[snd * 3 + 0] + shifts[eid * 3 + 0];
    const float vy = pos[rcv * 3 + 1] - pos[snd * 3 + 1] + shifts[eid * 3 + 1];
    const float vz = pos[rcv * 3 + 2] - pos[snd * 3 + 2] + shifts[eid * 3 + 2];
    const float r = sqrtf(vx * vx + vy * vy + vz * vz);
    const float safe_r = fmaxf(r, 1e-9f);
    const float rinv = 1.f / safe_r;
    const float ux = vx * rinv, uy = vy * rinv, uz = vz * rinv;

    // ---- spherical harmonics -> LDS
    {
        const float s3 = 1.7320508075688772f;
        const float s15 = 3.872983346207417f;
        const float s15h = 1.9364916731037085f;
        const float s5h = 1.118033988749895f;
        Yt[0 * 129 + tid] = 1.f;
        Yt[1 * 129 + tid] = s3 * ux;
        Yt[2 * 129 + tid] = s3 * uy;
        Yt[3 * 129 + tid] = s3 * uz;
        Yt[4 * 129 + tid] = s15 * ux * uy;
        Yt[5 * 129 + tid] = s15 * uy * uz;
        Yt[6 * 129 + tid] = s5h * (3.f * uz * uz - 1.f);
        Yt[7 * 129 + tid] = s15 * ux * uz;
        Yt[8 * 129 + tid] = s15h * (ux * ux - uy * uy);
        rcv_s[tid] = (unsigned short)rcv;
    }

    // ---- radial basis
    const float u = r * 0.2f;
    const float u2 = u * u;
    const float u6 = u2 * u2 * u2;
    const float u7 = u6 * u;
    const float u8 = u7 * u;
    float fcut = 1.f - 28.f * u6 + 48.f * u7 - 21.f * u8;
    fcut = (u < 1.f) ? fcut : 0.f;
    const float pref = 0.632455532f * rinv * fcut;
    float rb[NB];
#pragma unroll
    for (int k = 0; k < NB; ++k) {
        const float fk = (float)(k + 1) * 0.628318530718f;  // n*pi/RMAX
        rb[k] = __sinf(fk * safe_r) * pref;
    }

    // ---- layer 1 (registers)
    float h1[RH];
#pragma unroll
    for (int j = 0; j < RH; ++j) h1[j] = rb1[j];
#pragma unroll
    for (int k = 0; k < NB; ++k) {
#pragma unroll
        for (int j = 0; j < RH; ++j) h1[j] = fmaf(rb[k], rW1[k * RH + j], h1[j]);
    }
#pragma unroll
    for (int j = 0; j < RH; ++j) h1[j] = h1[j] / (1.f + __expf(-h1[j]));

    // ---- layer 2 (registers)
    float h2[RH];
#pragma unroll
    for (int j = 0; j < RH; ++j) h2[j] = rb2[j];
#pragma unroll
    for (int k = 0; k < RH; ++k) {
        const float hk = h1[k];
#pragma unroll
        for (int j = 0; j < RH; ++j) h2[j] = fmaf(hk, rW2[k * RH + j], h2[j]);
    }
#pragma unroll
    for (int j = 0; j < RH; ++j) h2[j] = h2[j] / (1.f + __expf(-h2[j]));

    const float* hrow = Wemb + species[snd] * CC;
    const int first_r = rcv_s[0];        // wave-uniform after barrier? read before sync is
    // fine: rcv_s[tid] was written by this thread's own wave only for its lane; need sync
    // before cross-lane reads -> done below (first __syncthreads covers it).

    // ==== two channel-halves: {layer3 -> Gt} then segmented reduce ====
#pragma unroll
    for (int half = 0; half < 2; ++half) {
        if (half == 1) __syncthreads();  // protect Gt overwrite (write-after-read)
#pragma unroll
        for (int cc2 = 0; cc2 < 2; ++cc2) {
            const int cc = half * 2 + cc2;  // 8-channel chunk index
            const float4 hsA = *(const float4*)(hrow + cc * 8);
            const float4 hsB = *(const float4*)(hrow + cc * 8 + 4);
            const float hs[8] = {hsA.x, hsA.y, hsA.z, hsA.w, hsB.x, hsB.y, hsB.z, hsB.w};
            float acc[24];
#pragma unroll
            for (int t = 0; t < 24; ++t) acc[t] = 0.f;
#pragma unroll
            for (int k = 0; k < RH; ++k) {
                const float hk = h2[k];
                const float* w = rW3 + k * 96 + cc * 24;
#pragma unroll
                for (int t = 0; t < 24; ++t) acc[t] = fmaf(hk, w[t], acc[t]);
            }
#pragma unroll
            for (int c8 = 0; c8 < 8; ++c8) {
#pragma unroll
                for (int l = 0; l < 3; ++l) {
                    const int s = cc2 * 24 + c8 * 3 + l;  // 0..47 within half
                    Gt[s * 129 + tid] = acc[c8 * 3 + l] * hs[c8];
                }
            }
        }
        __syncthreads();

        // ---- segmented reduce: thread = (c, j); c=tid>>3 (16 ch), j=tid&7 (m=j; j==0 also m=8)
        {
            const int c = tid >> 3;
            const int j = tid & 7;
            const int l_j = (j == 0) ? 0 : ((j < 4) ? 1 : 2);
            const int sj = (3 * c + l_j) * 129;
            const int s8 = (3 * c + 2) * 129;
            const int yj = j * 129;

            const int fr = rcv_s[0];
            const int lr = rcv_s[EBLK - 1];
            float aj = 0.f, a8 = 0.f;
            int prev = fr;

            for (int e2 = 0; e2 < EBLK; ++e2) {
                const int rr = rcv_s[e2];
                if (rr != prev) {  // wave-uniform
                    float* Ap = A + (size_t)prev * (CC * 9) + (half * 16 + c) * 9;
                    if (prev == fr || prev == lr) {
                        atomicAdd(Ap + j, aj);
                        if (j == 0) atomicAdd(Ap + 8, a8);
                    } else {
                        Ap[j] = aj;
                        if (j == 0) Ap[8] = a8;
                    }
                    aj = a8 = 0.f;
                    prev = rr;
                }
                aj = fmaf(Gt[sj + e2], Yt[yj + e2], aj);
                if (j == 0) a8 = fmaf(Gt[s8 + e2], Yt[8 * 129 + e2], a8);
            }
            float* Ap = A + (size_t)prev * (CC * 9) + (half * 16 + c) * 9;
            atomicAdd(Ap + j, aj);
            if (j == 0) atomicAdd(Ap + 8, a8);
        }
    }
}

// ---------------- node kernel: A -> A2 -> B -> node_e (plain store) ----------------
__global__ __launch_bounds__(256) void node_kernel(
    const float* __restrict__ A, const float* __restrict__ Wmix,
    const float* __restrict__ wquad, const float* __restrict__ Wread,
    const float* __restrict__ attrs, const float* __restrict__ ae,
    float* __restrict__ node_e) {
    __shared__ float Ald[8][CC * 9];
    const int t = threadIdx.x;
    const int ln = t >> 5;
    const int d = t & 31;
    const int n = blockIdx.x * 8 + ln;

    const float* Arow = A + (size_t)n * (CC * 9);
#pragma unroll
    for (int i = 0; i < 9; ++i) Ald[ln][d + 32 * i] = Arow[d + 32 * i] * (1.f / 16.f);
    __syncthreads();

    float A2[9];
#pragma unroll
    for (int m = 0; m < 9; ++m) {
        const int l = (m == 0) ? 0 : ((m < 4) ? 1 : 2);
        float acc = 0.f;
#pragma unroll
        for (int cch = 0; cch < CC; ++cch)
            acc = fmaf(Wmix[(l * CC + cch) * CC + d], Ald[ln][cch * 9 + m], acc);
        A2[m] = acc;
    }

    const float q0 = wquad[0], q1 = wquad[1], q2 = wquad[2];
    const float n0 = A2[0] * A2[0];
    const float n1 = A2[1] * A2[1] + A2[2] * A2[2] + A2[3] * A2[3];
    const float n2 = A2[4] * A2[4] + A2[5] * A2[5] + A2[6] * A2[6] + A2[7] * A2[7] + A2[8] * A2[8];
    const float B = A2[0] + n0 * q0 + n1 * q1 + n2 * q2;

    float v = B * Wread[d];
#pragma unroll
    for (int off = 16; off; off >>= 1) v += __shfl_xor(v, off, 32);

    if (d == 0) {
        float ne = v;
#pragma unroll
        for (int s = 0; s < NSPEC; ++s) ne += attrs[n * NSPEC + s] * ae[s];
        node_e[n] = ne;
    }
}

// ---------------- reduce: per-graph segment sum over sorted batch (no atomics) ----------------
__global__ __launch_bounds__(256) void reduce_kernel(const float* __restrict__ node_e,
                                                     const int* __restrict__ batch,
                                                     float* __restrict__ out) {
    __shared__ float part[4];
    const int g = blockIdx.x;
    int lo = 0, hi = NNODES;
    while (lo < hi) { int mid = (lo + hi) >> 1; if (batch[mid] < g) lo = mid + 1; else hi = mid; }
    const int start = lo;
    int lo2 = start, hi2 = NNODES;
    while (lo2 < hi2) { int mid = (lo2 + hi2) >> 1; if (batch[mid] < g + 1) lo2 = mid + 1; else hi2 = mid; }
    const int end = lo2;

    float s = 0.f;
    for (int i = start + (int)threadIdx.x; i < end; i += 256) s += node_e[i];
#pragma unroll
    for (int off = 32; off; off >>= 1) s += __shfl_xor(s, off, 64);
    if ((threadIdx.x & 63) == 0) part[threadIdx.x >> 6] = s;
    __syncthreads();
    if (threadIdx.x == 0) out[g] = part[0] + part[1] + part[2] + part[3];
}

extern "C" void kernel_launch(void* const* d_in, const int* in_sizes, int n_in,
                              void* d_out, int out_size, void* d_ws, size_t ws_size,
                              hipStream_t stream) {
    const float* attrs  = (const float*)d_in[0];
    const float* pos    = (const float*)d_in[1];
    const float* shifts = (const float*)d_in[2];
    const float* Wemb   = (const float*)d_in[3];
    const float* rW1    = (const float*)d_in[4];
    const float* rb1    = (const float*)d_in[5];
    const float* rW2    = (const float*)d_in[6];
    const float* rb2    = (const float*)d_in[7];
    const float* rW3    = (const float*)d_in[8];
    const float* Wmix   = (const float*)d_in[9];
    const float* wquad  = (const float*)d_in[10];
    const float* Wread  = (const float*)d_in[11];
    const float* ae     = (const float*)d_in[12];
    const int* eidx     = (const int*)d_in[13];
    const int* batch    = (const int*)d_in[14];
    float* out = (float*)d_out;

    // workspace layout; total ~62 MB
    char* wsp = (char*)d_ws;
    float* A      = (float*)wsp;  wsp += (size_t)NNODES * CC * 9 * 4;  // 57.6 MB
    int* perm     = (int*)wsp;    wsp += (size_t)NEDGES * 4;           // 3.2 MB
    int* offsets  = (int*)wsp;    wsp += (size_t)NNODES * 4;
    int* counts   = (int*)wsp;    wsp += (size_t)NNODES * 4;
    int* cursor   = (int*)wsp;    wsp += (size_t)NNODES * 4;
    int* species  = (int*)wsp;    wsp += (size_t)NNODES * 4;
    float* node_e = (float*)wsp;  wsp += (size_t)NNODES * 4;

    hipMemsetAsync(A, 0, (size_t)NNODES * CC * 9 * sizeof(float), stream);
    hipMemsetAsync(counts, 0, NNODES * sizeof(int), stream);
    hipMemsetAsync(cursor, 0, NNODES * sizeof(int), stream);

    species_kernel<<<(NNODES + 255) / 256, 256, 0, stream>>>(attrs, species);
    hist_kernel<<<NEDGES / 256, 256, 0, stream>>>(eidx, counts);
    scan_kernel<<<1, 1024, 0, stream>>>(counts, offsets);
    scatter_kernel<<<NEDGES / 256, 256, 0, stream>>>(eidx, offsets, cursor, perm);

    edge_kernel<<<NCHUNK, EBLK, 0, stream>>>(pos, shifts, eidx, perm,
                                             rW1, rb1, rW2, rb2, rW3,
                                             species, Wemb, A);
    node_kernel<<<NNODES / 8, 256, 0, stream>>>(A, Wmix, wquad, Wread, attrs, ae, node_e);
    reduce_kernel<<<NGRAPHS, 256, 0, stream>>>(node_e, batch, out);
}

// Round 5
// 903.271 us; speedup vs baseline: 16.3751x; 1.0456x over previous
//
#include <hip/hip_runtime.h>
#include <hip/hip_bf16.h>

#define NNODES 50000
#define NEDGES 800000
#define NGRAPHS 32
#define NSPEC 10
#define CC 32
#define RH 64
#define NB 8

#define EBLK 128
#define NCHUNK (NEDGES / EBLK)
#define GSTR 132  // Gt row stride in shorts (264B): bank=(66s+e2/2)&31, max 2-way

// ---------------- species: recover species id from one-hot attrs ----------------
__global__ __launch_bounds__(256) void species_kernel(const float* __restrict__ attrs,
                                                      int* __restrict__ species) {
    int n = blockIdx.x * 256 + threadIdx.x;
    if (n >= NNODES) return;
    float acc = 0.f;
#pragma unroll
    for (int s = 0; s < NSPEC; ++s) acc += attrs[n * NSPEC + s] * (float)s;
    species[n] = (int)(acc + 0.5f);
}

// ---------------- CSR build: histogram -> scan -> scatter ----------------
__global__ __launch_bounds__(256) void hist_kernel(const int* __restrict__ eidx,
                                                   int* __restrict__ counts) {
    int e = blockIdx.x * 256 + threadIdx.x;
    if (e >= NEDGES) return;
    atomicAdd(&counts[eidx[NEDGES + e]], 1);
}

__global__ __launch_bounds__(1024) void scan_kernel(const int* __restrict__ counts,
                                                    int* __restrict__ offsets) {
    __shared__ int sums[1024];
    const int t = threadIdx.x;
    const int CH = (NNODES + 1023) / 1024;  // 49
    const int base = t * CH;
    int s = 0;
    for (int i = 0; i < CH; ++i) {
        int idx = base + i;
        if (idx < NNODES) s += counts[idx];
    }
    sums[t] = s;
    __syncthreads();
    for (int off = 1; off < 1024; off <<= 1) {
        int add = (t >= off) ? sums[t - off] : 0;
        __syncthreads();
        sums[t] += add;
        __syncthreads();
    }
    int run = sums[t] - s;
    for (int i = 0; i < CH; ++i) {
        int idx = base + i;
        if (idx < NNODES) { offsets[idx] = run; run += counts[idx]; }
    }
}

__global__ __launch_bounds__(256) void scatter_kernel(const int* __restrict__ eidx,
                                                      const int* __restrict__ offsets,
                                                      int* __restrict__ cursor,
                                                      int* __restrict__ perm) {
    int e = blockIdx.x * 256 + threadIdx.x;
    if (e >= NEDGES) return;
    int rcv = eidx[NEDGES + e];
    int pos = atomicAdd(&cursor[rcv], 1);
    perm[offsets[rcv] + pos] = e;
}

// ---------------- edge kernel ----------------
// Phase1 (thread=edge): geometry + register MLP; layer3 in 2 channel-halves.
// Phase2 (per half): segmented reduce over 128 sorted edges via LDS.
// LDS: Gt 48x132 bf16 (12.4KB) + Yt 9x129 f32 (4.6KB) + rcv (0.26KB) = 17.3KB -> 9 blocks/CU.
__global__ __launch_bounds__(EBLK, 4) void edge_kernel(
    const float* __restrict__ pos, const float* __restrict__ shifts,
    const int* __restrict__ eidx, const int* __restrict__ perm,
    const float* __restrict__ rW1, const float* __restrict__ rb1,
    const float* __restrict__ rW2, const float* __restrict__ rb2,
    const float* __restrict__ rW3,
    const int* __restrict__ species, const float* __restrict__ Wemb,
    float* __restrict__ A) {
    __shared__ __hip_bfloat16 Gt[48 * GSTR];  // Gt[s][e], bf16
    __shared__ float Yt[9 * 129];
    __shared__ unsigned short rcv_s[EBLK];

    const int tid = threadIdx.x;
    const int slot = blockIdx.x * EBLK + tid;
    const int eid = perm[slot];

    const int snd = eidx[eid];
    const int rcv = eidx[NEDGES + eid];

    const float vx = pos[rcv * 3 + 0] - pos[snd * 3 + 0] + shifts[eid * 3 + 0];
    const float vy = pos[rcv * 3 + 1] - pos[snd * 3 + 1] + shifts[eid * 3 + 1];
    const float vz = pos[rcv * 3 + 2] - pos[snd * 3 + 2] + shifts[eid * 3 + 2];
    const float r = sqrtf(vx * vx + vy * vy + vz * vz);
    const float safe_r = fmaxf(r, 1e-9f);
    const float rinv = 1.f / safe_r;
    const float ux = vx * rinv, uy = vy * rinv, uz = vz * rinv;

    // ---- spherical harmonics -> LDS
    {
        const float s3 = 1.7320508075688772f;
        const float s15 = 3.872983346207417f;
        const float s15h = 1.9364916731037085f;
        const float s5h = 1.118033988749895f;
        Yt[0 * 129 + tid] = 1.f;
        Yt[1 * 129 + tid] = s3 * ux;
        Yt[2 * 129 + tid] = s3 * uy;
        Yt[3 * 129 + tid] = s3 * uz;
        Yt[4 * 129 + tid] = s15 * ux * uy;
        Yt[5 * 129 + tid] = s15 * uy * uz;
        Yt[6 * 129 + tid] = s5h * (3.f * uz * uz - 1.f);
        Yt[7 * 129 + tid] = s15 * ux * uz;
        Yt[8 * 129 + tid] = s15h * (ux * ux - uy * uy);
        rcv_s[tid] = (unsigned short)rcv;
    }

    // ---- radial basis
    const float u = r * 0.2f;
    const float u2 = u * u;
    const float u6 = u2 * u2 * u2;
    const float u7 = u6 * u;
    const float u8 = u7 * u;
    float fcut = 1.f - 28.f * u6 + 48.f * u7 - 21.f * u8;
    fcut = (u < 1.f) ? fcut : 0.f;
    const float pref = 0.632455532f * rinv * fcut;
    float rb[NB];
#pragma unroll
    for (int k = 0; k < NB; ++k) {
        const float fk = (float)(k + 1) * 0.628318530718f;  // n*pi/RMAX
        rb[k] = __sinf(fk * safe_r) * pref;
    }

    // ---- layer 1 (registers)
    float h1[RH];
#pragma unroll
    for (int j = 0; j < RH; ++j) h1[j] = rb1[j];
#pragma unroll
    for (int k = 0; k < NB; ++k) {
#pragma unroll
        for (int j = 0; j < RH; ++j) h1[j] = fmaf(rb[k], rW1[k * RH + j], h1[j]);
    }
#pragma unroll
    for (int j = 0; j < RH; ++j) h1[j] = h1[j] / (1.f + __expf(-h1[j]));

    // ---- layer 2 (registers)
    float h2[RH];
#pragma unroll
    for (int j = 0; j < RH; ++j) h2[j] = rb2[j];
#pragma unroll
    for (int k = 0; k < RH; ++k) {
        const float hk = h1[k];
#pragma unroll
        for (int j = 0; j < RH; ++j) h2[j] = fmaf(hk, rW2[k * RH + j], h2[j]);
    }
#pragma unroll
    for (int j = 0; j < RH; ++j) h2[j] = h2[j] / (1.f + __expf(-h2[j]));

    const float* hrow = Wemb + species[snd] * CC;

    // ==== two channel-halves: {layer3 -> Gt(bf16)} then segmented reduce ====
#pragma unroll
    for (int half = 0; half < 2; ++half) {
        if (half == 1) __syncthreads();  // protect Gt overwrite (write-after-read)
#pragma unroll
        for (int cc2 = 0; cc2 < 2; ++cc2) {
            const int cc = half * 2 + cc2;  // 8-channel chunk index
            const float4 hsA = *(const float4*)(hrow + cc * 8);
            const float4 hsB = *(const float4*)(hrow + cc * 8 + 4);
            const float hs[8] = {hsA.x, hsA.y, hsA.z, hsA.w, hsB.x, hsB.y, hsB.z, hsB.w};
            float acc[24];
#pragma unroll
            for (int t = 0; t < 24; ++t) acc[t] = 0.f;
#pragma unroll
            for (int k = 0; k < RH; ++k) {
                const float hk = h2[k];
                const float* w = rW3 + k * 96 + cc * 24;
#pragma unroll
                for (int t = 0; t < 24; ++t) acc[t] = fmaf(hk, w[t], acc[t]);
            }
#pragma unroll
            for (int c8 = 0; c8 < 8; ++c8) {
#pragma unroll
                for (int l = 0; l < 3; ++l) {
                    const int s = cc2 * 24 + c8 * 3 + l;  // 0..47 within half
                    Gt[s * GSTR + tid] = __float2bfloat16(acc[c8 * 3 + l] * hs[c8]);
                }
            }
        }
        __syncthreads();

        // ---- segmented reduce: thread = (c, j); c=tid>>3 (16 ch), j=tid&7 (m=j; j==0 also m=8)
        {
            const int c = tid >> 3;
            const int j = tid & 7;
            const int l_j = (j == 0) ? 0 : ((j < 4) ? 1 : 2);
            const int sj = (3 * c + l_j) * GSTR;
            const int s8 = (3 * c + 2) * GSTR;
            const int yj = j * 129;

            const int fr = rcv_s[0];
            const int lr = rcv_s[EBLK - 1];
            float aj = 0.f, a8 = 0.f;
            int prev = fr;

            for (int e2 = 0; e2 < EBLK; ++e2) {
                const int rr = rcv_s[e2];
                if (rr != prev) {  // wave-uniform
                    float* Ap = A + (size_t)prev * (CC * 9) + (half * 16 + c) * 9;
                    if (prev == fr || prev == lr) {
                        atomicAdd(Ap + j, aj);
                        if (j == 0) atomicAdd(Ap + 8, a8);
                    } else {
                        Ap[j] = aj;
                        if (j == 0) Ap[8] = a8;
                    }
                    aj = a8 = 0.f;
                    prev = rr;
                }
                aj = fmaf(__bfloat162float(Gt[sj + e2]), Yt[yj + e2], aj);
                if (j == 0) a8 = fmaf(__bfloat162float(Gt[s8 + e2]), Yt[8 * 129 + e2], a8);
            }
            float* Ap = A + (size_t)prev * (CC * 9) + (half * 16 + c) * 9;
            atomicAdd(Ap + j, aj);
            if (j == 0) atomicAdd(Ap + 8, a8);
        }
    }
}

// ---------------- node kernel: A -> A2 -> B -> node_e (plain store) ----------------
__global__ __launch_bounds__(256) void node_kernel(
    const float* __restrict__ A, const float* __restrict__ Wmix,
    const float* __restrict__ wquad, const float* __restrict__ Wread,
    const float* __restrict__ attrs, const float* __restrict__ ae,
    float* __restrict__ node_e) {
    __shared__ float Ald[8][CC * 9];
    const int t = threadIdx.x;
    const int ln = t >> 5;
    const int d = t & 31;
    const int n = blockIdx.x * 8 + ln;

    const float* Arow = A + (size_t)n * (CC * 9);
#pragma unroll
    for (int i = 0; i < 9; ++i) Ald[ln][d + 32 * i] = Arow[d + 32 * i] * (1.f / 16.f);
    __syncthreads();

    float A2[9];
#pragma unroll
    for (int m = 0; m < 9; ++m) {
        const int l = (m == 0) ? 0 : ((m < 4) ? 1 : 2);
        float acc = 0.f;
#pragma unroll
        for (int cch = 0; cch < CC; ++cch)
            acc = fmaf(Wmix[(l * CC + cch) * CC + d], Ald[ln][cch * 9 + m], acc);
        A2[m] = acc;
    }

    const float q0 = wquad[0], q1 = wquad[1], q2 = wquad[2];
    const float n0 = A2[0] * A2[0];
    const float n1 = A2[1] * A2[1] + A2[2] * A2[2] + A2[3] * A2[3];
    const float n2 = A2[4] * A2[4] + A2[5] * A2[5] + A2[6] * A2[6] + A2[7] * A2[7] + A2[8] * A2[8];
    const float B = A2[0] + n0 * q0 + n1 * q1 + n2 * q2;

    float v = B * Wread[d];
#pragma unroll
    for (int off = 16; off; off >>= 1) v += __shfl_xor(v, off, 32);

    if (d == 0) {
        float ne = v;
#pragma unroll
        for (int s = 0; s < NSPEC; ++s) ne += attrs[n * NSPEC + s] * ae[s];
        node_e[n] = ne;
    }
}

// ---------------- reduce: per-graph segment sum over sorted batch (no atomics) ----------------
__global__ __launch_bounds__(256) void reduce_kernel(const float* __restrict__ node_e,
                                                     const int* __restrict__ batch,
                                                     float* __restrict__ out) {
    __shared__ float part[4];
    const int g = blockIdx.x;
    int lo = 0, hi = NNODES;
    while (lo < hi) { int mid = (lo + hi) >> 1; if (batch[mid] < g) lo = mid + 1; else hi = mid; }
    const int start = lo;
    int lo2 = start, hi2 = NNODES;
    while (lo2 < hi2) { int mid = (lo2 + hi2) >> 1; if (batch[mid] < g + 1) lo2 = mid + 1; else hi2 = mid; }
    const int end = lo2;

    float s = 0.f;
    for (int i = start + (int)threadIdx.x; i < end; i += 256) s += node_e[i];
#pragma unroll
    for (int off = 32; off; off >>= 1) s += __shfl_xor(s, off, 64);
    if ((threadIdx.x & 63) == 0) part[threadIdx.x >> 6] = s;
    __syncthreads();
    if (threadIdx.x == 0) out[g] = part[0] + part[1] + part[2] + part[3];
}

extern "C" void kernel_launch(void* const* d_in, const int* in_sizes, int n_in,
                              void* d_out, int out_size, void* d_ws, size_t ws_size,
                              hipStream_t stream) {
    const float* attrs  = (const float*)d_in[0];
    const float* pos    = (const float*)d_in[1];
    const float* shifts = (const float*)d_in[2];
    const float* Wemb   = (const float*)d_in[3];
    const float* rW1    = (const float*)d_in[4];
    const float* rb1    = (const float*)d_in[5];
    const float* rW2    = (const float*)d_in[6];
    const float* rb2    = (const float*)d_in[7];
    const float* rW3    = (const float*)d_in[8];
    const float* Wmix   = (const float*)d_in[9];
    const float* wquad  = (const float*)d_in[10];
    const float* Wread  = (const float*)d_in[11];
    const float* ae     = (const float*)d_in[12];
    const int* eidx     = (const int*)d_in[13];
    const int* batch    = (const int*)d_in[14];
    float* out = (float*)d_out;

    // workspace layout; total ~62 MB
    char* wsp = (char*)d_ws;
    float* A      = (float*)wsp;  wsp += (size_t)NNODES * CC * 9 * 4;  // 57.6 MB
    int* perm     = (int*)wsp;    wsp += (size_t)NEDGES * 4;           // 3.2 MB
    int* offsets  = (int*)wsp;    wsp += (size_t)NNODES * 4;
    int* counts   = (int*)wsp;    wsp += (size_t)NNODES * 4;
    int* cursor   = (int*)wsp;    wsp += (size_t)NNODES * 4;
    int* species  = (int*)wsp;    wsp += (size_t)NNODES * 4;
    float* node_e = (float*)wsp;  wsp += (size_t)NNODES * 4;

    hipMemsetAsync(A, 0, (size_t)NNODES * CC * 9 * sizeof(float), stream);
    hipMemsetAsync(counts, 0, NNODES * sizeof(int), stream);
    hipMemsetAsync(cursor, 0, NNODES * sizeof(int), stream);

    species_kernel<<<(NNODES + 255) / 256, 256, 0, stream>>>(attrs, species);
    hist_kernel<<<NEDGES / 256, 256, 0, stream>>>(eidx, counts);
    scan_kernel<<<1, 1024, 0, stream>>>(counts, offsets);
    scatter_kernel<<<NEDGES / 256, 256, 0, stream>>>(eidx, offsets, cursor, perm);

    edge_kernel<<<NCHUNK, EBLK, 0, stream>>>(pos, shifts, eidx, perm,
                                             rW1, rb1, rW2, rb2, rW3,
                                             species, Wemb, A);
    node_kernel<<<NNODES / 8, 256, 0, stream>>>(A, Wmix, wquad, Wread, attrs, ae, node_e);
    reduce_kernel<<<NGRAPHS, 256, 0, stream>>>(node_e, batch, out);
}

// Round 6
// 717.775 us; speedup vs baseline: 20.6070x; 1.2584x over previous
//
#include <hip/hip_runtime.h>
#include <hip/hip_bf16.h>

#define NNODES 50000
#define NEDGES 800000
#define NGRAPHS 32
#define NSPEC 10
#define CC 32
#define RH 64
#define NB 8

#define EBLK 128
#define NCHUNK (NEDGES / EBLK)
#define GSTR 132  // Gt row stride in shorts (264B): bank=(66s+e2/2)&31, max 2-way

// ---------------- species: recover species id from one-hot attrs ----------------
__global__ __launch_bounds__(256) void species_kernel(const float* __restrict__ attrs,
                                                      int* __restrict__ species) {
    int n = blockIdx.x * 256 + threadIdx.x;
    if (n >= NNODES) return;
    float acc = 0.f;
#pragma unroll
    for (int s = 0; s < NSPEC; ++s) acc += attrs[n * NSPEC + s] * (float)s;
    species[n] = (int)(acc + 0.5f);
}

// ---------------- CSR build: histogram -> scan -> scatter ----------------
__global__ __launch_bounds__(256) void hist_kernel(const int* __restrict__ eidx,
                                                   int* __restrict__ counts) {
    int e = blockIdx.x * 256 + threadIdx.x;
    if (e >= NEDGES) return;
    atomicAdd(&counts[eidx[NEDGES + e]], 1);
}

__global__ __launch_bounds__(1024) void scan_kernel(const int* __restrict__ counts,
                                                    int* __restrict__ offsets) {
    __shared__ int sums[1024];
    const int t = threadIdx.x;
    const int CH = (NNODES + 1023) / 1024;  // 49
    const int base = t * CH;
    int s = 0;
    for (int i = 0; i < CH; ++i) {
        int idx = base + i;
        if (idx < NNODES) s += counts[idx];
    }
    sums[t] = s;
    __syncthreads();
    for (int off = 1; off < 1024; off <<= 1) {
        int add = (t >= off) ? sums[t - off] : 0;
        __syncthreads();
        sums[t] += add;
        __syncthreads();
    }
    int run = sums[t] - s;
    for (int i = 0; i < CH; ++i) {
        int idx = base + i;
        if (idx < NNODES) { offsets[idx] = run; run += counts[idx]; }
    }
}

__global__ __launch_bounds__(256) void scatter_kernel(const int* __restrict__ eidx,
                                                      const int* __restrict__ offsets,
                                                      int* __restrict__ cursor,
                                                      int* __restrict__ perm) {
    int e = blockIdx.x * 256 + threadIdx.x;
    if (e >= NEDGES) return;
    int rcv = eidx[NEDGES + e];
    int pos = atomicAdd(&cursor[rcv], 1);
    perm[offsets[rcv] + pos] = e;
}

// ---------------- edge kernel ----------------
// Phase1 (thread=edge): geometry + register MLP (h1/h2 bf16-packed: ~115 VGPR, no spill).
// Phase2 (per channel-half): segmented reduce over 128 sorted edges, segment list
// built once per block via ballot (no per-iter compare/branch).
__global__ __launch_bounds__(EBLK, 4) void edge_kernel(
    const float* __restrict__ pos, const float* __restrict__ shifts,
    const int* __restrict__ eidx, const int* __restrict__ perm,
    const float* __restrict__ rW1, const float* __restrict__ rb1,
    const float* __restrict__ rW2, const float* __restrict__ rb2,
    const float* __restrict__ rW3,
    const int* __restrict__ species, const float* __restrict__ Wemb,
    float* __restrict__ A) {
    __shared__ __hip_bfloat16 Gt[48 * GSTR];  // Gt[s][e], bf16
    __shared__ float Yt[9 * 129];
    __shared__ unsigned short rcv_s[EBLK];
    __shared__ int seg_start_s[EBLK + 1];
    __shared__ unsigned long long bal_s[2];

    const int tid = threadIdx.x;
    const int slot = blockIdx.x * EBLK + tid;
    const int eid = perm[slot];

    const int snd = eidx[eid];
    const int rcv = eidx[NEDGES + eid];

    const float vx = pos[rcv * 3 + 0] - pos[snd * 3 + 0] + shifts[eid * 3 + 0];
    const float vy = pos[rcv * 3 + 1] - pos[snd * 3 + 1] + shifts[eid * 3 + 1];
    const float vz = pos[rcv * 3 + 2] - pos[snd * 3 + 2] + shifts[eid * 3 + 2];
    const float r = sqrtf(vx * vx + vy * vy + vz * vz);
    const float safe_r = fmaxf(r, 1e-9f);
    const float rinv = 1.f / safe_r;
    const float ux = vx * rinv, uy = vy * rinv, uz = vz * rinv;

    // ---- spherical harmonics -> LDS
    {
        const float s3 = 1.7320508075688772f;
        const float s15 = 3.872983346207417f;
        const float s15h = 1.9364916731037085f;
        const float s5h = 1.118033988749895f;
        Yt[0 * 129 + tid] = 1.f;
        Yt[1 * 129 + tid] = s3 * ux;
        Yt[2 * 129 + tid] = s3 * uy;
        Yt[3 * 129 + tid] = s3 * uz;
        Yt[4 * 129 + tid] = s15 * ux * uy;
        Yt[5 * 129 + tid] = s15 * uy * uz;
        Yt[6 * 129 + tid] = s5h * (3.f * uz * uz - 1.f);
        Yt[7 * 129 + tid] = s15 * ux * uz;
        Yt[8 * 129 + tid] = s15h * (ux * ux - uy * uy);
        rcv_s[tid] = (unsigned short)rcv;
    }
    __syncthreads();  // rcv_s visible for neighbor reads

    // ---- build segment list once (ballot-based)
    {
        const bool head = (tid == 0) || (rcv_s[tid] != rcv_s[tid - 1]);
        const unsigned long long bal = __ballot(head);
        if ((tid & 63) == 0) bal_s[tid >> 6] = bal;
        __syncthreads();
        const int lane = tid & 63;
        const unsigned long long below =
            (lane == 0) ? 0ull : (bal & ((1ull << lane) - 1ull));
        int pre = __popcll(below) + ((tid >> 6) ? __popcll(bal_s[0]) : 0);
        if (head) seg_start_s[pre] = tid;
        if (tid == 0)
            seg_start_s[__popcll(bal_s[0]) + __popcll(bal_s[1])] = EBLK;  // sentinel
    }

    // ---- radial basis
    const float u = r * 0.2f;
    const float u2 = u * u;
    const float u6 = u2 * u2 * u2;
    const float u7 = u6 * u;
    const float u8 = u7 * u;
    float fcut = 1.f - 28.f * u6 + 48.f * u7 - 21.f * u8;
    fcut = (u < 1.f) ? fcut : 0.f;
    const float pref = 0.632455532f * rinv * fcut;
    float rb[NB];
#pragma unroll
    for (int k = 0; k < NB; ++k) {
        const float fk = (float)(k + 1) * 0.628318530718f;  // n*pi/RMAX
        rb[k] = __sinf(fk * safe_r) * pref;
    }

    // ---- layer 1 (f32 regs), then silu+pack to bf16 pairs (32 VGPR)
    unsigned hp1[RH / 2];
    {
        float h1[RH];
#pragma unroll
        for (int j = 0; j < RH; ++j) h1[j] = rb1[j];
#pragma unroll
        for (int k = 0; k < NB; ++k) {
#pragma unroll
            for (int j = 0; j < RH; ++j) h1[j] = fmaf(rb[k], rW1[k * RH + j], h1[j]);
        }
#pragma unroll
        for (int j = 0; j < RH; ++j) h1[j] = h1[j] / (1.f + __expf(-h1[j]));
#pragma unroll
        for (int i = 0; i < RH / 2; ++i) {
            const unsigned lo = (unsigned)__bfloat16_as_ushort(__float2bfloat16(h1[2 * i]));
            const unsigned hi = (unsigned)__bfloat16_as_ushort(__float2bfloat16(h1[2 * i + 1]));
            hp1[i] = lo | (hi << 16);
        }
    }

    // ---- layer 2 (accumulate f32, inputs unpacked bf16), silu+pack
    unsigned hp2[RH / 2];
    {
        float h2[RH];
#pragma unroll
        for (int j = 0; j < RH; ++j) h2[j] = rb2[j];
#pragma unroll
        for (int i = 0; i < RH / 2; ++i) {
            const float ka = __uint_as_float(hp1[i] << 16);
            const float kb = __uint_as_float(hp1[i] & 0xffff0000u);
            const float* wa = rW2 + (2 * i) * RH;
            const float* wb = rW2 + (2 * i + 1) * RH;
#pragma unroll
            for (int j = 0; j < RH; ++j) h2[j] = fmaf(ka, wa[j], h2[j]);
#pragma unroll
            for (int j = 0; j < RH; ++j) h2[j] = fmaf(kb, wb[j], h2[j]);
        }
#pragma unroll
        for (int j = 0; j < RH; ++j) h2[j] = h2[j] / (1.f + __expf(-h2[j]));
#pragma unroll
        for (int i = 0; i < RH / 2; ++i) {
            const unsigned lo = (unsigned)__bfloat16_as_ushort(__float2bfloat16(h2[2 * i]));
            const unsigned hi = (unsigned)__bfloat16_as_ushort(__float2bfloat16(h2[2 * i + 1]));
            hp2[i] = lo | (hi << 16);
        }
    }

    const float* hrow = Wemb + species[snd] * CC;

    // ==== two channel-halves: {layer3 -> Gt(bf16)} then segmented reduce ====
#pragma unroll
    for (int half = 0; half < 2; ++half) {
        if (half == 1) __syncthreads();  // protect Gt overwrite (write-after-read)
#pragma unroll
        for (int cc2 = 0; cc2 < 2; ++cc2) {
            const int cc = half * 2 + cc2;  // 8-channel chunk index
            const float4 hsA = *(const float4*)(hrow + cc * 8);
            const float4 hsB = *(const float4*)(hrow + cc * 8 + 4);
            const float hs[8] = {hsA.x, hsA.y, hsA.z, hsA.w, hsB.x, hsB.y, hsB.z, hsB.w};
            float acc[24];
#pragma unroll
            for (int t = 0; t < 24; ++t) acc[t] = 0.f;
#pragma unroll
            for (int i = 0; i < RH / 2; ++i) {
                const float ka = __uint_as_float(hp2[i] << 16);
                const float kb = __uint_as_float(hp2[i] & 0xffff0000u);
                const float* wa = rW3 + (2 * i) * 96 + cc * 24;
                const float* wb = rW3 + (2 * i + 1) * 96 + cc * 24;
#pragma unroll
                for (int t = 0; t < 24; ++t) acc[t] = fmaf(ka, wa[t], acc[t]);
#pragma unroll
                for (int t = 0; t < 24; ++t) acc[t] = fmaf(kb, wb[t], acc[t]);
            }
#pragma unroll
            for (int c8 = 0; c8 < 8; ++c8) {
#pragma unroll
                for (int l = 0; l < 3; ++l) {
                    const int s = cc2 * 24 + c8 * 3 + l;  // 0..47 within half
                    Gt[s * GSTR + tid] = __float2bfloat16(acc[c8 * 3 + l] * hs[c8]);
                }
            }
        }
        __syncthreads();

        // ---- segmented reduce over precomputed segments; thread = (c, j)
        {
            const int c = tid >> 3;
            const int j = tid & 7;
            const int l_j = (j == 0) ? 0 : ((j < 4) ? 1 : 2);
            const int sj = (3 * c + l_j) * GSTR;
            const int s8 = (3 * c + 2) * GSTR;
            const int yj = j * 129;

            const int nseg_local = seg_start_s[0] == 0
                ? 0 : 0;  // placeholder to keep compiler quiet (unused)
            (void)nseg_local;

            // nseg: recompute uniformly from sentinel scan is overkill; read ballots
            const int nseg = __popcll(bal_s[0]) + __popcll(bal_s[1]);

            for (int sgi = 0; sgi < nseg; ++sgi) {
                const int st = seg_start_s[sgi];
                const int en = seg_start_s[sgi + 1];
                const int node = rcv_s[st];
                float aj = 0.f, a8 = 0.f;
                for (int e2 = st; e2 < en; ++e2) {
                    aj = fmaf(__bfloat162float(Gt[sj + e2]), Yt[yj + e2], aj);
                    if (j == 0) a8 = fmaf(__bfloat162float(Gt[s8 + e2]), Yt[8 * 129 + e2], a8);
                }
                float* Ap = A + (size_t)node * (CC * 9) + (half * 16 + c) * 9;
                if (sgi == 0 || sgi == nseg - 1) {
                    atomicAdd(Ap + j, aj);
                    if (j == 0) atomicAdd(Ap + 8, a8);
                } else {
                    Ap[j] = aj;
                    if (j == 0) Ap[8] = a8;
                }
            }
        }
    }
}

// ---------------- node kernel: A -> A2 -> B -> node_e (plain store) ----------------
__global__ __launch_bounds__(256) void node_kernel(
    const float* __restrict__ A, const float* __restrict__ Wmix,
    const float* __restrict__ wquad, const float* __restrict__ Wread,
    const float* __restrict__ attrs, const float* __restrict__ ae,
    float* __restrict__ node_e) {
    __shared__ float Ald[8][CC * 9];
    const int t = threadIdx.x;
    const int ln = t >> 5;
    const int d = t & 31;
    const int n = blockIdx.x * 8 + ln;

    const float* Arow = A + (size_t)n * (CC * 9);
#pragma unroll
    for (int i = 0; i < 9; ++i) Ald[ln][d + 32 * i] = Arow[d + 32 * i] * (1.f / 16.f);
    __syncthreads();

    float A2[9];
#pragma unroll
    for (int m = 0; m < 9; ++m) {
        const int l = (m == 0) ? 0 : ((m < 4) ? 1 : 2);
        float acc = 0.f;
#pragma unroll
        for (int cch = 0; cch < CC; ++cch)
            acc = fmaf(Wmix[(l * CC + cch) * CC + d], Ald[ln][cch * 9 + m], acc);
        A2[m] = acc;
    }

    const float q0 = wquad[0], q1 = wquad[1], q2 = wquad[2];
    const float n0 = A2[0] * A2[0];
    const float n1 = A2[1] * A2[1] + A2[2] * A2[2] + A2[3] * A2[3];
    const float n2 = A2[4] * A2[4] + A2[5] * A2[5] + A2[6] * A2[6] + A2[7] * A2[7] + A2[8] * A2[8];
    const float B = A2[0] + n0 * q0 + n1 * q1 + n2 * q2;

    float v = B * Wread[d];
#pragma unroll
    for (int off = 16; off; off >>= 1) v += __shfl_xor(v, off, 32);

    if (d == 0) {
        float ne = v;
#pragma unroll
        for (int s = 0; s < NSPEC; ++s) ne += attrs[n * NSPEC + s] * ae[s];
        node_e[n] = ne;
    }
}

// ---------------- reduce: per-graph segment sum over sorted batch (no atomics) ----------------
__global__ __launch_bounds__(256) void reduce_kernel(const float* __restrict__ node_e,
                                                     const int* __restrict__ batch,
                                                     float* __restrict__ out) {
    __shared__ float part[4];
    const int g = blockIdx.x;
    int lo = 0, hi = NNODES;
    while (lo < hi) { int mid = (lo + hi) >> 1; if (batch[mid] < g) lo = mid + 1; else hi = mid; }
    const int start = lo;
    int lo2 = start, hi2 = NNODES;
    while (lo2 < hi2) { int mid = (lo2 + hi2) >> 1; if (batch[mid] < g + 1) lo2 = mid + 1; else hi2 = mid; }
    const int end = lo2;

    float s = 0.f;
    for (int i = start + (int)threadIdx.x; i < end; i += 256) s += node_e[i];
#pragma unroll
    for (int off = 32; off; off >>= 1) s += __shfl_xor(s, off, 64);
    if ((threadIdx.x & 63) == 0) part[threadIdx.x >> 6] = s;
    __syncthreads();
    if (threadIdx.x == 0) out[g] = part[0] + part[1] + part[2] + part[3];
}

extern "C" void kernel_launch(void* const* d_in, const int* in_sizes, int n_in,
                              void* d_out, int out_size, void* d_ws, size_t ws_size,
                              hipStream_t stream) {
    const float* attrs  = (const float*)d_in[0];
    const float* pos    = (const float*)d_in[1];
    const float* shifts = (const float*)d_in[2];
    const float* Wemb   = (const float*)d_in[3];
    const float* rW1    = (const float*)d_in[4];
    const float* rb1    = (const float*)d_in[5];
    const float* rW2    = (const float*)d_in[6];
    const float* rb2    = (const float*)d_in[7];
    const float* rW3    = (const float*)d_in[8];
    const float* Wmix   = (const float*)d_in[9];
    const float* wquad  = (const float*)d_in[10];
    const float* Wread  = (const float*)d_in[11];
    const float* ae     = (const float*)d_in[12];
    const int* eidx     = (const int*)d_in[13];
    const int* batch    = (const int*)d_in[14];
    float* out = (float*)d_out;

    // workspace layout; total ~62 MB
    char* wsp = (char*)d_ws;
    float* A      = (float*)wsp;  wsp += (size_t)NNODES * CC * 9 * 4;  // 57.6 MB
    int* perm     = (int*)wsp;    wsp += (size_t)NEDGES * 4;           // 3.2 MB
    int* offsets  = (int*)wsp;    wsp += (size_t)NNODES * 4;
    int* counts   = (int*)wsp;    wsp += (size_t)NNODES * 4;
    int* cursor   = (int*)wsp;    wsp += (size_t)NNODES * 4;
    int* species  = (int*)wsp;    wsp += (size_t)NNODES * 4;
    float* node_e = (float*)wsp;  wsp += (size_t)NNODES * 4;

    hipMemsetAsync(A, 0, (size_t)NNODES * CC * 9 * sizeof(float), stream);
    hipMemsetAsync(counts, 0, NNODES * sizeof(int), stream);
    hipMemsetAsync(cursor, 0, NNODES * sizeof(int), stream);

    species_kernel<<<(NNODES + 255) / 256, 256, 0, stream>>>(attrs, species);
    hist_kernel<<<NEDGES / 256, 256, 0, stream>>>(eidx, counts);
    scan_kernel<<<1, 1024, 0, stream>>>(counts, offsets);
    scatter_kernel<<<NEDGES / 256, 256, 0, stream>>>(eidx, offsets, cursor, perm);

    edge_kernel<<<NCHUNK, EBLK, 0, stream>>>(pos, shifts, eidx, perm,
                                             rW1, rb1, rW2, rb2, rW3,
                                             species, Wemb, A);
    node_kernel<<<NNODES / 8, 256, 0, stream>>>(A, Wmix, wquad, Wread, attrs, ae, node_e);
    reduce_kernel<<<NGRAPHS, 256, 0, stream>>>(node_e, batch, out);
}

// Round 7
// 541.590 us; speedup vs baseline: 27.3106x; 1.3253x over previous
//
#include <hip/hip_runtime.h>
#include <hip/hip_bf16.h>

#define NNODES 50000
#define NEDGES 800000
#define NGRAPHS 32
#define NSPEC 10
#define CC 32
#define RH 64
#define NB 8

#define EBLK 128
#define NCHUNK (NEDGES / EBLK)
#define GSTR 130   // Gt row stride in shorts: bank=(65s+e>>1)%32 = (s+e>>1)%32 -> distinct per s
#define ASTR 72    // act row stride in shorts (144B, 16B aligned)

typedef __bf16 bf16x8 __attribute__((ext_vector_type(8)));
typedef float f32x4 __attribute__((ext_vector_type(4)));

// ---------------- species: recover species id from one-hot attrs ----------------
__global__ __launch_bounds__(256) void species_kernel(const float* __restrict__ attrs,
                                                      int* __restrict__ species) {
    int n = blockIdx.x * 256 + threadIdx.x;
    if (n >= NNODES) return;
    float acc = 0.f;
#pragma unroll
    for (int s = 0; s < NSPEC; ++s) acc += attrs[n * NSPEC + s] * (float)s;
    species[n] = (int)(acc + 0.5f);
}

// ---------------- prep: transpose weights to bf16 [col][k] for MFMA B-frags ----------------
__global__ __launch_bounds__(256) void prep_kernel(const float* __restrict__ rW2,
                                                   const float* __restrict__ rW3,
                                                   __hip_bfloat16* __restrict__ W2T,
                                                   __hip_bfloat16* __restrict__ W3T) {
    int t = blockIdx.x * 256 + threadIdx.x;
    if (t < 64 * 64) {
        int c = t >> 6, k = t & 63;
        W2T[t] = __float2bfloat16(rW2[k * 64 + c]);
    }
    if (t < 96 * 64) {
        int c = t >> 6, k = t & 63;
        W3T[t] = __float2bfloat16(rW3[k * 96 + c]);
    }
}

// ---------------- CSR build: histogram -> scan -> scatter ----------------
__global__ __launch_bounds__(256) void hist_kernel(const int* __restrict__ eidx,
                                                   int* __restrict__ counts) {
    int e = blockIdx.x * 256 + threadIdx.x;
    if (e >= NEDGES) return;
    atomicAdd(&counts[eidx[NEDGES + e]], 1);
}

__global__ __launch_bounds__(1024) void scan_kernel(const int* __restrict__ counts,
                                                    int* __restrict__ offsets) {
    __shared__ int sums[1024];
    const int t = threadIdx.x;
    const int CH = (NNODES + 1023) / 1024;  // 49
    const int base = t * CH;
    int s = 0;
    for (int i = 0; i < CH; ++i) {
        int idx = base + i;
        if (idx < NNODES) s += counts[idx];
    }
    sums[t] = s;
    __syncthreads();
    for (int off = 1; off < 1024; off <<= 1) {
        int add = (t >= off) ? sums[t - off] : 0;
        __syncthreads();
        sums[t] += add;
        __syncthreads();
    }
    int run = sums[t] - s;
    for (int i = 0; i < CH; ++i) {
        int idx = base + i;
        if (idx < NNODES) { offsets[idx] = run; run += counts[idx]; }
    }
}

__global__ __launch_bounds__(256) void scatter_kernel(const int* __restrict__ eidx,
                                                      const int* __restrict__ offsets,
                                                      int* __restrict__ cursor,
                                                      int* __restrict__ perm) {
    int e = blockIdx.x * 256 + threadIdx.x;
    if (e >= NEDGES) return;
    int rcv = eidx[NEDGES + e];
    int pos = atomicAdd(&cursor[rcv], 1);
    perm[offsets[rcv] + pos] = e;
}

// ---------------- phase-2 + Gt-store helper (templated on column half P) ----------------
template <int P>
__device__ __forceinline__ void pass_store_reduce(
    const f32x4 (&acc3)[4][6], const int (&sp_r)[4][4],
    __hip_bfloat16* Gt, const float* Yt, const float* WembLds,
    const unsigned short* rcv_s, const int* seg_start_s,
    const unsigned long long* bal_s, float* __restrict__ A,
    int tid, int w, int lnlo, int q4) {
    // ---- store Gt[s][e] = R * h_sender for cols [P*48, P*48+48)
#pragma unroll
    for (int nti = 0; nti < 3; ++nti) {
        const int nt = P * 3 + nti;
        const int col = nt * 16 + lnlo;
        const int cch = col / 3;           // channel 0..31
        const int s = col - P * 48;        // 0..47
#pragma unroll
        for (int mt = 0; mt < 4; ++mt) {
#pragma unroll
            for (int rr = 0; rr < 4; ++rr) {
                const int e2 = w * 64 + mt * 16 + q4 * 4 + rr;
                const float hs = WembLds[sp_r[mt][rr] * 32 + cch];
                Gt[s * GSTR + e2] = __float2bfloat16(acc3[mt][nt][rr] * hs);
            }
        }
    }
    __syncthreads();

    // ---- segmented reduce: thread = (c, j)
    {
        const int c = tid >> 3;
        const int j = tid & 7;
        const int l_j = (j == 0) ? 0 : ((j < 4) ? 1 : 2);
        const __hip_bfloat16* gj = Gt + (3 * c + l_j) * GSTR;
        const __hip_bfloat16* g8 = Gt + (3 * c + 2) * GSTR;
        const float* yj = Yt + j * 129;
        const float* y8 = Yt + 8 * 129;
        const int nseg = __popcll(bal_s[0]) + __popcll(bal_s[1]);

        for (int sgi = 0; sgi < nseg; ++sgi) {
            const int st = seg_start_s[sgi];
            const int en = seg_start_s[sgi + 1];
            const int node = rcv_s[st];
            float aj = 0.f, a8 = 0.f;
            for (int e2 = st; e2 < en; ++e2) {
                aj = fmaf(__bfloat162float(gj[e2]), yj[e2], aj);
                if (j == 0) a8 = fmaf(__bfloat162float(g8[e2]), y8[e2], a8);
            }
            float* Ap = A + (size_t)node * (CC * 9) + (P * 16 + c) * 9;
            if (sgi == 0 || sgi == nseg - 1) {
                atomicAdd(Ap + j, aj);
                if (j == 0) atomicAdd(Ap + 8, a8);
            } else {
                Ap[j] = aj;
                if (j == 0) Ap[8] = a8;
            }
        }
    }
    __syncthreads();  // protect Gt before next pass overwrites
}

// ---------------- edge kernel: MFMA MLP + segmented scatter ----------------
__global__ __launch_bounds__(EBLK, 2) void edge_kernel(
    const float* __restrict__ pos, const float* __restrict__ shifts,
    const int* __restrict__ eidx, const int* __restrict__ perm,
    const float* __restrict__ rW1, const float* __restrict__ rb1,
    const float* __restrict__ rb2,
    const __hip_bfloat16* __restrict__ W2T, const __hip_bfloat16* __restrict__ W3T,
    const int* __restrict__ species, const float* __restrict__ Wemb,
    float* __restrict__ A) {
    __shared__ __hip_bfloat16 act[128 * ASTR];   // 18,432 B : act1 then act2
    __shared__ __hip_bfloat16 Gt[48 * GSTR];     // 12,480 B
    __shared__ float Yt[9 * 129];                //  4,644 B
    __shared__ float WembLds[NSPEC * CC];        //  1,280 B
    __shared__ unsigned short rcv_s[EBLK];
    __shared__ unsigned short spec_s[EBLK];
    __shared__ int seg_start_s[EBLK + 1];
    __shared__ unsigned long long bal_s[2];

    const int tid = threadIdx.x;
    const int lane = tid & 63;
    const int w = tid >> 6;
    const int lnlo = lane & 15;
    const int q4 = lane >> 4;

    const int slot = blockIdx.x * EBLK + tid;
    const int eid = perm[slot];
    const int snd = eidx[eid];
    const int rcv = eidx[NEDGES + eid];

    const float vx = pos[rcv * 3 + 0] - pos[snd * 3 + 0] + shifts[eid * 3 + 0];
    const float vy = pos[rcv * 3 + 1] - pos[snd * 3 + 1] + shifts[eid * 3 + 1];
    const float vz = pos[rcv * 3 + 2] - pos[snd * 3 + 2] + shifts[eid * 3 + 2];
    const float r = sqrtf(vx * vx + vy * vy + vz * vz);
    const float safe_r = fmaxf(r, 1e-9f);
    const float rinv = 1.f / safe_r;
    const float ux = vx * rinv, uy = vy * rinv, uz = vz * rinv;

    // ---- spherical harmonics + metadata -> LDS
    {
        const float s3 = 1.7320508075688772f;
        const float s15 = 3.872983346207417f;
        const float s15h = 1.9364916731037085f;
        const float s5h = 1.118033988749895f;
        Yt[0 * 129 + tid] = 1.f;
        Yt[1 * 129 + tid] = s3 * ux;
        Yt[2 * 129 + tid] = s3 * uy;
        Yt[3 * 129 + tid] = s3 * uz;
        Yt[4 * 129 + tid] = s15 * ux * uy;
        Yt[5 * 129 + tid] = s15 * uy * uz;
        Yt[6 * 129 + tid] = s5h * (3.f * uz * uz - 1.f);
        Yt[7 * 129 + tid] = s15 * ux * uz;
        Yt[8 * 129 + tid] = s15h * (ux * ux - uy * uy);
        rcv_s[tid] = (unsigned short)rcv;
        spec_s[tid] = (unsigned short)species[snd];
        for (int i = tid; i < NSPEC * CC; i += EBLK) WembLds[i] = Wemb[i];
    }
    __syncthreads();

    // ---- build segment list once (ballot-based)
    {
        const bool head = (tid == 0) || (rcv_s[tid] != rcv_s[tid - 1]);
        const unsigned long long bal = __ballot(head);
        if ((tid & 63) == 0) bal_s[tid >> 6] = bal;
        __syncthreads();
        const unsigned long long below =
            (lane == 0) ? 0ull : (bal & ((1ull << lane) - 1ull));
        int pre = __popcll(below) + (w ? __popcll(bal_s[0]) : 0);
        if (head) seg_start_s[pre] = tid;
        if (tid == 0)
            seg_start_s[__popcll(bal_s[0]) + __popcll(bal_s[1])] = EBLK;  // sentinel
    }

    // ---- radial basis
    const float u = r * 0.2f;
    const float u2 = u * u;
    const float u6 = u2 * u2 * u2;
    const float u7 = u6 * u;
    const float u8 = u7 * u;
    float fcut = 1.f - 28.f * u6 + 48.f * u7 - 21.f * u8;
    fcut = (u < 1.f) ? fcut : 0.f;
    const float pref = 0.632455532f * rinv * fcut;
    float rb[NB];
#pragma unroll
    for (int k = 0; k < NB; ++k) {
        const float fk = (float)(k + 1) * 0.628318530718f;  // n*pi/RMAX
        rb[k] = __sinf(fk * safe_r) * pref;
    }

    // ---- layer 1 (per-thread VALU, K=8), silu, pack -> act1 row (bf16)
    {
        float h1[RH];
#pragma unroll
        for (int j = 0; j < RH; ++j) h1[j] = rb1[j];
#pragma unroll
        for (int k = 0; k < NB; ++k) {
#pragma unroll
            for (int j = 0; j < RH; ++j) h1[j] = fmaf(rb[k], rW1[k * RH + j], h1[j]);
        }
#pragma unroll
        for (int j = 0; j < RH; ++j) h1[j] = h1[j] / (1.f + __expf(-h1[j]));
#pragma unroll
        for (int i = 0; i < 8; ++i) {
            uint4 v;
            unsigned p0 = (unsigned)__bfloat16_as_ushort(__float2bfloat16(h1[8 * i + 0])) |
                          ((unsigned)__bfloat16_as_ushort(__float2bfloat16(h1[8 * i + 1])) << 16);
            unsigned p1 = (unsigned)__bfloat16_as_ushort(__float2bfloat16(h1[8 * i + 2])) |
                          ((unsigned)__bfloat16_as_ushort(__float2bfloat16(h1[8 * i + 3])) << 16);
            unsigned p2 = (unsigned)__bfloat16_as_ushort(__float2bfloat16(h1[8 * i + 4])) |
                          ((unsigned)__bfloat16_as_ushort(__float2bfloat16(h1[8 * i + 5])) << 16);
            unsigned p3 = (unsigned)__bfloat16_as_ushort(__float2bfloat16(h1[8 * i + 6])) |
                          ((unsigned)__bfloat16_as_ushort(__float2bfloat16(h1[8 * i + 7])) << 16);
            v.x = p0; v.y = p1; v.z = p2; v.w = p3;
            *(uint4*)&act[tid * ASTR + i * 8] = v;
        }
    }
    __syncthreads();

    // ---- layer 2: [64e x 64] @ W2T -> acc2, MFMA 16x16x32
    f32x4 acc2[4][4];
#pragma unroll
    for (int mt = 0; mt < 4; ++mt)
#pragma unroll
        for (int nt = 0; nt < 4; ++nt) acc2[mt][nt] = (f32x4){0.f, 0.f, 0.f, 0.f};
    {
        bf16x8 a2[4][2], b2[4][2];
#pragma unroll
        for (int mt = 0; mt < 4; ++mt)
#pragma unroll
            for (int kk = 0; kk < 2; ++kk)
                a2[mt][kk] = *(const bf16x8*)&act[(w * 64 + mt * 16 + lnlo) * ASTR + kk * 32 + q4 * 8];
#pragma unroll
        for (int nt = 0; nt < 4; ++nt)
#pragma unroll
            for (int kk = 0; kk < 2; ++kk)
                b2[nt][kk] = *(const bf16x8*)&W2T[(nt * 16 + lnlo) * 64 + kk * 32 + q4 * 8];
#pragma unroll
        for (int kk = 0; kk < 2; ++kk)
#pragma unroll
            for (int mt = 0; mt < 4; ++mt)
#pragma unroll
                for (int nt = 0; nt < 4; ++nt)
                    acc2[mt][nt] = __builtin_amdgcn_mfma_f32_16x16x32_bf16(
                        a2[mt][kk], b2[nt][kk], acc2[mt][nt], 0, 0, 0);
    }
    __syncthreads();  // all act1 reads complete

    // ---- silu(acc2) -> act2 (same buffer)
#pragma unroll
    for (int mt = 0; mt < 4; ++mt)
#pragma unroll
        for (int nt = 0; nt < 4; ++nt)
#pragma unroll
            for (int rr = 0; rr < 4; ++rr) {
                const float x = acc2[mt][nt][rr];
                const float sx = x / (1.f + __expf(-x));
                act[(w * 64 + mt * 16 + q4 * 4 + rr) * ASTR + nt * 16 + lnlo] =
                    __float2bfloat16(sx);
            }
    __syncthreads();

    // ---- layer 3: [64e x 64] @ W3T (96 cols) -> acc3
    f32x4 acc3[4][6];
#pragma unroll
    for (int mt = 0; mt < 4; ++mt)
#pragma unroll
        for (int nt = 0; nt < 6; ++nt) acc3[mt][nt] = (f32x4){0.f, 0.f, 0.f, 0.f};
    {
        bf16x8 a3[4][2], b3[6][2];
#pragma unroll
        for (int mt = 0; mt < 4; ++mt)
#pragma unroll
            for (int kk = 0; kk < 2; ++kk)
                a3[mt][kk] = *(const bf16x8*)&act[(w * 64 + mt * 16 + lnlo) * ASTR + kk * 32 + q4 * 8];
#pragma unroll
        for (int nt = 0; nt < 6; ++nt)
#pragma unroll
            for (int kk = 0; kk < 2; ++kk)
                b3[nt][kk] = *(const bf16x8*)&W3T[(nt * 16 + lnlo) * 64 + kk * 32 + q4 * 8];
#pragma unroll
        for (int kk = 0; kk < 2; ++kk)
#pragma unroll
            for (int mt = 0; mt < 4; ++mt)
#pragma unroll
                for (int nt = 0; nt < 6; ++nt)
                    acc3[mt][nt] = __builtin_amdgcn_mfma_f32_16x16x32_bf16(
                        a3[mt][kk], b3[nt][kk], acc3[mt][nt], 0, 0, 0);
    }

    // ---- preload sender species for the 16 rows this lane owns
    int sp_r[4][4];
#pragma unroll
    for (int mt = 0; mt < 4; ++mt)
#pragma unroll
        for (int rr = 0; rr < 4; ++rr)
            sp_r[mt][rr] = (int)spec_s[w * 64 + mt * 16 + q4 * 4 + rr];

    // ---- two column-halves: Gt store + segmented reduce
    pass_store_reduce<0>(acc3, sp_r, Gt, Yt, WembLds, rcv_s, seg_start_s, bal_s, A,
                         tid, w, lnlo, q4);
    pass_store_reduce<1>(acc3, sp_r, Gt, Yt, WembLds, rcv_s, seg_start_s, bal_s, A,
                         tid, w, lnlo, q4);
}

// ---------------- node kernel: A -> A2 -> B -> node_e (plain store) ----------------
__global__ __launch_bounds__(256) void node_kernel(
    const float* __restrict__ A, const float* __restrict__ Wmix,
    const float* __restrict__ wquad, const float* __restrict__ Wread,
    const float* __restrict__ attrs, const float* __restrict__ ae,
    float* __restrict__ node_e) {
    __shared__ float Ald[8][CC * 9];
    const int t = threadIdx.x;
    const int ln = t >> 5;
    const int d = t & 31;
    const int n = blockIdx.x * 8 + ln;

    const float* Arow = A + (size_t)n * (CC * 9);
#pragma unroll
    for (int i = 0; i < 9; ++i) Ald[ln][d + 32 * i] = Arow[d + 32 * i] * (1.f / 16.f);
    __syncthreads();

    float A2[9];
#pragma unroll
    for (int m = 0; m < 9; ++m) {
        const int l = (m == 0) ? 0 : ((m < 4) ? 1 : 2);
        float acc = 0.f;
#pragma unroll
        for (int cch = 0; cch < CC; ++cch)
            acc = fmaf(Wmix[(l * CC + cch) * CC + d], Ald[ln][cch * 9 + m], acc);
        A2[m] = acc;
    }

    const float q0 = wquad[0], q1 = wquad[1], q2 = wquad[2];
    const float n0 = A2[0] * A2[0];
    const float n1 = A2[1] * A2[1] + A2[2] * A2[2] + A2[3] * A2[3];
    const float n2 = A2[4] * A2[4] + A2[5] * A2[5] + A2[6] * A2[6] + A2[7] * A2[7] + A2[8] * A2[8];
    const float B = A2[0] + n0 * q0 + n1 * q1 + n2 * q2;

    float v = B * Wread[d];
#pragma unroll
    for (int off = 16; off; off >>= 1) v += __shfl_xor(v, off, 32);

    if (d == 0) {
        float ne = v;
#pragma unroll
        for (int s = 0; s < NSPEC; ++s) ne += attrs[n * NSPEC + s] * ae[s];
        node_e[n] = ne;
    }
}

// ---------------- reduce: per-graph segment sum over sorted batch ----------------
__global__ __launch_bounds__(256) void reduce_kernel(const float* __restrict__ node_e,
                                                     const int* __restrict__ batch,
                                                     float* __restrict__ out) {
    __shared__ float part[4];
    const int g = blockIdx.x;
    int lo = 0, hi = NNODES;
    while (lo < hi) { int mid = (lo + hi) >> 1; if (batch[mid] < g) lo = mid + 1; else hi = mid; }
    const int start = lo;
    int lo2 = start, hi2 = NNODES;
    while (lo2 < hi2) { int mid = (lo2 + hi2) >> 1; if (batch[mid] < g + 1) lo2 = mid + 1; else hi2 = mid; }
    const int end = lo2;

    float s = 0.f;
    for (int i = start + (int)threadIdx.x; i < end; i += 256) s += node_e[i];
#pragma unroll
    for (int off = 32; off; off >>= 1) s += __shfl_xor(s, off, 64);
    if ((threadIdx.x & 63) == 0) part[threadIdx.x >> 6] = s;
    __syncthreads();
    if (threadIdx.x == 0) out[g] = part[0] + part[1] + part[2] + part[3];
}

extern "C" void kernel_launch(void* const* d_in, const int* in_sizes, int n_in,
                              void* d_out, int out_size, void* d_ws, size_t ws_size,
                              hipStream_t stream) {
    const float* attrs  = (const float*)d_in[0];
    const float* pos    = (const float*)d_in[1];
    const float* shifts = (const float*)d_in[2];
    const float* Wemb   = (const float*)d_in[3];
    const float* rW1    = (const float*)d_in[4];
    const float* rb1    = (const float*)d_in[5];
    const float* rW2    = (const float*)d_in[6];
    const float* rb2    = (const float*)d_in[7];
    const float* rW3    = (const float*)d_in[8];
    const float* Wmix   = (const float*)d_in[9];
    const float* wquad  = (const float*)d_in[10];
    const float* Wread  = (const float*)d_in[11];
    const float* ae     = (const float*)d_in[12];
    const int* eidx     = (const int*)d_in[13];
    const int* batch    = (const int*)d_in[14];
    float* out = (float*)d_out;

    // workspace layout; total ~62 MB
    char* wsp = (char*)d_ws;
    float* A      = (float*)wsp;  wsp += (size_t)NNODES * CC * 9 * 4;  // 57.6 MB
    int* perm     = (int*)wsp;    wsp += (size_t)NEDGES * 4;           // 3.2 MB
    int* offsets  = (int*)wsp;    wsp += (size_t)NNODES * 4;
    int* counts   = (int*)wsp;    wsp += (size_t)NNODES * 4;
    int* cursor   = (int*)wsp;    wsp += (size_t)NNODES * 4;
    int* species  = (int*)wsp;    wsp += (size_t)NNODES * 4;
    float* node_e = (float*)wsp;  wsp += (size_t)NNODES * 4;
    __hip_bfloat16* W2T = (__hip_bfloat16*)wsp; wsp += 64 * 64 * 2;    // 8 KB
    __hip_bfloat16* W3T = (__hip_bfloat16*)wsp; wsp += 96 * 64 * 2;    // 12 KB

    hipMemsetAsync(A, 0, (size_t)NNODES * CC * 9 * sizeof(float), stream);
    hipMemsetAsync(counts, 0, NNODES * sizeof(int), stream);
    hipMemsetAsync(cursor, 0, NNODES * sizeof(int), stream);

    species_kernel<<<(NNODES + 255) / 256, 256, 0, stream>>>(attrs, species);
    prep_kernel<<<24, 256, 0, stream>>>(rW2, rW3, W2T, W3T);
    hist_kernel<<<NEDGES / 256, 256, 0, stream>>>(eidx, counts);
    scan_kernel<<<1, 1024, 0, stream>>>(counts, offsets);
    scatter_kernel<<<NEDGES / 256, 256, 0, stream>>>(eidx, offsets, cursor, perm);

    edge_kernel<<<NCHUNK, EBLK, 0, stream>>>(pos, shifts, eidx, perm,
                                             rW1, rb1, rb2, W2T, W3T,
                                             species, Wemb, A);
    node_kernel<<<NNODES / 8, 256, 0, stream>>>(A, Wmix, wquad, Wread, attrs, ae, node_e);
    reduce_kernel<<<NGRAPHS, 256, 0, stream>>>(node_e, batch, out);
}

// Round 8
// 382.483 us; speedup vs baseline: 38.6714x; 1.4160x over previous
//
#include <hip/hip_runtime.h>
#include <hip/hip_bf16.h>

#define NNODES 50000
#define NEDGES 800000
#define NGRAPHS 32
#define NSPEC 10
#define CC 32
#define RH 64
#define NB 8

#define EBLK 128
#define NCHUNK (NEDGES / EBLK)
#define GSTR 136   // Gt row stride (shorts); 272B rows -> 16B-aligned uint4 reads
#define YSTR 136   // Yt row stride (shorts, bf16)
#define ASTR 72    // act row stride in shorts (144B, 16B aligned)
#define SCAN_N 53248  // 1024*52 padded scan domain

typedef __bf16 bf16x8 __attribute__((ext_vector_type(8)));
typedef float f32x4 __attribute__((ext_vector_type(4)));

// ---------------- fused prelude: histogram + species + weight transpose ----------------
__global__ __launch_bounds__(256) void prep_hist_kernel(
    const float* __restrict__ attrs, const int* __restrict__ eidx,
    const float* __restrict__ rW2, const float* __restrict__ rW3,
    int* __restrict__ counts, int* __restrict__ species,
    __hip_bfloat16* __restrict__ W2T, __hip_bfloat16* __restrict__ W3T) {
    int g = blockIdx.x * 256 + threadIdx.x;
    if (g < NEDGES) atomicAdd(&counts[eidx[NEDGES + g]], 1);
    if (g < NNODES) {
        float acc = 0.f;
#pragma unroll
        for (int s = 0; s < NSPEC; ++s) acc += attrs[g * NSPEC + s] * (float)s;
        species[g] = (int)(acc + 0.5f);
    }
    if (g < 64 * 64) {
        int c = g >> 6, k = g & 63;
        W2T[g] = __float2bfloat16(rW2[k * 64 + c]);
    }
    if (g < 96 * 64) {
        int c = g >> 6, k = g & 63;
        W3T[g] = __float2bfloat16(rW3[k * 96 + c]);
    }
}

// ---------------- scan: single block, int4 coalesced-ish, CH=52 ----------------
__global__ __launch_bounds__(1024) void scan_kernel(const int* __restrict__ counts,
                                                    int* __restrict__ offsets) {
    __shared__ int sums[1024];
    const int t = threadIdx.x;
    const int base = t * 52;
    int loc[52];
    int s = 0;
#pragma unroll
    for (int i = 0; i < 13; ++i) {
        int4 v = *(const int4*)&counts[base + i * 4];
        loc[i * 4 + 0] = v.x; loc[i * 4 + 1] = v.y;
        loc[i * 4 + 2] = v.z; loc[i * 4 + 3] = v.w;
        s += v.x + v.y + v.z + v.w;
    }
    sums[t] = s;
    __syncthreads();
    for (int off = 1; off < 1024; off <<= 1) {
        int add = (t >= off) ? sums[t - off] : 0;
        __syncthreads();
        sums[t] += add;
        __syncthreads();
    }
    int run = sums[t] - s;  // exclusive prefix for this chunk
#pragma unroll
    for (int i = 0; i < 13; ++i) {
        int4 o;
        o.x = run; run += loc[i * 4 + 0];
        o.y = run; run += loc[i * 4 + 1];
        o.z = run; run += loc[i * 4 + 2];
        o.w = run; run += loc[i * 4 + 3];
        *(int4*)&offsets[base + i * 4] = o;
    }
}

__global__ __launch_bounds__(256) void scatter_kernel(const int* __restrict__ eidx,
                                                      const int* __restrict__ offsets,
                                                      int* __restrict__ cursor,
                                                      int* __restrict__ perm) {
    int e = blockIdx.x * 256 + threadIdx.x;
    if (e >= NEDGES) return;
    int rcv = eidx[NEDGES + e];
    int pos = atomicAdd(&cursor[rcv], 1);
    perm[offsets[rcv] + pos] = e;
}

// ---------------- segment flush helper ----------------
__device__ __forceinline__ void flushseg(float* __restrict__ A, int node, int cur,
                                         int nseg, int cbase, int j, float aj, float a8) {
    float* Ap = A + (size_t)node * (CC * 9) + cbase * 9;
    if (cur == 0 || cur == nseg - 1) {
        atomicAdd(Ap + j, aj);
        if (j == 0) atomicAdd(Ap + 8, a8);
    } else {
        Ap[j] = aj;
        if (j == 0) Ap[8] = a8;
    }
}

// ---------------- phase-2 + Gt-store (templated on column half P) ----------------
template <int P>
__device__ __forceinline__ void pass_store_reduce(
    const f32x4 (&acc3)[4][6], const int (&sp_r)[4][4],
    __hip_bfloat16* Gt, const __hip_bfloat16* Yt, const float* WembLds,
    const unsigned short* rcv_s, const unsigned long long* bal_s,
    float* __restrict__ A, int tid, int w, int lnlo, int q4) {
    // ---- store Gt[s][e] = R * h_sender for cols [P*48, P*48+48)
#pragma unroll
    for (int nti = 0; nti < 3; ++nti) {
        const int nt = P * 3 + nti;
        const int col = nt * 16 + lnlo;
        const int cch = col / 3;           // channel 0..31
        const int s = col - P * 48;        // 0..47
#pragma unroll
        for (int mt = 0; mt < 4; ++mt) {
#pragma unroll
            for (int rr = 0; rr < 4; ++rr) {
                const int e2 = w * 64 + mt * 16 + q4 * 4 + rr;
                const float hs = WembLds[sp_r[mt][rr] * 32 + cch];
                Gt[s * GSTR + e2] = __float2bfloat16(acc3[mt][nt][rr] * hs);
            }
        }
    }
    __syncthreads();

    // ---- segmented reduce, vectorized 8-wide; thread = (c, j)
    {
        const int c = tid >> 3;
        const int j = tid & 7;
        const int l_j = (j == 0) ? 0 : ((j < 4) ? 1 : 2);
        const uint4* gj = (const uint4*)(Gt + (3 * c + l_j) * GSTR);
        const uint4* g8 = (const uint4*)(Gt + (3 * c + 2) * GSTR);
        const uint4* yj = (const uint4*)(Yt + j * YSTR);
        const uint4* y8 = (const uint4*)(Yt + 8 * YSTR);
        const unsigned long long b0 = bal_s[0], b1 = bal_s[1];
        const int nseg = __popcll(b0) + __popcll(b1);
        const int cbase = P * 16 + c;

        float aj = 0.f, a8 = 0.f;
        int cur = 0;
        int node = rcv_s[0];

        for (int ch = 0; ch < 16; ++ch) {
            unsigned msk = (unsigned)(((ch < 8) ? (b0 >> (ch * 8)) : (b1 >> ((ch - 8) * 8))) & 0xffull);
            if (ch == 0) msk &= ~1u;
            const uint4 gv = gj[ch];
            const uint4 yv = yj[ch];
            uint4 gv8 = {0, 0, 0, 0}, yv8 = {0, 0, 0, 0};
            if (j == 0) { gv8 = g8[ch]; yv8 = y8[ch]; }
            const unsigned gw[4] = {gv.x, gv.y, gv.z, gv.w};
            const unsigned yw[4] = {yv.x, yv.y, yv.z, yv.w};
            const unsigned gw8[4] = {gv8.x, gv8.y, gv8.z, gv8.w};
            const unsigned yw8[4] = {yv8.x, yv8.y, yv8.z, yv8.w};
#pragma unroll
            for (int i = 0; i < 8; ++i) {
                if (msk & (1u << i)) {
                    flushseg(A, node, cur, nseg, cbase, j, aj, a8);
                    aj = 0.f; a8 = 0.f; ++cur;
                    node = rcv_s[ch * 8 + i];
                }
                const unsigned gu = gw[i >> 1], yu = yw[i >> 1];
                const float gf = __uint_as_float((i & 1) ? (gu & 0xffff0000u) : (gu << 16));
                const float yf = __uint_as_float((i & 1) ? (yu & 0xffff0000u) : (yu << 16));
                aj = fmaf(gf, yf, aj);
                if (j == 0) {
                    const unsigned hu = gw8[i >> 1], zu = yw8[i >> 1];
                    const float hf = __uint_as_float((i & 1) ? (hu & 0xffff0000u) : (hu << 16));
                    const float zf = __uint_as_float((i & 1) ? (zu & 0xffff0000u) : (zu << 16));
                    a8 = fmaf(hf, zf, a8);
                }
            }
        }
        flushseg(A, node, cur, nseg, cbase, j, aj, a8);
    }
    __syncthreads();  // protect Gt before next pass overwrites
}

// ---------------- edge kernel: MFMA MLP + segmented scatter ----------------
__global__ __launch_bounds__(EBLK, 2) void edge_kernel(
    const float* __restrict__ pos, const float* __restrict__ shifts,
    const int* __restrict__ eidx, const int* __restrict__ perm,
    const float* __restrict__ rW1, const float* __restrict__ rb1,
    const __hip_bfloat16* __restrict__ W2T, const __hip_bfloat16* __restrict__ W3T,
    const int* __restrict__ species, const float* __restrict__ Wemb,
    float* __restrict__ A) {
    // union: act (128x72 shorts = 18432B) overlays Gt (48x136 shorts = 13056B)
    __shared__ __align__(16) short smem_u[128 * ASTR];
    __shared__ __align__(16) __hip_bfloat16 Yt[9 * YSTR];   // 2448B
    __shared__ float WembLds[NSPEC * CC];                   // 1280B
    __shared__ unsigned short rcv_s[EBLK];
    __shared__ unsigned char spec_s[EBLK];
    __shared__ unsigned long long bal_s[2];

    __hip_bfloat16* act = (__hip_bfloat16*)smem_u;
    __hip_bfloat16* Gt = (__hip_bfloat16*)smem_u;

    const int tid = threadIdx.x;
    const int lane = tid & 63;
    const int w = tid >> 6;
    const int lnlo = lane & 15;
    const int q4 = lane >> 4;

    const int slot = blockIdx.x * EBLK + tid;
    const int eid = perm[slot];
    const int snd = eidx[eid];
    const int rcv = eidx[NEDGES + eid];

    const float vx = pos[rcv * 3 + 0] - pos[snd * 3 + 0] + shifts[eid * 3 + 0];
    const float vy = pos[rcv * 3 + 1] - pos[snd * 3 + 1] + shifts[eid * 3 + 1];
    const float vz = pos[rcv * 3 + 2] - pos[snd * 3 + 2] + shifts[eid * 3 + 2];
    const float r = sqrtf(vx * vx + vy * vy + vz * vz);
    const float safe_r = fmaxf(r, 1e-9f);
    const float rinv = 1.f / safe_r;
    const float ux = vx * rinv, uy = vy * rinv, uz = vz * rinv;

    // ---- spherical harmonics (bf16) + metadata -> LDS
    {
        const float s3 = 1.7320508075688772f;
        const float s15 = 3.872983346207417f;
        const float s15h = 1.9364916731037085f;
        const float s5h = 1.118033988749895f;
        Yt[0 * YSTR + tid] = __float2bfloat16(1.f);
        Yt[1 * YSTR + tid] = __float2bfloat16(s3 * ux);
        Yt[2 * YSTR + tid] = __float2bfloat16(s3 * uy);
        Yt[3 * YSTR + tid] = __float2bfloat16(s3 * uz);
        Yt[4 * YSTR + tid] = __float2bfloat16(s15 * ux * uy);
        Yt[5 * YSTR + tid] = __float2bfloat16(s15 * uy * uz);
        Yt[6 * YSTR + tid] = __float2bfloat16(s5h * (3.f * uz * uz - 1.f));
        Yt[7 * YSTR + tid] = __float2bfloat16(s15 * ux * uz);
        Yt[8 * YSTR + tid] = __float2bfloat16(s15h * (ux * ux - uy * uy));
        rcv_s[tid] = (unsigned short)rcv;
        spec_s[tid] = (unsigned char)species[snd];
        for (int i = tid; i < NSPEC * CC; i += EBLK) WembLds[i] = Wemb[i];
    }
    __syncthreads();

    // ---- segment-head ballot (heads recovered from masks in phase-2)
    {
        const bool head = (tid == 0) || (rcv_s[tid] != rcv_s[tid - 1]);
        const unsigned long long bal = __ballot(head);
        if ((tid & 63) == 0) bal_s[tid >> 6] = bal;
    }

    // ---- radial basis
    const float u = r * 0.2f;
    const float u2 = u * u;
    const float u6 = u2 * u2 * u2;
    const float u7 = u6 * u;
    const float u8 = u7 * u;
    float fcut = 1.f - 28.f * u6 + 48.f * u7 - 21.f * u8;
    fcut = (u < 1.f) ? fcut : 0.f;
    const float pref = 0.632455532f * rinv * fcut;
    float rb[NB];
#pragma unroll
    for (int k = 0; k < NB; ++k) {
        const float fk = (float)(k + 1) * 0.628318530718f;  // n*pi/RMAX
        rb[k] = __sinf(fk * safe_r) * pref;
    }

    // ---- layer 1 (per-thread VALU, K=8), silu, pack -> act1 row (bf16)
    {
        float h1[RH];
#pragma unroll
        for (int j = 0; j < RH; ++j) h1[j] = rb1[j];
#pragma unroll
        for (int k = 0; k < NB; ++k) {
#pragma unroll
            for (int j = 0; j < RH; ++j) h1[j] = fmaf(rb[k], rW1[k * RH + j], h1[j]);
        }
#pragma unroll
        for (int j = 0; j < RH; ++j) h1[j] = h1[j] / (1.f + __expf(-h1[j]));
#pragma unroll
        for (int i = 0; i < 8; ++i) {
            uint4 v;
            v.x = (unsigned)__bfloat16_as_ushort(__float2bfloat16(h1[8 * i + 0])) |
                  ((unsigned)__bfloat16_as_ushort(__float2bfloat16(h1[8 * i + 1])) << 16);
            v.y = (unsigned)__bfloat16_as_ushort(__float2bfloat16(h1[8 * i + 2])) |
                  ((unsigned)__bfloat16_as_ushort(__float2bfloat16(h1[8 * i + 3])) << 16);
            v.z = (unsigned)__bfloat16_as_ushort(__float2bfloat16(h1[8 * i + 4])) |
                  ((unsigned)__bfloat16_as_ushort(__float2bfloat16(h1[8 * i + 5])) << 16);
            v.w = (unsigned)__bfloat16_as_ushort(__float2bfloat16(h1[8 * i + 6])) |
                  ((unsigned)__bfloat16_as_ushort(__float2bfloat16(h1[8 * i + 7])) << 16);
            *(uint4*)&act[tid * ASTR + i * 8] = v;
        }
    }
    __syncthreads();

    // ---- layer 2: [64e x 64] @ W2T -> acc2, MFMA 16x16x32
    f32x4 acc2[4][4];
#pragma unroll
    for (int mt = 0; mt < 4; ++mt)
#pragma unroll
        for (int nt = 0; nt < 4; ++nt) acc2[mt][nt] = (f32x4){0.f, 0.f, 0.f, 0.f};
    {
        bf16x8 a2[4][2], b2[4][2];
#pragma unroll
        for (int mt = 0; mt < 4; ++mt)
#pragma unroll
            for (int kk = 0; kk < 2; ++kk)
                a2[mt][kk] = *(const bf16x8*)&act[(w * 64 + mt * 16 + lnlo) * ASTR + kk * 32 + q4 * 8];
#pragma unroll
        for (int nt = 0; nt < 4; ++nt)
#pragma unroll
            for (int kk = 0; kk < 2; ++kk)
                b2[nt][kk] = *(const bf16x8*)&W2T[(nt * 16 + lnlo) * 64 + kk * 32 + q4 * 8];
#pragma unroll
        for (int kk = 0; kk < 2; ++kk)
#pragma unroll
            for (int mt = 0; mt < 4; ++mt)
#pragma unroll
                for (int nt = 0; nt < 4; ++nt)
                    acc2[mt][nt] = __builtin_amdgcn_mfma_f32_16x16x32_bf16(
                        a2[mt][kk], b2[nt][kk], acc2[mt][nt], 0, 0, 0);
    }
    __syncthreads();  // all act1 reads complete

    // ---- silu(acc2) -> act2 (same buffer)
#pragma unroll
    for (int mt = 0; mt < 4; ++mt)
#pragma unroll
        for (int nt = 0; nt < 4; ++nt)
#pragma unroll
            for (int rr = 0; rr < 4; ++rr) {
                const float x = acc2[mt][nt][rr];
                const float sx = x / (1.f + __expf(-x));
                act[(w * 64 + mt * 16 + q4 * 4 + rr) * ASTR + nt * 16 + lnlo] =
                    __float2bfloat16(sx);
            }
    __syncthreads();

    // ---- layer 3: [64e x 64] @ W3T (96 cols) -> acc3
    f32x4 acc3[4][6];
#pragma unroll
    for (int mt = 0; mt < 4; ++mt)
#pragma unroll
        for (int nt = 0; nt < 6; ++nt) acc3[mt][nt] = (f32x4){0.f, 0.f, 0.f, 0.f};
    {
        bf16x8 a3[4][2], b3[6][2];
#pragma unroll
        for (int mt = 0; mt < 4; ++mt)
#pragma unroll
            for (int kk = 0; kk < 2; ++kk)
                a3[mt][kk] = *(const bf16x8*)&act[(w * 64 + mt * 16 + lnlo) * ASTR + kk * 32 + q4 * 8];
#pragma unroll
        for (int nt = 0; nt < 6; ++nt)
#pragma unroll
            for (int kk = 0; kk < 2; ++kk)
                b3[nt][kk] = *(const bf16x8*)&W3T[(nt * 16 + lnlo) * 64 + kk * 32 + q4 * 8];
#pragma unroll
        for (int kk = 0; kk < 2; ++kk)
#pragma unroll
            for (int mt = 0; mt < 4; ++mt)
#pragma unroll
                for (int nt = 0; nt < 6; ++nt)
                    acc3[mt][nt] = __builtin_amdgcn_mfma_f32_16x16x32_bf16(
                        a3[mt][kk], b3[nt][kk], acc3[mt][nt], 0, 0, 0);
    }
    __syncthreads();  // act fully dead (Gt overlays it)

    // ---- preload sender species for the 16 rows this lane owns
    int sp_r[4][4];
#pragma unroll
    for (int mt = 0; mt < 4; ++mt)
#pragma unroll
        for (int rr = 0; rr < 4; ++rr)
            sp_r[mt][rr] = (int)spec_s[w * 64 + mt * 16 + q4 * 4 + rr];

    // ---- two column-halves: Gt store + segmented reduce
    pass_store_reduce<0>(acc3, sp_r, Gt, Yt, WembLds, rcv_s, bal_s, A, tid, w, lnlo, q4);
    pass_store_reduce<1>(acc3, sp_r, Gt, Yt, WembLds, rcv_s, bal_s, A, tid, w, lnlo, q4);
}

// ---------------- node kernel: A -> A2 -> B -> node_e (plain store) ----------------
__global__ __launch_bounds__(256) void node_kernel(
    const float* __restrict__ A, const float* __restrict__ Wmix,
    const float* __restrict__ wquad, const float* __restrict__ Wread,
    const float* __restrict__ attrs, const float* __restrict__ ae,
    float* __restrict__ node_e) {
    __shared__ float Ald[8][CC * 9];
    const int t = threadIdx.x;
    const int ln = t >> 5;
    const int d = t & 31;
    const int n = blockIdx.x * 8 + ln;

    const float* Arow = A + (size_t)n * (CC * 9);
#pragma unroll
    for (int i = 0; i < 9; ++i) Ald[ln][d + 32 * i] = Arow[d + 32 * i] * (1.f / 16.f);
    __syncthreads();

    float A2[9];
#pragma unroll
    for (int m = 0; m < 9; ++m) {
        const int l = (m == 0) ? 0 : ((m < 4) ? 1 : 2);
        float acc = 0.f;
#pragma unroll
        for (int cch = 0; cch < CC; ++cch)
            acc = fmaf(Wmix[(l * CC + cch) * CC + d], Ald[ln][cch * 9 + m], acc);
        A2[m] = acc;
    }

    const float q0 = wquad[0], q1 = wquad[1], q2 = wquad[2];
    const float n0 = A2[0] * A2[0];
    const float n1 = A2[1] * A2[1] + A2[2] * A2[2] + A2[3] * A2[3];
    const float n2 = A2[4] * A2[4] + A2[5] * A2[5] + A2[6] * A2[6] + A2[7] * A2[7] + A2[8] * A2[8];
    const float B = A2[0] + n0 * q0 + n1 * q1 + n2 * q2;

    float v = B * Wread[d];
#pragma unroll
    for (int off = 16; off; off >>= 1) v += __shfl_xor(v, off, 32);

    if (d == 0) {
        float ne = v;
#pragma unroll
        for (int s = 0; s < NSPEC; ++s) ne += attrs[n * NSPEC + s] * ae[s];
        node_e[n] = ne;
    }
}

// ---------------- reduce: per-graph segment sum over sorted batch ----------------
__global__ __launch_bounds__(256) void reduce_kernel(const float* __restrict__ node_e,
                                                     const int* __restrict__ batch,
                                                     float* __restrict__ out) {
    __shared__ float part[4];
    const int g = blockIdx.x;
    int lo = 0, hi = NNODES;
    while (lo < hi) { int mid = (lo + hi) >> 1; if (batch[mid] < g) lo = mid + 1; else hi = mid; }
    const int start = lo;
    int lo2 = start, hi2 = NNODES;
    while (lo2 < hi2) { int mid = (lo2 + hi2) >> 1; if (batch[mid] < g + 1) lo2 = mid + 1; else hi2 = mid; }
    const int end = lo2;

    float s = 0.f;
    for (int i = start + (int)threadIdx.x; i < end; i += 256) s += node_e[i];
#pragma unroll
    for (int off = 32; off; off >>= 1) s += __shfl_xor(s, off, 64);
    if ((threadIdx.x & 63) == 0) part[threadIdx.x >> 6] = s;
    __syncthreads();
    if (threadIdx.x == 0) out[g] = part[0] + part[1] + part[2] + part[3];
}

extern "C" void kernel_launch(void* const* d_in, const int* in_sizes, int n_in,
                              void* d_out, int out_size, void* d_ws, size_t ws_size,
                              hipStream_t stream) {
    const float* attrs  = (const float*)d_in[0];
    const float* pos    = (const float*)d_in[1];
    const float* shifts = (const float*)d_in[2];
    const float* Wemb   = (const float*)d_in[3];
    const float* rW1    = (const float*)d_in[4];
    const float* rb1    = (const float*)d_in[5];
    const float* rW2    = (const float*)d_in[6];
    const float* rb2    = (const float*)d_in[7];
    const float* rW3    = (const float*)d_in[8];
    const float* Wmix   = (const float*)d_in[9];
    const float* wquad  = (const float*)d_in[10];
    const float* Wread  = (const float*)d_in[11];
    const float* ae     = (const float*)d_in[12];
    const int* eidx     = (const int*)d_in[13];
    const int* batch    = (const int*)d_in[14];
    float* out = (float*)d_out;
    (void)rb2;

    // workspace layout; ~62.5 MB
    char* wsp = (char*)d_ws;
    float* A      = (float*)wsp;  wsp += (size_t)NNODES * CC * 9 * 4;  // 57.6 MB
    int* perm     = (int*)wsp;    wsp += (size_t)NEDGES * 4;           // 3.2 MB
    int* offsets  = (int*)wsp;    wsp += (size_t)SCAN_N * 4;           // 213 KB
    int* counts   = (int*)wsp;    wsp += (size_t)SCAN_N * 4;           // 213 KB (memset w/ cursor)
    int* cursor   = (int*)wsp;    wsp += (size_t)SCAN_N * 4;           // 213 KB
    int* species  = (int*)wsp;    wsp += (size_t)NNODES * 4;
    float* node_e = (float*)wsp;  wsp += (size_t)NNODES * 4;
    __hip_bfloat16* W2T = (__hip_bfloat16*)wsp; wsp += 64 * 64 * 2;    // 8 KB
    __hip_bfloat16* W3T = (__hip_bfloat16*)wsp; wsp += 96 * 64 * 2;    // 12 KB

    hipMemsetAsync(A, 0, (size_t)NNODES * CC * 9 * sizeof(float), stream);
    hipMemsetAsync(counts, 0, (size_t)SCAN_N * 2 * sizeof(int), stream);  // counts+cursor

    prep_hist_kernel<<<NEDGES / 256, 256, 0, stream>>>(attrs, eidx, rW2, rW3,
                                                       counts, species, W2T, W3T);
    scan_kernel<<<1, 1024, 0, stream>>>(counts, offsets);
    scatter_kernel<<<NEDGES / 256, 256, 0, stream>>>(eidx, offsets, cursor, perm);

    edge_kernel<<<NCHUNK, EBLK, 0, stream>>>(pos, shifts, eidx, perm,
                                             rW1, rb1, W2T, W3T,
                                             species, Wemb, A);
    node_kernel<<<NNODES / 8, 256, 0, stream>>>(A, Wmix, wquad, Wread, attrs, ae, node_e);
    reduce_kernel<<<NGRAPHS, 256, 0, stream>>>(node_e, batch, out);
}

// Round 9
// 339.896 us; speedup vs baseline: 43.5168x; 1.1253x over previous
//
#include <hip/hip_runtime.h>
#include <hip/hip_bf16.h>

#define NNODES 50000
#define NEDGES 800000
#define NGRAPHS 32
#define NSPEC 10
#define CC 32
#define RH 64
#define NB 8

#define EBLK 128
#define NCHUNK (NEDGES / EBLK)
#define GSTR 136   // Gt row stride (shorts); 272B rows -> 16B-aligned uint4 reads
#define YSTR 136   // Yt row stride (shorts, bf16)
#define ASTR 72    // act row stride in shorts (144B, 16B aligned)
#define RBSTR 40   // rbA row stride in shorts (80B, 16B aligned; bank stride 20)
#define SCAN_N 53248  // 1024*52 padded scan domain

typedef __bf16 bf16x8 __attribute__((ext_vector_type(8)));
typedef float f32x4 __attribute__((ext_vector_type(4)));

__device__ __forceinline__ unsigned pack2bf(float a, float b) {
    return (unsigned)__bfloat16_as_ushort(__float2bfloat16(a)) |
           ((unsigned)__bfloat16_as_ushort(__float2bfloat16(b)) << 16);
}

// ---------------- fused prelude: histogram + species + weight transpose ----------------
__global__ __launch_bounds__(256) void prep_hist_kernel(
    const float* __restrict__ attrs, const int* __restrict__ eidx,
    const float* __restrict__ rW1, const float* __restrict__ rb1,
    const float* __restrict__ rW2, const float* __restrict__ rW3,
    int* __restrict__ counts, int* __restrict__ species,
    __hip_bfloat16* __restrict__ W1T, __hip_bfloat16* __restrict__ W2T,
    __hip_bfloat16* __restrict__ W3T) {
    int g = blockIdx.x * 256 + threadIdx.x;
    if (g < NEDGES) atomicAdd(&counts[eidx[NEDGES + g]], 1);
    if (g < NNODES) {
        float acc = 0.f;
#pragma unroll
        for (int s = 0; s < NSPEC; ++s) acc += attrs[g * NSPEC + s] * (float)s;
        species[g] = (int)(acc + 0.5f);
    }
    if (g < 64 * 32) {  // W1T[col][k]: k<8 = rW1[k][col], k==8 = rb1[col], else 0
        int c = g >> 5, k = g & 31;
        float v = (k < 8) ? rW1[k * 64 + c] : ((k == 8) ? rb1[c] : 0.f);
        W1T[g] = __float2bfloat16(v);
    }
    if (g < 64 * 64) {
        int c = g >> 6, k = g & 63;
        W2T[g] = __float2bfloat16(rW2[k * 64 + c]);
    }
    if (g < 96 * 64) {
        int c = g >> 6, k = g & 63;
        W3T[g] = __float2bfloat16(rW3[k * 96 + c]);
    }
}

// ---------------- scan: single block, int4, CH=52 ----------------
__global__ __launch_bounds__(1024) void scan_kernel(const int* __restrict__ counts,
                                                    int* __restrict__ offsets) {
    __shared__ int sums[1024];
    const int t = threadIdx.x;
    const int base = t * 52;
    int loc[52];
    int s = 0;
#pragma unroll
    for (int i = 0; i < 13; ++i) {
        int4 v = *(const int4*)&counts[base + i * 4];
        loc[i * 4 + 0] = v.x; loc[i * 4 + 1] = v.y;
        loc[i * 4 + 2] = v.z; loc[i * 4 + 3] = v.w;
        s += v.x + v.y + v.z + v.w;
    }
    sums[t] = s;
    __syncthreads();
    for (int off = 1; off < 1024; off <<= 1) {
        int add = (t >= off) ? sums[t - off] : 0;
        __syncthreads();
        sums[t] += add;
        __syncthreads();
    }
    int run = sums[t] - s;
#pragma unroll
    for (int i = 0; i < 13; ++i) {
        int4 o;
        o.x = run; run += loc[i * 4 + 0];
        o.y = run; run += loc[i * 4 + 1];
        o.z = run; run += loc[i * 4 + 2];
        o.w = run; run += loc[i * 4 + 3];
        *(int4*)&offsets[base + i * 4] = o;
    }
}

__global__ __launch_bounds__(256) void scatter_kernel(const int* __restrict__ eidx,
                                                      const int* __restrict__ offsets,
                                                      int* __restrict__ cursor,
                                                      int* __restrict__ perm) {
    int e = blockIdx.x * 256 + threadIdx.x;
    if (e >= NEDGES) return;
    int rcv = eidx[NEDGES + e];
    int pos = atomicAdd(&cursor[rcv], 1);
    perm[offsets[rcv] + pos] = e;
}

// ---------------- segment flush helper ----------------
__device__ __forceinline__ void flushseg(float* __restrict__ A, int node, int cur,
                                         int nseg, int cbase, int j, float aj, float a8) {
    float* Ap = A + (size_t)node * (CC * 9) + cbase * 9;
    if (cur == 0 || cur == nseg - 1) {
        atomicAdd(Ap + j, aj);
        if (j == 0) atomicAdd(Ap + 8, a8);
    } else {
        Ap[j] = aj;
        if (j == 0) Ap[8] = a8;
    }
}

// ---------------- phase-2 + Gt-store (templated on column half P) ----------------
template <int P>
__device__ __forceinline__ void pass_store_reduce(
    const f32x4 (&acc3)[4][6], const int (&sp_r)[4][4],
    __hip_bfloat16* Gt, const __hip_bfloat16* Yt, const float* WembLds,
    const unsigned short* rcv_s, const unsigned long long* bal_s,
    float* __restrict__ A, int tid, int w, int lnlo, int q4) {
    // ---- store Gt[s][e] = R * h_sender, packed 4-wide along e (rr=0..3)
#pragma unroll
    for (int nti = 0; nti < 3; ++nti) {
        const int nt = P * 3 + nti;
        const int col = nt * 16 + lnlo;
        const int cch = col / 3;           // channel 0..31
        const int s = nti * 16 + lnlo;     // 0..47 within half
#pragma unroll
        for (int mt = 0; mt < 4; ++mt) {
            const float f0 = acc3[mt][nt][0] * WembLds[sp_r[mt][0] * 32 + cch];
            const float f1 = acc3[mt][nt][1] * WembLds[sp_r[mt][1] * 32 + cch];
            const float f2 = acc3[mt][nt][2] * WembLds[sp_r[mt][2] * 32 + cch];
            const float f3 = acc3[mt][nt][3] * WembLds[sp_r[mt][3] * 32 + cch];
            uint2 pk;
            pk.x = pack2bf(f0, f1);
            pk.y = pack2bf(f2, f3);
            *(uint2*)&Gt[s * GSTR + w * 64 + mt * 16 + q4 * 4] = pk;
        }
    }
    __syncthreads();

    // ---- segmented reduce, vectorized 8-wide; thread = (c, j)
    {
        const int c = tid >> 3;
        const int j = tid & 7;
        const int l_j = (j == 0) ? 0 : ((j < 4) ? 1 : 2);
        const uint4* gj = (const uint4*)(Gt + (3 * c + l_j) * GSTR);
        const uint4* g8 = (const uint4*)(Gt + (3 * c + 2) * GSTR);
        const uint4* yj = (const uint4*)(Yt + j * YSTR);
        const uint4* y8 = (const uint4*)(Yt + 8 * YSTR);
        const unsigned long long b0 = bal_s[0], b1 = bal_s[1];
        const int nseg = __popcll(b0) + __popcll(b1);
        const int cbase = P * 16 + c;

        float aj = 0.f, a8 = 0.f;
        int cur = 0;
        int node = rcv_s[0];

        for (int ch = 0; ch < 16; ++ch) {
            unsigned msk = (unsigned)(((ch < 8) ? (b0 >> (ch * 8)) : (b1 >> ((ch - 8) * 8))) & 0xffull);
            if (ch == 0) msk &= ~1u;
            const uint4 gv = gj[ch];
            const uint4 yv = yj[ch];
            uint4 gv8 = {0, 0, 0, 0}, yv8 = {0, 0, 0, 0};
            if (j == 0) { gv8 = g8[ch]; yv8 = y8[ch]; }
            const unsigned gw[4] = {gv.x, gv.y, gv.z, gv.w};
            const unsigned yw[4] = {yv.x, yv.y, yv.z, yv.w};
            const unsigned gw8[4] = {gv8.x, gv8.y, gv8.z, gv8.w};
            const unsigned yw8[4] = {yv8.x, yv8.y, yv8.z, yv8.w};
#pragma unroll
            for (int i = 0; i < 8; ++i) {
                if (msk & (1u << i)) {
                    flushseg(A, node, cur, nseg, cbase, j, aj, a8);
                    aj = 0.f; a8 = 0.f; ++cur;
                    node = rcv_s[ch * 8 + i];
                }
                const unsigned gu = gw[i >> 1], yu = yw[i >> 1];
                const float gf = __uint_as_float((i & 1) ? (gu & 0xffff0000u) : (gu << 16));
                const float yf = __uint_as_float((i & 1) ? (yu & 0xffff0000u) : (yu << 16));
                aj = fmaf(gf, yf, aj);
                if (j == 0) {
                    const unsigned hu = gw8[i >> 1], zu = yw8[i >> 1];
                    const float hf = __uint_as_float((i & 1) ? (hu & 0xffff0000u) : (hu << 16));
                    const float zf = __uint_as_float((i & 1) ? (zu & 0xffff0000u) : (zu << 16));
                    a8 = fmaf(hf, zf, a8);
                }
            }
        }
        flushseg(A, node, cur, nseg, cbase, j, aj, a8);
    }
    __syncthreads();  // protect Gt before next pass overwrites
}

// ---------------- edge kernel: full-MFMA MLP + segmented scatter ----------------
__global__ __launch_bounds__(EBLK, 3) void edge_kernel(
    const float* __restrict__ pos, const float* __restrict__ shifts,
    const int* __restrict__ eidx, const int* __restrict__ perm,
    const __hip_bfloat16* __restrict__ W1T, const __hip_bfloat16* __restrict__ W2T,
    const __hip_bfloat16* __restrict__ W3T,
    const int* __restrict__ species, const float* __restrict__ Wemb,
    float* __restrict__ A) {
    // union: act (128x72 shorts) overlays Gt (48x136) and rbA (128x40)
    __shared__ __align__(16) short smem_u[128 * ASTR];
    __shared__ __align__(16) __hip_bfloat16 Yt[9 * YSTR];
    __shared__ float WembLds[NSPEC * CC];
    __shared__ unsigned short rcv_s[EBLK];
    __shared__ unsigned char spec_s[EBLK];
    __shared__ unsigned long long bal_s[2];

    __hip_bfloat16* act = (__hip_bfloat16*)smem_u;
    __hip_bfloat16* Gt = (__hip_bfloat16*)smem_u;
    __hip_bfloat16* rbA = (__hip_bfloat16*)smem_u;

    const int tid = threadIdx.x;
    const int lane = tid & 63;
    const int w = tid >> 6;
    const int lnlo = lane & 15;
    const int q4 = lane >> 4;

    const int slot = blockIdx.x * EBLK + tid;
    const int eid = perm[slot];
    const int snd = eidx[eid];
    const int rcv = eidx[NEDGES + eid];

    const float vx = pos[rcv * 3 + 0] - pos[snd * 3 + 0] + shifts[eid * 3 + 0];
    const float vy = pos[rcv * 3 + 1] - pos[snd * 3 + 1] + shifts[eid * 3 + 1];
    const float vz = pos[rcv * 3 + 2] - pos[snd * 3 + 2] + shifts[eid * 3 + 2];
    const float r = sqrtf(vx * vx + vy * vy + vz * vz);
    const float safe_r = fmaxf(r, 1e-9f);
    const float rinv = 1.f / safe_r;
    const float ux = vx * rinv, uy = vy * rinv, uz = vz * rinv;

    // ---- spherical harmonics (bf16) + metadata -> LDS
    {
        const float s3 = 1.7320508075688772f;
        const float s15 = 3.872983346207417f;
        const float s15h = 1.9364916731037085f;
        const float s5h = 1.118033988749895f;
        Yt[0 * YSTR + tid] = __float2bfloat16(1.f);
        Yt[1 * YSTR + tid] = __float2bfloat16(s3 * ux);
        Yt[2 * YSTR + tid] = __float2bfloat16(s3 * uy);
        Yt[3 * YSTR + tid] = __float2bfloat16(s3 * uz);
        Yt[4 * YSTR + tid] = __float2bfloat16(s15 * ux * uy);
        Yt[5 * YSTR + tid] = __float2bfloat16(s15 * uy * uz);
        Yt[6 * YSTR + tid] = __float2bfloat16(s5h * (3.f * uz * uz - 1.f));
        Yt[7 * YSTR + tid] = __float2bfloat16(s15 * ux * uz);
        Yt[8 * YSTR + tid] = __float2bfloat16(s15h * (ux * ux - uy * uy));
        rcv_s[tid] = (unsigned short)rcv;
        spec_s[tid] = (unsigned char)species[snd];
        for (int i = tid; i < NSPEC * CC; i += EBLK) WembLds[i] = Wemb[i];
    }

    // ---- radial basis -> rbA row (own wave's rows; no barrier needed before frag load)
    {
        const float u = r * 0.2f;
        const float u2 = u * u;
        const float u6 = u2 * u2 * u2;
        const float u7 = u6 * u;
        const float u8v = u7 * u;
        float fcut = 1.f - 28.f * u6 + 48.f * u7 - 21.f * u8v;
        fcut = (u < 1.f) ? fcut : 0.f;
        const float pref = 0.632455532f * rinv * fcut;
        float rb[NB];
#pragma unroll
        for (int k = 0; k < NB; ++k) {
            const float fk = (float)(k + 1) * 0.628318530718f;  // n*pi/RMAX
            rb[k] = __sinf(fk * safe_r) * pref;
        }
        uint4 v0, v1;
        v0.x = pack2bf(rb[0], rb[1]); v0.y = pack2bf(rb[2], rb[3]);
        v0.z = pack2bf(rb[4], rb[5]); v0.w = pack2bf(rb[6], rb[7]);
        v1.x = 0x3F80u; v1.y = 0u; v1.z = 0u; v1.w = 0u;  // k=8 -> 1.0 (bias), k=9..11 -> 0
        uint4 vz4 = {0u, 0u, 0u, 0u};
        *(uint4*)&rbA[tid * RBSTR + 0] = v0;
        *(uint4*)&rbA[tid * RBSTR + 8] = v1;
        *(uint4*)&rbA[tid * RBSTR + 16] = vz4;
        *(uint4*)&rbA[tid * RBSTR + 24] = vz4;
    }

    // ---- segment-head ballot (needs rcv_s of tid-1: same-wave ok for lane>0; cross-wave
    //      boundary tid=64 reads tid=63 -> needs barrier first)
    __syncthreads();
    {
        const bool head = (tid == 0) || (rcv_s[tid] != rcv_s[tid - 1]);
        const unsigned long long bal = __ballot(head);
        if ((tid & 63) == 0) bal_s[tid >> 6] = bal;
    }

    // ---- layer 1: [64e x (8+bias)] @ W1T -> acc1 via MFMA (K=32 padded)
    f32x4 acc1[4][4];
#pragma unroll
    for (int mt = 0; mt < 4; ++mt)
#pragma unroll
        for (int nt = 0; nt < 4; ++nt) acc1[mt][nt] = (f32x4){0.f, 0.f, 0.f, 0.f};
    {
        bf16x8 a1[4], b1[4];
#pragma unroll
        for (int mt = 0; mt < 4; ++mt)
            a1[mt] = *(const bf16x8*)&rbA[(w * 64 + mt * 16 + lnlo) * RBSTR + q4 * 8];
#pragma unroll
        for (int nt = 0; nt < 4; ++nt)
            b1[nt] = *(const bf16x8*)&W1T[(nt * 16 + lnlo) * 32 + q4 * 8];
        __syncthreads();  // all rbA frag reads issued & consumed before act overwrite
#pragma unroll
        for (int mt = 0; mt < 4; ++mt)
#pragma unroll
            for (int nt = 0; nt < 4; ++nt)
                acc1[mt][nt] = __builtin_amdgcn_mfma_f32_16x16x32_bf16(
                    a1[mt], b1[nt], acc1[mt][nt], 0, 0, 0);
    }

    // ---- silu(acc1) -> act1 (h1), fragment layout row=q4*4+rr col=nt*16+lnlo
#pragma unroll
    for (int mt = 0; mt < 4; ++mt)
#pragma unroll
        for (int nt = 0; nt < 4; ++nt)
#pragma unroll
            for (int rr = 0; rr < 4; ++rr) {
                const float x = acc1[mt][nt][rr];
                act[(w * 64 + mt * 16 + q4 * 4 + rr) * ASTR + nt * 16 + lnlo] =
                    __float2bfloat16(x / (1.f + __expf(-x)));
            }
    __syncthreads();

    // ---- layer 2: [64e x 64] @ W2T -> acc2, MFMA 16x16x32
    f32x4 acc2[4][4];
#pragma unroll
    for (int mt = 0; mt < 4; ++mt)
#pragma unroll
        for (int nt = 0; nt < 4; ++nt) acc2[mt][nt] = (f32x4){0.f, 0.f, 0.f, 0.f};
    {
        bf16x8 a2[4][2], b2[4][2];
#pragma unroll
        for (int mt = 0; mt < 4; ++mt)
#pragma unroll
            for (int kk = 0; kk < 2; ++kk)
                a2[mt][kk] = *(const bf16x8*)&act[(w * 64 + mt * 16 + lnlo) * ASTR + kk * 32 + q4 * 8];
#pragma unroll
        for (int nt = 0; nt < 4; ++nt)
#pragma unroll
            for (int kk = 0; kk < 2; ++kk)
                b2[nt][kk] = *(const bf16x8*)&W2T[(nt * 16 + lnlo) * 64 + kk * 32 + q4 * 8];
#pragma unroll
        for (int kk = 0; kk < 2; ++kk)
#pragma unroll
            for (int mt = 0; mt < 4; ++mt)
#pragma unroll
                for (int nt = 0; nt < 4; ++nt)
                    acc2[mt][nt] = __builtin_amdgcn_mfma_f32_16x16x32_bf16(
                        a2[mt][kk], b2[nt][kk], acc2[mt][nt], 0, 0, 0);
    }
    __syncthreads();  // all act1 reads complete

    // ---- silu(acc2) -> act2 (same buffer)
#pragma unroll
    for (int mt = 0; mt < 4; ++mt)
#pragma unroll
        for (int nt = 0; nt < 4; ++nt)
#pragma unroll
            for (int rr = 0; rr < 4; ++rr) {
                const float x = acc2[mt][nt][rr];
                act[(w * 64 + mt * 16 + q4 * 4 + rr) * ASTR + nt * 16 + lnlo] =
                    __float2bfloat16(x / (1.f + __expf(-x)));
            }
    __syncthreads();

    // ---- layer 3: [64e x 64] @ W3T (96 cols) -> acc3
    f32x4 acc3[4][6];
#pragma unroll
    for (int mt = 0; mt < 4; ++mt)
#pragma unroll
        for (int nt = 0; nt < 6; ++nt) acc3[mt][nt] = (f32x4){0.f, 0.f, 0.f, 0.f};
    {
        bf16x8 a3[4][2], b3[6][2];
#pragma unroll
        for (int mt = 0; mt < 4; ++mt)
#pragma unroll
            for (int kk = 0; kk < 2; ++kk)
                a3[mt][kk] = *(const bf16x8*)&act[(w * 64 + mt * 16 + lnlo) * ASTR + kk * 32 + q4 * 8];
#pragma unroll
        for (int nt = 0; nt < 6; ++nt)
#pragma unroll
            for (int kk = 0; kk < 2; ++kk)
                b3[nt][kk] = *(const bf16x8*)&W3T[(nt * 16 + lnlo) * 64 + kk * 32 + q4 * 8];
#pragma unroll
        for (int kk = 0; kk < 2; ++kk)
#pragma unroll
            for (int mt = 0; mt < 4; ++mt)
#pragma unroll
                for (int nt = 0; nt < 6; ++nt)
                    acc3[mt][nt] = __builtin_amdgcn_mfma_f32_16x16x32_bf16(
                        a3[mt][kk], b3[nt][kk], acc3[mt][nt], 0, 0, 0);
    }
    __syncthreads();  // act fully dead (Gt overlays it)

    // ---- preload sender species for the 16 rows this lane owns
    int sp_r[4][4];
#pragma unroll
    for (int mt = 0; mt < 4; ++mt)
#pragma unroll
        for (int rr = 0; rr < 4; ++rr)
            sp_r[mt][rr] = (int)spec_s[w * 64 + mt * 16 + q4 * 4 + rr];

    // ---- two column-halves: Gt store + segmented reduce
    pass_store_reduce<0>(acc3, sp_r, Gt, Yt, WembLds, rcv_s, bal_s, A, tid, w, lnlo, q4);
    pass_store_reduce<1>(acc3, sp_r, Gt, Yt, WembLds, rcv_s, bal_s, A, tid, w, lnlo, q4);
}

// ---------------- node kernel: A -> A2 -> B -> node_e (plain store) ----------------
__global__ __launch_bounds__(256) void node_kernel(
    const float* __restrict__ A, const float* __restrict__ Wmix,
    const float* __restrict__ wquad, const float* __restrict__ Wread,
    const float* __restrict__ attrs, const float* __restrict__ ae,
    float* __restrict__ node_e) {
    __shared__ float Ald[8][CC * 9];
    const int t = threadIdx.x;
    const int ln = t >> 5;
    const int d = t & 31;
    const int n = blockIdx.x * 8 + ln;

    const float* Arow = A + (size_t)n * (CC * 9);
#pragma unroll
    for (int i = 0; i < 9; ++i) Ald[ln][d + 32 * i] = Arow[d + 32 * i] * (1.f / 16.f);
    __syncthreads();

    float A2[9];
#pragma unroll
    for (int m = 0; m < 9; ++m) {
        const int l = (m == 0) ? 0 : ((m < 4) ? 1 : 2);
        float acc = 0.f;
#pragma unroll
        for (int cch = 0; cch < CC; ++cch)
            acc = fmaf(Wmix[(l * CC + cch) * CC + d], Ald[ln][cch * 9 + m], acc);
        A2[m] = acc;
    }

    const float q0 = wquad[0], q1 = wquad[1], q2 = wquad[2];
    const float n0 = A2[0] * A2[0];
    const float n1 = A2[1] * A2[1] + A2[2] * A2[2] + A2[3] * A2[3];
    const float n2 = A2[4] * A2[4] + A2[5] * A2[5] + A2[6] * A2[6] + A2[7] * A2[7] + A2[8] * A2[8];
    const float B = A2[0] + n0 * q0 + n1 * q1 + n2 * q2;

    float v = B * Wread[d];
#pragma unroll
    for (int off = 16; off; off >>= 1) v += __shfl_xor(v, off, 32);

    if (d == 0) {
        float ne = v;
#pragma unroll
        for (int s = 0; s < NSPEC; ++s) ne += attrs[n * NSPEC + s] * ae[s];
        node_e[n] = ne;
    }
}

// ---------------- reduce: per-graph segment sum over sorted batch ----------------
__global__ __launch_bounds__(256) void reduce_kernel(const float* __restrict__ node_e,
                                                     const int* __restrict__ batch,
                                                     float* __restrict__ out) {
    __shared__ float part[4];
    const int g = blockIdx.x;
    int lo = 0, hi = NNODES;
    while (lo < hi) { int mid = (lo + hi) >> 1; if (batch[mid] < g) lo = mid + 1; else hi = mid; }
    const int start = lo;
    int lo2 = start, hi2 = NNODES;
    while (lo2 < hi2) { int mid = (lo2 + hi2) >> 1; if (batch[mid] < g + 1) lo2 = mid + 1; else hi2 = mid; }
    const int end = lo2;

    float s = 0.f;
    for (int i = start + (int)threadIdx.x; i < end; i += 256) s += node_e[i];
#pragma unroll
    for (int off = 32; off; off >>= 1) s += __shfl_xor(s, off, 64);
    if ((threadIdx.x & 63) == 0) part[threadIdx.x >> 6] = s;
    __syncthreads();
    if (threadIdx.x == 0) out[g] = part[0] + part[1] + part[2] + part[3];
}

extern "C" void kernel_launch(void* const* d_in, const int* in_sizes, int n_in,
                              void* d_out, int out_size, void* d_ws, size_t ws_size,
                              hipStream_t stream) {
    const float* attrs  = (const float*)d_in[0];
    const float* pos    = (const float*)d_in[1];
    const float* shifts = (const float*)d_in[2];
    const float* Wemb   = (const float*)d_in[3];
    const float* rW1    = (const float*)d_in[4];
    const float* rb1    = (const float*)d_in[5];
    const float* rW2    = (const float*)d_in[6];
    const float* rb2    = (const float*)d_in[7];
    const float* rW3    = (const float*)d_in[8];
    const float* Wmix   = (const float*)d_in[9];
    const float* wquad  = (const float*)d_in[10];
    const float* Wread  = (const float*)d_in[11];
    const float* ae     = (const float*)d_in[12];
    const int* eidx     = (const int*)d_in[13];
    const int* batch    = (const int*)d_in[14];
    float* out = (float*)d_out;
    (void)rb2;

    // workspace layout; ~62.5 MB
    char* wsp = (char*)d_ws;
    float* A      = (float*)wsp;  wsp += (size_t)NNODES * CC * 9 * 4;  // 57.6 MB
    int* perm     = (int*)wsp;    wsp += (size_t)NEDGES * 4;           // 3.2 MB
    int* offsets  = (int*)wsp;    wsp += (size_t)SCAN_N * 4;
    int* counts   = (int*)wsp;    wsp += (size_t)SCAN_N * 4;           // memset w/ cursor
    int* cursor   = (int*)wsp;    wsp += (size_t)SCAN_N * 4;
    int* species  = (int*)wsp;    wsp += (size_t)NNODES * 4;
    float* node_e = (float*)wsp;  wsp += (size_t)NNODES * 4;
    __hip_bfloat16* W1T = (__hip_bfloat16*)wsp; wsp += 64 * 32 * 2;    // 4 KB
    __hip_bfloat16* W2T = (__hip_bfloat16*)wsp; wsp += 64 * 64 * 2;    // 8 KB
    __hip_bfloat16* W3T = (__hip_bfloat16*)wsp; wsp += 96 * 64 * 2;    // 12 KB

    hipMemsetAsync(A, 0, (size_t)NNODES * CC * 9 * sizeof(float), stream);
    hipMemsetAsync(counts, 0, (size_t)SCAN_N * 2 * sizeof(int), stream);  // counts+cursor

    prep_hist_kernel<<<NEDGES / 256, 256, 0, stream>>>(attrs, eidx, rW1, rb1, rW2, rW3,
                                                       counts, species, W1T, W2T, W3T);
    scan_kernel<<<1, 1024, 0, stream>>>(counts, offsets);
    scatter_kernel<<<NEDGES / 256, 256, 0, stream>>>(eidx, offsets, cursor, perm);

    edge_kernel<<<NCHUNK, EBLK, 0, stream>>>(pos, shifts, eidx, perm,
                                             W1T, W2T, W3T, species, Wemb, A);
    node_kernel<<<NNODES / 8, 256, 0, stream>>>(A, Wmix, wquad, Wread, attrs, ae, node_e);
    reduce_kernel<<<NGRAPHS, 256, 0, stream>>>(node_e, batch, out);
}

// Round 10
// 321.084 us; speedup vs baseline: 46.0663x; 1.0586x over previous
//
#include <hip/hip_runtime.h>
#include <hip/hip_bf16.h>

#define NNODES 50000
#define NEDGES 800000
#define NGRAPHS 32
#define NSPEC 10
#define CC 32
#define RH 64
#define NB 8

#define EBLK 128
#define NCHUNK (NEDGES / EBLK)
#define GSTR 136   // Gt row stride (shorts); 272B rows -> 16B-aligned uint4 reads
#define YSTRF 132  // Yt row stride (floats); 528B rows, 16B-aligned float4 reads
#define ASTR 72    // act row stride in shorts (144B, 16B aligned)
#define RBSTR 40   // rbA row stride in shorts (80B, 16B aligned)
#define SCAN_N 53248  // 1024*52 padded scan domain

typedef __bf16 bf16x8 __attribute__((ext_vector_type(8)));
typedef float f32x4 __attribute__((ext_vector_type(4)));

__device__ __forceinline__ unsigned pack2bf(float a, float b) {
    return (unsigned)__bfloat16_as_ushort(__float2bfloat16(a)) |
           ((unsigned)__bfloat16_as_ushort(__float2bfloat16(b)) << 16);
}

// ---------------- fused prelude: histogram(+rank) + species + weight transpose ----------------
__global__ __launch_bounds__(256) void prep_hist_kernel(
    const float* __restrict__ attrs, const int* __restrict__ eidx,
    const float* __restrict__ rW1, const float* __restrict__ rb1,
    const float* __restrict__ rW2, const float* __restrict__ rW3,
    int* __restrict__ counts, int* __restrict__ rank, int* __restrict__ species,
    __hip_bfloat16* __restrict__ W1T, __hip_bfloat16* __restrict__ W2T,
    __hip_bfloat16* __restrict__ W3T) {
    int g = blockIdx.x * 256 + threadIdx.x;
    if (g < NEDGES) rank[g] = atomicAdd(&counts[eidx[NEDGES + g]], 1);
    if (g < NNODES) {
        float acc = 0.f;
#pragma unroll
        for (int s = 0; s < NSPEC; ++s) acc += attrs[g * NSPEC + s] * (float)s;
        species[g] = (int)(acc + 0.5f);
    }
    if (g < 64 * 32) {  // W1T[col][k]: k<8 = rW1[k][col], k==8 = rb1[col], else 0
        int c = g >> 5, k = g & 31;
        float v = (k < 8) ? rW1[k * 64 + c] : ((k == 8) ? rb1[c] : 0.f);
        W1T[g] = __float2bfloat16(v);
    }
    if (g < 64 * 64) {
        int c = g >> 6, k = g & 63;
        W2T[g] = __float2bfloat16(rW2[k * 64 + c]);
    }
    if (g < 96 * 64) {
        int c = g >> 6, k = g & 63;
        W3T[g] = __float2bfloat16(rW3[k * 96 + c]);
    }
}

// ---------------- scan: single block, int4, CH=52 ----------------
__global__ __launch_bounds__(1024) void scan_kernel(const int* __restrict__ counts,
                                                    int* __restrict__ offsets) {
    __shared__ int sums[1024];
    const int t = threadIdx.x;
    const int base = t * 52;
    int loc[52];
    int s = 0;
#pragma unroll
    for (int i = 0; i < 13; ++i) {
        int4 v = *(const int4*)&counts[base + i * 4];
        loc[i * 4 + 0] = v.x; loc[i * 4 + 1] = v.y;
        loc[i * 4 + 2] = v.z; loc[i * 4 + 3] = v.w;
        s += v.x + v.y + v.z + v.w;
    }
    sums[t] = s;
    __syncthreads();
    for (int off = 1; off < 1024; off <<= 1) {
        int add = (t >= off) ? sums[t - off] : 0;
        __syncthreads();
        sums[t] += add;
        __syncthreads();
    }
    int run = sums[t] - s;
#pragma unroll
    for (int i = 0; i < 13; ++i) {
        int4 o;
        o.x = run; run += loc[i * 4 + 0];
        o.y = run; run += loc[i * 4 + 1];
        o.z = run; run += loc[i * 4 + 2];
        o.w = run; run += loc[i * 4 + 3];
        *(int4*)&offsets[base + i * 4] = o;
    }
}

// ---------------- scatter: atomic-free (uses precomputed rank) ----------------
__global__ __launch_bounds__(256) void scatter_kernel(const int* __restrict__ eidx,
                                                      const int* __restrict__ offsets,
                                                      const int* __restrict__ rank,
                                                      int* __restrict__ perm) {
    int e = blockIdx.x * 256 + threadIdx.x;
    if (e >= NEDGES) return;
    int rcv = eidx[NEDGES + e];
    perm[offsets[rcv] + rank[e]] = e;
}

// ---------------- segment flush helper ----------------
__device__ __forceinline__ void flushseg(float* __restrict__ A, int node, int cur,
                                         int nseg, int cbase, int j, float aj, float a8) {
    float* Ap = A + (size_t)node * (CC * 9) + cbase * 9;
    if (cur == 0 || cur == nseg - 1) {
        atomicAdd(Ap + j, aj);
        if (j == 0) atomicAdd(Ap + 8, a8);
    } else {
        Ap[j] = aj;
        if (j == 0) Ap[8] = a8;
    }
}

// ---------------- phase-2 + Gt-store (templated on column half P) ----------------
template <int P>
__device__ __forceinline__ void pass_store_reduce(
    const f32x4 (&acc3)[4][6], const int (&sp_r)[4][4],
    __hip_bfloat16* Gt, const float* Yt, const float* WembLds,
    const unsigned short* rcv_s, const unsigned long long* bal_s,
    float* __restrict__ A, int tid, int w, int lnlo, int q4) {
    // ---- store Gt[s][e] = R * h_sender, packed 4-wide along e (rr=0..3)
#pragma unroll
    for (int nti = 0; nti < 3; ++nti) {
        const int nt = P * 3 + nti;
        const int col = nt * 16 + lnlo;
        const int cch = col / 3;           // channel 0..31
        const int s = nti * 16 + lnlo;     // 0..47 within half
#pragma unroll
        for (int mt = 0; mt < 4; ++mt) {
            const float f0 = acc3[mt][nt][0] * WembLds[sp_r[mt][0] * 32 + cch];
            const float f1 = acc3[mt][nt][1] * WembLds[sp_r[mt][1] * 32 + cch];
            const float f2 = acc3[mt][nt][2] * WembLds[sp_r[mt][2] * 32 + cch];
            const float f3 = acc3[mt][nt][3] * WembLds[sp_r[mt][3] * 32 + cch];
            uint2 pk;
            pk.x = pack2bf(f0, f1);
            pk.y = pack2bf(f2, f3);
            *(uint2*)&Gt[s * GSTR + w * 64 + mt * 16 + q4 * 4] = pk;
        }
    }
    __syncthreads();

    // ---- segmented reduce, vectorized 8-wide; thread = (c, j); Y in f32 (no unpack)
    {
        const int c = tid >> 3;
        const int j = tid & 7;
        const int l_j = (j == 0) ? 0 : ((j < 4) ? 1 : 2);
        const uint4* gj = (const uint4*)(Gt + (3 * c + l_j) * GSTR);
        const uint4* g8 = (const uint4*)(Gt + (3 * c + 2) * GSTR);
        const float4* yj = (const float4*)(Yt + j * YSTRF);
        const float4* y8f = (const float4*)(Yt + 8 * YSTRF);
        const unsigned long long b0 = bal_s[0], b1 = bal_s[1];
        const int nseg = __popcll(b0) + __popcll(b1);
        const int cbase = P * 16 + c;

        float aj = 0.f, a8 = 0.f;
        int cur = 0;
        int node = rcv_s[0];

        for (int ch = 0; ch < 16; ++ch) {
            unsigned msk = (unsigned)(((ch < 8) ? (b0 >> (ch * 8)) : (b1 >> ((ch - 8) * 8))) & 0xffull);
            if (ch == 0) msk &= ~1u;
            const uint4 gv = gj[ch];
            const float4 ya = yj[2 * ch];
            const float4 yb = yj[2 * ch + 1];
            uint4 gv8 = {0, 0, 0, 0};
            float4 y8a = {0.f, 0.f, 0.f, 0.f}, y8b = {0.f, 0.f, 0.f, 0.f};
            if (j == 0) { gv8 = g8[ch]; y8a = y8f[2 * ch]; y8b = y8f[2 * ch + 1]; }
            const unsigned gw[4] = {gv.x, gv.y, gv.z, gv.w};
            const unsigned gw8[4] = {gv8.x, gv8.y, gv8.z, gv8.w};
            const float yf[8] = {ya.x, ya.y, ya.z, ya.w, yb.x, yb.y, yb.z, yb.w};
            const float yf8[8] = {y8a.x, y8a.y, y8a.z, y8a.w, y8b.x, y8b.y, y8b.z, y8b.w};
#pragma unroll
            for (int i = 0; i < 8; ++i) {
                if (msk & (1u << i)) {
                    flushseg(A, node, cur, nseg, cbase, j, aj, a8);
                    aj = 0.f; a8 = 0.f; ++cur;
                    node = rcv_s[ch * 8 + i];
                }
                const unsigned gu = gw[i >> 1];
                const float gf = __uint_as_float((i & 1) ? (gu & 0xffff0000u) : (gu << 16));
                aj = fmaf(gf, yf[i], aj);
                if (j == 0) {
                    const unsigned hu = gw8[i >> 1];
                    const float hf = __uint_as_float((i & 1) ? (hu & 0xffff0000u) : (hu << 16));
                    a8 = fmaf(hf, yf8[i], a8);
                }
            }
        }
        flushseg(A, node, cur, nseg, cbase, j, aj, a8);
    }
    __syncthreads();  // protect Gt before next pass overwrites
}

// ---------------- edge kernel: full-MFMA MLP + segmented scatter ----------------
__global__ __launch_bounds__(EBLK, 3) void edge_kernel(
    const float* __restrict__ pos, const float* __restrict__ shifts,
    const int* __restrict__ eidx, const int* __restrict__ perm,
    const __hip_bfloat16* __restrict__ W1T, const __hip_bfloat16* __restrict__ W2T,
    const __hip_bfloat16* __restrict__ W3T, const float* __restrict__ rb2,
    const int* __restrict__ species, const float* __restrict__ Wemb,
    float* __restrict__ A) {
    // union: act (128x72 shorts) overlays Gt (48x136) and rbA (128x40)
    __shared__ __align__(16) short smem_u[128 * ASTR];
    __shared__ __align__(16) float Yt[9 * YSTRF];
    __shared__ float WembLds[NSPEC * CC];
    __shared__ float rb2L[RH];
    __shared__ unsigned short rcv_s[EBLK];
    __shared__ unsigned char spec_s[EBLK];
    __shared__ unsigned long long bal_s[2];

    __hip_bfloat16* act = (__hip_bfloat16*)smem_u;
    __hip_bfloat16* Gt = (__hip_bfloat16*)smem_u;
    __hip_bfloat16* rbA = (__hip_bfloat16*)smem_u;

    const int tid = threadIdx.x;
    const int lane = tid & 63;
    const int w = tid >> 6;
    const int lnlo = lane & 15;
    const int q4 = lane >> 4;

    const int slot = blockIdx.x * EBLK + tid;
    const int eid = perm[slot];
    const int snd = eidx[eid];
    const int rcv = eidx[NEDGES + eid];

    const float vx = pos[rcv * 3 + 0] - pos[snd * 3 + 0] + shifts[eid * 3 + 0];
    const float vy = pos[rcv * 3 + 1] - pos[snd * 3 + 1] + shifts[eid * 3 + 1];
    const float vz = pos[rcv * 3 + 2] - pos[snd * 3 + 2] + shifts[eid * 3 + 2];
    const float r = sqrtf(vx * vx + vy * vy + vz * vz);
    const float safe_r = fmaxf(r, 1e-9f);
    const float rinv = 1.f / safe_r;
    const float ux = vx * rinv, uy = vy * rinv, uz = vz * rinv;

    // ---- spherical harmonics (f32) + metadata -> LDS
    {
        const float s3 = 1.7320508075688772f;
        const float s15 = 3.872983346207417f;
        const float s15h = 1.9364916731037085f;
        const float s5h = 1.118033988749895f;
        Yt[0 * YSTRF + tid] = 1.f;
        Yt[1 * YSTRF + tid] = s3 * ux;
        Yt[2 * YSTRF + tid] = s3 * uy;
        Yt[3 * YSTRF + tid] = s3 * uz;
        Yt[4 * YSTRF + tid] = s15 * ux * uy;
        Yt[5 * YSTRF + tid] = s15 * uy * uz;
        Yt[6 * YSTRF + tid] = s5h * (3.f * uz * uz - 1.f);
        Yt[7 * YSTRF + tid] = s15 * ux * uz;
        Yt[8 * YSTRF + tid] = s15h * (ux * ux - uy * uy);
        rcv_s[tid] = (unsigned short)rcv;
        spec_s[tid] = (unsigned char)species[snd];
        for (int i = tid; i < NSPEC * CC; i += EBLK) WembLds[i] = Wemb[i];
        if (tid < RH) rb2L[tid] = rb2[tid];
    }

    // ---- radial basis -> rbA row (own wave's rows)
    {
        const float u = r * 0.2f;
        const float u2 = u * u;
        const float u6 = u2 * u2 * u2;
        const float u7 = u6 * u;
        const float u8v = u7 * u;
        float fcut = 1.f - 28.f * u6 + 48.f * u7 - 21.f * u8v;
        fcut = (u < 1.f) ? fcut : 0.f;
        const float pref = 0.632455532f * rinv * fcut;
        float rb[NB];
#pragma unroll
        for (int k = 0; k < NB; ++k) {
            const float fk = (float)(k + 1) * 0.628318530718f;  // n*pi/RMAX
            rb[k] = __sinf(fk * safe_r) * pref;
        }
        uint4 v0, v1;
        v0.x = pack2bf(rb[0], rb[1]); v0.y = pack2bf(rb[2], rb[3]);
        v0.z = pack2bf(rb[4], rb[5]); v0.w = pack2bf(rb[6], rb[7]);
        v1.x = 0x3F80u; v1.y = 0u; v1.z = 0u; v1.w = 0u;  // k=8 -> 1.0 (bias row)
        uint4 vz4 = {0u, 0u, 0u, 0u};
        *(uint4*)&rbA[tid * RBSTR + 0] = v0;
        *(uint4*)&rbA[tid * RBSTR + 8] = v1;
        *(uint4*)&rbA[tid * RBSTR + 16] = vz4;
        *(uint4*)&rbA[tid * RBSTR + 24] = vz4;
    }

    __syncthreads();  // rcv_s visible cross-wave
    {
        const bool head = (tid == 0) || (rcv_s[tid] != rcv_s[tid - 1]);
        const unsigned long long bal = __ballot(head);
        if ((tid & 63) == 0) bal_s[tid >> 6] = bal;
    }

    // ---- layer 1: [64e x (8+bias)] @ W1T -> acc1 via MFMA (K=32 padded)
    f32x4 acc1[4][4];
#pragma unroll
    for (int mt = 0; mt < 4; ++mt)
#pragma unroll
        for (int nt = 0; nt < 4; ++nt) acc1[mt][nt] = (f32x4){0.f, 0.f, 0.f, 0.f};
    {
        bf16x8 a1[4], b1[4];
#pragma unroll
        for (int mt = 0; mt < 4; ++mt)
            a1[mt] = *(const bf16x8*)&rbA[(w * 64 + mt * 16 + lnlo) * RBSTR + q4 * 8];
#pragma unroll
        for (int nt = 0; nt < 4; ++nt)
            b1[nt] = *(const bf16x8*)&W1T[(nt * 16 + lnlo) * 32 + q4 * 8];
        __syncthreads();  // rbA consumed before act overwrite
#pragma unroll
        for (int mt = 0; mt < 4; ++mt)
#pragma unroll
            for (int nt = 0; nt < 4; ++nt)
                acc1[mt][nt] = __builtin_amdgcn_mfma_f32_16x16x32_bf16(
                    a1[mt], b1[nt], acc1[mt][nt], 0, 0, 0);
    }

    // ---- silu(acc1) -> act1 (h1)
#pragma unroll
    for (int mt = 0; mt < 4; ++mt)
#pragma unroll
        for (int nt = 0; nt < 4; ++nt)
#pragma unroll
            for (int rr = 0; rr < 4; ++rr) {
                const float x = acc1[mt][nt][rr];
                act[(w * 64 + mt * 16 + q4 * 4 + rr) * ASTR + nt * 16 + lnlo] =
                    __float2bfloat16(x / (1.f + __expf(-x)));
            }
    __syncthreads();

    // ---- layer 2: [64e x 64] @ W2T -> acc2
    f32x4 acc2[4][4];
#pragma unroll
    for (int mt = 0; mt < 4; ++mt)
#pragma unroll
        for (int nt = 0; nt < 4; ++nt) acc2[mt][nt] = (f32x4){0.f, 0.f, 0.f, 0.f};
    {
        bf16x8 a2[4][2], b2[4][2];
#pragma unroll
        for (int mt = 0; mt < 4; ++mt)
#pragma unroll
            for (int kk = 0; kk < 2; ++kk)
                a2[mt][kk] = *(const bf16x8*)&act[(w * 64 + mt * 16 + lnlo) * ASTR + kk * 32 + q4 * 8];
#pragma unroll
        for (int nt = 0; nt < 4; ++nt)
#pragma unroll
            for (int kk = 0; kk < 2; ++kk)
                b2[nt][kk] = *(const bf16x8*)&W2T[(nt * 16 + lnlo) * 64 + kk * 32 + q4 * 8];
#pragma unroll
        for (int kk = 0; kk < 2; ++kk)
#pragma unroll
            for (int mt = 0; mt < 4; ++mt)
#pragma unroll
                for (int nt = 0; nt < 4; ++nt)
                    acc2[mt][nt] = __builtin_amdgcn_mfma_f32_16x16x32_bf16(
                        a2[mt][kk], b2[nt][kk], acc2[mt][nt], 0, 0, 0);
    }
    __syncthreads();  // all act1 reads complete

    // ---- silu(acc2 + rb2) -> act2
#pragma unroll
    for (int mt = 0; mt < 4; ++mt)
#pragma unroll
        for (int nt = 0; nt < 4; ++nt) {
            const float bias = rb2L[nt * 16 + lnlo];
#pragma unroll
            for (int rr = 0; rr < 4; ++rr) {
                const float x = acc2[mt][nt][rr] + bias;
                act[(w * 64 + mt * 16 + q4 * 4 + rr) * ASTR + nt * 16 + lnlo] =
                    __float2bfloat16(x / (1.f + __expf(-x)));
            }
        }
    __syncthreads();

    // ---- layer 3: [64e x 64] @ W3T (96 cols) -> acc3
    f32x4 acc3[4][6];
#pragma unroll
    for (int mt = 0; mt < 4; ++mt)
#pragma unroll
        for (int nt = 0; nt < 6; ++nt) acc3[mt][nt] = (f32x4){0.f, 0.f, 0.f, 0.f};
    {
        bf16x8 a3[4][2], b3[6][2];
#pragma unroll
        for (int mt = 0; mt < 4; ++mt)
#pragma unroll
            for (int kk = 0; kk < 2; ++kk)
                a3[mt][kk] = *(const bf16x8*)&act[(w * 64 + mt * 16 + lnlo) * ASTR + kk * 32 + q4 * 8];
#pragma unroll
        for (int nt = 0; nt < 6; ++nt)
#pragma unroll
            for (int kk = 0; kk < 2; ++kk)
                b3[nt][kk] = *(const bf16x8*)&W3T[(nt * 16 + lnlo) * 64 + kk * 32 + q4 * 8];
#pragma unroll
        for (int kk = 0; kk < 2; ++kk)
#pragma unroll
            for (int mt = 0; mt < 4; ++mt)
#pragma unroll
                for (int nt = 0; nt < 6; ++nt)
                    acc3[mt][nt] = __builtin_amdgcn_mfma_f32_16x16x32_bf16(
                        a3[mt][kk], b3[nt][kk], acc3[mt][nt], 0, 0, 0);
    }
    __syncthreads();  // act dead (Gt overlays it)

    // ---- preload sender species for the 16 rows this lane owns
    int sp_r[4][4];
#pragma unroll
    for (int mt = 0; mt < 4; ++mt)
#pragma unroll
        for (int rr = 0; rr < 4; ++rr)
            sp_r[mt][rr] = (int)spec_s[w * 64 + mt * 16 + q4 * 4 + rr];

    // ---- two column-halves: Gt store + segmented reduce
    pass_store_reduce<0>(acc3, sp_r, Gt, Yt, WembLds, rcv_s, bal_s, A, tid, w, lnlo, q4);
    pass_store_reduce<1>(acc3, sp_r, Gt, Yt, WembLds, rcv_s, bal_s, A, tid, w, lnlo, q4);
}

// ---------------- node kernel: A -> A2 -> B -> node_e, fused per-graph reduce ----------------
__global__ __launch_bounds__(256) void node_kernel(
    const float* __restrict__ A, const float* __restrict__ Wmix,
    const float* __restrict__ wquad, const float* __restrict__ Wread,
    const float* __restrict__ attrs, const float* __restrict__ ae,
    const int* __restrict__ batch, float* __restrict__ out) {
    __shared__ float Ald[8][CC * 9];
    __shared__ float ne_s[8];
    __shared__ int g_s[8];
    const int t = threadIdx.x;
    const int ln = t >> 5;
    const int d = t & 31;
    const int n = blockIdx.x * 8 + ln;

    const float* Arow = A + (size_t)n * (CC * 9);
#pragma unroll
    for (int i = 0; i < 9; ++i) Ald[ln][d + 32 * i] = Arow[d + 32 * i] * (1.f / 16.f);
    __syncthreads();

    float A2[9];
#pragma unroll
    for (int m = 0; m < 9; ++m) {
        const int l = (m == 0) ? 0 : ((m < 4) ? 1 : 2);
        float acc = 0.f;
#pragma unroll
        for (int cch = 0; cch < CC; ++cch)
            acc = fmaf(Wmix[(l * CC + cch) * CC + d], Ald[ln][cch * 9 + m], acc);
        A2[m] = acc;
    }

    const float q0 = wquad[0], q1 = wquad[1], q2 = wquad[2];
    const float n0 = A2[0] * A2[0];
    const float n1 = A2[1] * A2[1] + A2[2] * A2[2] + A2[3] * A2[3];
    const float n2 = A2[4] * A2[4] + A2[5] * A2[5] + A2[6] * A2[6] + A2[7] * A2[7] + A2[8] * A2[8];
    const float B = A2[0] + n0 * q0 + n1 * q1 + n2 * q2;

    float v = B * Wread[d];
#pragma unroll
    for (int off = 16; off; off >>= 1) v += __shfl_xor(v, off, 32);

    if (d == 0) {
        float ne = v;
#pragma unroll
        for (int s = 0; s < NSPEC; ++s) ne += attrs[n * NSPEC + s] * ae[s];
        ne_s[ln] = ne;
        g_s[ln] = batch[n];
    }
    __syncthreads();
    if (t == 0) {  // batch sorted -> g_s nondecreasing; merge runs, 1-2 atomics/block
        float acc = ne_s[0];
        int g = g_s[0];
#pragma unroll
        for (int i = 1; i < 8; ++i) {
            if (g_s[i] == g) acc += ne_s[i];
            else { atomicAdd(&out[g], acc); g = g_s[i]; acc = ne_s[i]; }
        }
        atomicAdd(&out[g], acc);
    }
}

extern "C" void kernel_launch(void* const* d_in, const int* in_sizes, int n_in,
                              void* d_out, int out_size, void* d_ws, size_t ws_size,
                              hipStream_t stream) {
    const float* attrs  = (const float*)d_in[0];
    const float* pos    = (const float*)d_in[1];
    const float* shifts = (const float*)d_in[2];
    const float* Wemb   = (const float*)d_in[3];
    const float* rW1    = (const float*)d_in[4];
    const float* rb1    = (const float*)d_in[5];
    const float* rW2    = (const float*)d_in[6];
    const float* rb2    = (const float*)d_in[7];
    const float* rW3    = (const float*)d_in[8];
    const float* Wmix   = (const float*)d_in[9];
    const float* wquad  = (const float*)d_in[10];
    const float* Wread  = (const float*)d_in[11];
    const float* ae     = (const float*)d_in[12];
    const int* eidx     = (const int*)d_in[13];
    const int* batch    = (const int*)d_in[14];
    float* out = (float*)d_out;

    // workspace layout; ~61.5 MB. rank aliases A (A is memset AFTER scatter).
    char* wsp = (char*)d_ws;
    float* A      = (float*)wsp;  wsp += (size_t)NNODES * CC * 9 * 4;  // 57.6 MB
    int* rank     = (int*)A;                                           // alias (dead before memset A)
    int* perm     = (int*)wsp;    wsp += (size_t)NEDGES * 4;           // 3.2 MB
    int* offsets  = (int*)wsp;    wsp += (size_t)SCAN_N * 4;
    int* counts   = (int*)wsp;    wsp += (size_t)SCAN_N * 4;
    int* species  = (int*)wsp;    wsp += (size_t)NNODES * 4;
    __hip_bfloat16* W1T = (__hip_bfloat16*)wsp; wsp += 64 * 32 * 2;
    __hip_bfloat16* W2T = (__hip_bfloat16*)wsp; wsp += 64 * 64 * 2;
    __hip_bfloat16* W3T = (__hip_bfloat16*)wsp; wsp += 96 * 64 * 2;

    hipMemsetAsync(counts, 0, (size_t)SCAN_N * sizeof(int), stream);
    hipMemsetAsync(out, 0, NGRAPHS * sizeof(float), stream);

    prep_hist_kernel<<<NEDGES / 256, 256, 0, stream>>>(attrs, eidx, rW1, rb1, rW2, rW3,
                                                       counts, rank, species, W1T, W2T, W3T);
    scan_kernel<<<1, 1024, 0, stream>>>(counts, offsets);
    scatter_kernel<<<NEDGES / 256, 256, 0, stream>>>(eidx, offsets, rank, perm);

    hipMemsetAsync(A, 0, (size_t)NNODES * CC * 9 * sizeof(float), stream);  // after rank use

    edge_kernel<<<NCHUNK, EBLK, 0, stream>>>(pos, shifts, eidx, perm,
                                             W1T, W2T, W3T, rb2, species, Wemb, A);
    node_kernel<<<NNODES / 8, 256, 0, stream>>>(A, Wmix, wquad, Wread, attrs, ae, batch, out);
}

// Round 11
// 309.489 us; speedup vs baseline: 47.7923x; 1.0375x over previous
//
#include <hip/hip_runtime.h>
#include <hip/hip_bf16.h>

#define NNODES 50000
#define NEDGES 800000
#define NGRAPHS 32
#define NSPEC 10
#define CC 32
#define RH 64
#define NB 8

#define EBLK 128
#define NCHUNK (NEDGES / EBLK)
#define GSTR 136   // Gt row stride (shorts); 272B rows -> 16B-aligned uint4 reads
#define YSTRF 132  // Yt row stride (floats)
#define ASTR 72    // act row stride in shorts (144B)
#define RBSTR 40   // rbA row stride in shorts (80B)
#define SCAN_N 53248

typedef __bf16 bf16x8 __attribute__((ext_vector_type(8)));
typedef float f32x4 __attribute__((ext_vector_type(4)));

__device__ __forceinline__ unsigned pack2bf(float a, float b) {
    return (unsigned)__bfloat16_as_ushort(__float2bfloat16(a)) |
           ((unsigned)__bfloat16_as_ushort(__float2bfloat16(b)) << 16);
}
__device__ __forceinline__ float silu(float x) { return x / (1.f + __expf(-x)); }

// ---------------- fused prelude: histogram(+rank) + species + weight transpose ----------------
__global__ __launch_bounds__(256) void prep_hist_kernel(
    const float* __restrict__ attrs, const int* __restrict__ eidx,
    const float* __restrict__ rW1, const float* __restrict__ rb1,
    const float* __restrict__ rW2, const float* __restrict__ rW3,
    int* __restrict__ counts, int* __restrict__ rank, int* __restrict__ species,
    __hip_bfloat16* __restrict__ W1T, __hip_bfloat16* __restrict__ W2T,
    __hip_bfloat16* __restrict__ W3T) {
    __shared__ float at[256 * NSPEC];
    const int tid = threadIdx.x;
    int g = blockIdx.x * 256 + tid;
    if (g < NEDGES) rank[g] = atomicAdd(&counts[eidx[NEDGES + g]], 1);
    const int nbase = blockIdx.x * 256;
    if (nbase < NNODES) {  // uniform per block
        for (int i = tid; i < 256 * NSPEC; i += 256) {
            int idx = nbase * NSPEC + i;
            at[i] = (idx < NNODES * NSPEC) ? attrs[idx] : 0.f;
        }
        __syncthreads();
        if (g < NNODES) {
            float acc = 0.f;
#pragma unroll
            for (int s = 0; s < NSPEC; ++s) acc += at[tid * NSPEC + s] * (float)s;
            species[g] = (int)(acc + 0.5f);
        }
    }
    if (g < 64 * 32) {  // W1T[col][k]: k<8 = rW1[k][col], k==8 = rb1[col], else 0
        int c = g >> 5, k = g & 31;
        float v = (k < 8) ? rW1[k * 64 + c] : ((k == 8) ? rb1[c] : 0.f);
        W1T[g] = __float2bfloat16(v);
    }
    if (g < 64 * 64) {
        int c = g >> 6, k = g & 63;
        W2T[g] = __float2bfloat16(rW2[k * 64 + c]);
    }
    if (g < 96 * 64) {
        int c = g >> 6, k = g & 63;
        W3T[g] = __float2bfloat16(rW3[k * 96 + c]);
    }
}

// ---------------- scan: single block, int4, CH=52 ----------------
__global__ __launch_bounds__(1024) void scan_kernel(const int* __restrict__ counts,
                                                    int* __restrict__ offsets) {
    __shared__ int sums[1024];
    const int t = threadIdx.x;
    const int base = t * 52;
    int loc[52];
    int s = 0;
#pragma unroll
    for (int i = 0; i < 13; ++i) {
        int4 v = *(const int4*)&counts[base + i * 4];
        loc[i * 4 + 0] = v.x; loc[i * 4 + 1] = v.y;
        loc[i * 4 + 2] = v.z; loc[i * 4 + 3] = v.w;
        s += v.x + v.y + v.z + v.w;
    }
    sums[t] = s;
    __syncthreads();
    for (int off = 1; off < 1024; off <<= 1) {
        int add = (t >= off) ? sums[t - off] : 0;
        __syncthreads();
        sums[t] += add;
        __syncthreads();
    }
    int run = sums[t] - s;
#pragma unroll
    for (int i = 0; i < 13; ++i) {
        int4 o;
        o.x = run; run += loc[i * 4 + 0];
        o.y = run; run += loc[i * 4 + 1];
        o.z = run; run += loc[i * 4 + 2];
        o.w = run; run += loc[i * 4 + 3];
        *(int4*)&offsets[base + i * 4] = o;
    }
}

// ---------------- scatter: atomic-free (precomputed rank) ----------------
__global__ __launch_bounds__(256) void scatter_kernel(const int* __restrict__ eidx,
                                                      const int* __restrict__ offsets,
                                                      const int* __restrict__ rank,
                                                      int* __restrict__ perm) {
    int e = blockIdx.x * 256 + threadIdx.x;
    if (e >= NEDGES) return;
    int rcv = eidx[NEDGES + e];
    perm[offsets[rcv] + rank[e]] = e;
}

// ---------------- zero only chunk-boundary A rows (replaces 57.6MB memset) ----------------
__global__ __launch_bounds__(576) void zero_bounds_kernel(const int* __restrict__ perm,
                                                          const int* __restrict__ eidx,
                                                          float* __restrict__ A) {
    const int c = blockIdx.x;
    const int t = threadIdx.x;
    const int slot = (t < 288) ? c * EBLK : (c * EBLK + EBLK - 1);
    const int e = perm[slot];
    const int rcv = eidx[NEDGES + e];
    A[(size_t)rcv * (CC * 9) + (t % 288)] = 0.f;
}

// ---------------- segment flush helper ----------------
__device__ __forceinline__ void flushseg(float* __restrict__ A, int node, int cur,
                                         int nseg, int cbase, int j, bool wr8,
                                         float aj, float a8) {
    float* Ap = A + (size_t)node * (CC * 9) + cbase * 9;
    if (cur == 0 || cur == nseg - 1) {
        atomicAdd(Ap + j, aj);
        if (wr8) atomicAdd(Ap + 8, a8);
    } else {
        Ap[j] = aj;
        if (wr8) Ap[8] = a8;
    }
}

// ---------------- phase-2 + Gt-store (templated on column half P) ----------------
template <int P>
__device__ __forceinline__ void pass_store_reduce(
    const f32x4 (&acc3)[4][6], const int (&sp_r)[4][4],
    __hip_bfloat16* Gt, const float* Yt, const float* WembLds,
    const unsigned short* rcv_s, const unsigned long long* bal_s,
    float* __restrict__ A, int tid, int w, int lnlo, int q4) {
    // ---- store Gt[s][e] = R * h_sender, packed 4-wide along e (rr=0..3)
#pragma unroll
    for (int nti = 0; nti < 3; ++nti) {
        const int nt = P * 3 + nti;
        const int col = nt * 16 + lnlo;
        const int cch = col / 3;           // channel 0..31
        const int s = nti * 16 + lnlo;     // 0..47 within half
#pragma unroll
        for (int mt = 0; mt < 4; ++mt) {
            const float f0 = acc3[mt][nt][0] * WembLds[sp_r[mt][0] * 32 + cch];
            const float f1 = acc3[mt][nt][1] * WembLds[sp_r[mt][1] * 32 + cch];
            const float f2 = acc3[mt][nt][2] * WembLds[sp_r[mt][2] * 32 + cch];
            const float f3 = acc3[mt][nt][3] * WembLds[sp_r[mt][3] * 32 + cch];
            uint2 pk;
            pk.x = pack2bf(f0, f1);
            pk.y = pack2bf(f2, f3);
            *(uint2*)&Gt[s * GSTR + w * 64 + mt * 16 + q4 * 4] = pk;
        }
    }
    __syncthreads();

    // ---- segmented reduce, 8-wide; thread = (c, j); j==7 also handles m=8 (same G row as m=7)
    {
        const int c = tid >> 3;
        const int j = tid & 7;
        const bool m8 = (j == 7);
        const int l_j = (j == 0) ? 0 : ((j < 4) ? 1 : 2);
        const uint4* gj = (const uint4*)(Gt + (3 * c + l_j) * GSTR);
        const float4* yj = (const float4*)(Yt + j * YSTRF);
        const float4* y8f = (const float4*)(Yt + 8 * YSTRF);
        const unsigned long long b0 = bal_s[0], b1 = bal_s[1];
        const int nseg = __popcll(b0) + __popcll(b1);
        const int cbase = P * 16 + c;

        float aj = 0.f, a8 = 0.f;
        int cur = 0;
        int node = rcv_s[0];

        for (int ch = 0; ch < 16; ++ch) {
            unsigned msk = (unsigned)(((ch < 8) ? (b0 >> (ch * 8)) : (b1 >> ((ch - 8) * 8))) & 0xffull);
            if (ch == 0) msk &= ~1u;
            const uint4 gv = gj[ch];
            const float4 ya = yj[2 * ch];
            const float4 yb = yj[2 * ch + 1];
            float4 y8a = {0.f, 0.f, 0.f, 0.f}, y8b = {0.f, 0.f, 0.f, 0.f};
            if (m8) { y8a = y8f[2 * ch]; y8b = y8f[2 * ch + 1]; }
            const unsigned gw[4] = {gv.x, gv.y, gv.z, gv.w};
            const float yf[8] = {ya.x, ya.y, ya.z, ya.w, yb.x, yb.y, yb.z, yb.w};
            const float yf8[8] = {y8a.x, y8a.y, y8a.z, y8a.w, y8b.x, y8b.y, y8b.z, y8b.w};
#pragma unroll
            for (int i = 0; i < 8; ++i) {
                if (msk & (1u << i)) {
                    flushseg(A, node, cur, nseg, cbase, j, m8, aj, a8);
                    aj = 0.f; a8 = 0.f; ++cur;
                    node = rcv_s[ch * 8 + i];
                }
                const unsigned gu = gw[i >> 1];
                const float gf = __uint_as_float((i & 1) ? (gu & 0xffff0000u) : (gu << 16));
                aj = fmaf(gf, yf[i], aj);
                if (m8) a8 = fmaf(gf, yf8[i], a8);  // m=8 reuses G row 3c+2
            }
        }
        flushseg(A, node, cur, nseg, cbase, j, m8, aj, a8);
    }
    __syncthreads();  // protect Gt before next pass overwrites
}

// ---------------- edge kernel: full-MFMA MLP + segmented scatter ----------------
__global__ __launch_bounds__(EBLK, 3) void edge_kernel(
    const float* __restrict__ pos, const float* __restrict__ shifts,
    const int* __restrict__ eidx, const int* __restrict__ perm,
    const __hip_bfloat16* __restrict__ W1T, const __hip_bfloat16* __restrict__ W2T,
    const __hip_bfloat16* __restrict__ W3T, const float* __restrict__ rb2,
    const int* __restrict__ species, const float* __restrict__ Wemb,
    float* __restrict__ A) {
    // union: act (128x72 shorts) overlays Gt (48x136) and rbA (128x40)
    __shared__ __align__(16) short smem_u[128 * ASTR];
    __shared__ __align__(16) float Yt[9 * YSTRF];
    __shared__ float WembLds[NSPEC * CC];
    __shared__ float rb2L[RH];
    __shared__ unsigned short rcv_s[EBLK];
    __shared__ unsigned char spec_s[EBLK];
    __shared__ unsigned long long bal_s[2];

    __hip_bfloat16* act = (__hip_bfloat16*)smem_u;
    __hip_bfloat16* Gt = (__hip_bfloat16*)smem_u;
    __hip_bfloat16* rbA = (__hip_bfloat16*)smem_u;

    const int tid = threadIdx.x;
    const int lane = tid & 63;
    const int w = tid >> 6;
    const int lnlo = lane & 15;
    const int q4 = lane >> 4;

    const int slot = blockIdx.x * EBLK + tid;
    const int eid = perm[slot];
    const int snd = eidx[eid];
    const int rcv = eidx[NEDGES + eid];

    const float vx = pos[rcv * 3 + 0] - pos[snd * 3 + 0] + shifts[eid * 3 + 0];
    const float vy = pos[rcv * 3 + 1] - pos[snd * 3 + 1] + shifts[eid * 3 + 1];
    const float vz = pos[rcv * 3 + 2] - pos[snd * 3 + 2] + shifts[eid * 3 + 2];
    const float r = sqrtf(vx * vx + vy * vy + vz * vz);
    const float safe_r = fmaxf(r, 1e-9f);
    const float rinv = 1.f / safe_r;
    const float ux = vx * rinv, uy = vy * rinv, uz = vz * rinv;

    // ---- spherical harmonics (f32) + metadata -> LDS
    {
        const float s3 = 1.7320508075688772f;
        const float s15 = 3.872983346207417f;
        const float s15h = 1.9364916731037085f;
        const float s5h = 1.118033988749895f;
        Yt[0 * YSTRF + tid] = 1.f;
        Yt[1 * YSTRF + tid] = s3 * ux;
        Yt[2 * YSTRF + tid] = s3 * uy;
        Yt[3 * YSTRF + tid] = s3 * uz;
        Yt[4 * YSTRF + tid] = s15 * ux * uy;
        Yt[5 * YSTRF + tid] = s15 * uy * uz;
        Yt[6 * YSTRF + tid] = s5h * (3.f * uz * uz - 1.f);
        Yt[7 * YSTRF + tid] = s15 * ux * uz;
        Yt[8 * YSTRF + tid] = s15h * (ux * ux - uy * uy);
        rcv_s[tid] = (unsigned short)rcv;
        spec_s[tid] = (unsigned char)species[snd];
        for (int i = tid; i < NSPEC * CC; i += EBLK) WembLds[i] = Wemb[i];
        if (tid < RH) rb2L[tid] = rb2[tid];
    }

    // ---- radial basis -> rbA row
    {
        const float u = r * 0.2f;
        const float u2 = u * u;
        const float u6 = u2 * u2 * u2;
        const float u7 = u6 * u;
        const float u8v = u7 * u;
        float fcut = 1.f - 28.f * u6 + 48.f * u7 - 21.f * u8v;
        fcut = (u < 1.f) ? fcut : 0.f;
        const float pref = 0.632455532f * rinv * fcut;
        float rb[NB];
#pragma unroll
        for (int k = 0; k < NB; ++k) {
            const float fk = (float)(k + 1) * 0.628318530718f;
            rb[k] = __sinf(fk * safe_r) * pref;
        }
        uint4 v0, v1;
        v0.x = pack2bf(rb[0], rb[1]); v0.y = pack2bf(rb[2], rb[3]);
        v0.z = pack2bf(rb[4], rb[5]); v0.w = pack2bf(rb[6], rb[7]);
        v1.x = 0x3F80u; v1.y = 0u; v1.z = 0u; v1.w = 0u;  // k=8 -> 1.0 (bias row)
        uint4 vz4 = {0u, 0u, 0u, 0u};
        *(uint4*)&rbA[tid * RBSTR + 0] = v0;
        *(uint4*)&rbA[tid * RBSTR + 8] = v1;
        *(uint4*)&rbA[tid * RBSTR + 16] = vz4;
        *(uint4*)&rbA[tid * RBSTR + 24] = vz4;
    }

    __syncthreads();  // rcv_s visible cross-wave
    {
        const bool head = (tid == 0) || (rcv_s[tid] != rcv_s[tid - 1]);
        const unsigned long long bal = __ballot(head);
        if ((tid & 63) == 0) bal_s[tid >> 6] = bal;
    }

    // ---- layer 1 (SWAPPED: A=weights, B=act): acc1[jt][et], C = [ch][edge]
    f32x4 acc1[4][4];
#pragma unroll
    for (int jt = 0; jt < 4; ++jt)
#pragma unroll
        for (int et = 0; et < 4; ++et) acc1[jt][et] = (f32x4){0.f, 0.f, 0.f, 0.f};
    {
        bf16x8 wf[4], af[4];
#pragma unroll
        for (int jt = 0; jt < 4; ++jt)
            wf[jt] = *(const bf16x8*)&W1T[(jt * 16 + lnlo) * 32 + q4 * 8];
#pragma unroll
        for (int et = 0; et < 4; ++et)
            af[et] = *(const bf16x8*)&rbA[(w * 64 + et * 16 + lnlo) * RBSTR + q4 * 8];
        __syncthreads();  // rbA consumed before act overwrite
#pragma unroll
        for (int jt = 0; jt < 4; ++jt)
#pragma unroll
            for (int et = 0; et < 4; ++et)
                acc1[jt][et] = __builtin_amdgcn_mfma_f32_16x16x32_bf16(
                    wf[jt], af[et], acc1[jt][et], 0, 0, 0);
    }

    // ---- silu(acc1) -> act[e][ch], packed b64 (4 contiguous channels per lane)
#pragma unroll
    for (int jt = 0; jt < 4; ++jt) {
        const int ch0 = jt * 16 + q4 * 4;
#pragma unroll
        for (int et = 0; et < 4; ++et) {
            const int e = w * 64 + et * 16 + lnlo;
            uint2 pk;
            pk.x = pack2bf(silu(acc1[jt][et][0]), silu(acc1[jt][et][1]));
            pk.y = pack2bf(silu(acc1[jt][et][2]), silu(acc1[jt][et][3]));
            *(uint2*)&act[e * ASTR + ch0] = pk;
        }
    }
    __syncthreads();

    // ---- layer 2 (SWAPPED): acc2[jt][et]
    f32x4 acc2[4][4];
#pragma unroll
    for (int jt = 0; jt < 4; ++jt)
#pragma unroll
        for (int et = 0; et < 4; ++et) acc2[jt][et] = (f32x4){0.f, 0.f, 0.f, 0.f};
    {
        bf16x8 wf[4][2], af[4][2];
#pragma unroll
        for (int jt = 0; jt < 4; ++jt)
#pragma unroll
            for (int kk = 0; kk < 2; ++kk)
                wf[jt][kk] = *(const bf16x8*)&W2T[(jt * 16 + lnlo) * 64 + kk * 32 + q4 * 8];
#pragma unroll
        for (int et = 0; et < 4; ++et)
#pragma unroll
            for (int kk = 0; kk < 2; ++kk)
                af[et][kk] = *(const bf16x8*)&act[(w * 64 + et * 16 + lnlo) * ASTR + kk * 32 + q4 * 8];
#pragma unroll
        for (int kk = 0; kk < 2; ++kk)
#pragma unroll
            for (int jt = 0; jt < 4; ++jt)
#pragma unroll
                for (int et = 0; et < 4; ++et)
                    acc2[jt][et] = __builtin_amdgcn_mfma_f32_16x16x32_bf16(
                        wf[jt][kk], af[et][kk], acc2[jt][et], 0, 0, 0);
    }
    __syncthreads();  // all act1 reads complete

    // ---- silu(acc2 + rb2) -> act2, packed b64
#pragma unroll
    for (int jt = 0; jt < 4; ++jt) {
        const int ch0 = jt * 16 + q4 * 4;
        const float4 bv = *(const float4*)&rb2L[ch0];
#pragma unroll
        for (int et = 0; et < 4; ++et) {
            const int e = w * 64 + et * 16 + lnlo;
            uint2 pk;
            pk.x = pack2bf(silu(acc2[jt][et][0] + bv.x), silu(acc2[jt][et][1] + bv.y));
            pk.y = pack2bf(silu(acc2[jt][et][2] + bv.z), silu(acc2[jt][et][3] + bv.w));
            *(uint2*)&act[e * ASTR + ch0] = pk;
        }
    }
    __syncthreads();

    // ---- layer 3 (UNSWAPPED: A=act, B=W3T): acc3[mt][nt], C = [edge][ch]
    f32x4 acc3[4][6];
#pragma unroll
    for (int mt = 0; mt < 4; ++mt)
#pragma unroll
        for (int nt = 0; nt < 6; ++nt) acc3[mt][nt] = (f32x4){0.f, 0.f, 0.f, 0.f};
    {
        bf16x8 a3[4][2], b3[6][2];
#pragma unroll
        for (int mt = 0; mt < 4; ++mt)
#pragma unroll
            for (int kk = 0; kk < 2; ++kk)
                a3[mt][kk] = *(const bf16x8*)&act[(w * 64 + mt * 16 + lnlo) * ASTR + kk * 32 + q4 * 8];
#pragma unroll
        for (int nt = 0; nt < 6; ++nt)
#pragma unroll
            for (int kk = 0; kk < 2; ++kk)
                b3[nt][kk] = *(const bf16x8*)&W3T[(nt * 16 + lnlo) * 64 + kk * 32 + q4 * 8];
#pragma unroll
        for (int kk = 0; kk < 2; ++kk)
#pragma unroll
            for (int mt = 0; mt < 4; ++mt)
#pragma unroll
                for (int nt = 0; nt < 6; ++nt)
                    acc3[mt][nt] = __builtin_amdgcn_mfma_f32_16x16x32_bf16(
                        a3[mt][kk], b3[nt][kk], acc3[mt][nt], 0, 0, 0);
    }
    __syncthreads();  // act dead (Gt overlays it)

    // ---- preload sender species for the 16 rows this lane owns
    int sp_r[4][4];
#pragma unroll
    for (int mt = 0; mt < 4; ++mt)
#pragma unroll
        for (int rr = 0; rr < 4; ++rr)
            sp_r[mt][rr] = (int)spec_s[w * 64 + mt * 16 + q4 * 4 + rr];

    // ---- two column-halves: Gt store + segmented reduce
    pass_store_reduce<0>(acc3, sp_r, Gt, Yt, WembLds, rcv_s, bal_s, A, tid, w, lnlo, q4);
    pass_store_reduce<1>(acc3, sp_r, Gt, Yt, WembLds, rcv_s, bal_s, A, tid, w, lnlo, q4);
}

// ---------------- node kernel: A -> A2 -> B -> node_e, fused per-graph reduce ----------------
__global__ __launch_bounds__(256) void node_kernel(
    const float* __restrict__ A, const float* __restrict__ Wmix,
    const float* __restrict__ wquad, const float* __restrict__ Wread,
    const float* __restrict__ attrs, const float* __restrict__ ae,
    const int* __restrict__ batch, const int* __restrict__ counts,
    float* __restrict__ out) {
    __shared__ float Ald[8][CC * 9];
    __shared__ float ne_s[8];
    __shared__ int g_s[8];
    const int t = threadIdx.x;
    const int ln = t >> 5;
    const int d = t & 31;
    const int n = blockIdx.x * 8 + ln;

    const float sc = (counts[n] != 0) ? (1.f / 16.f) : 0.f;  // zero-edge rows: unwritten garbage
    const float* Arow = A + (size_t)n * (CC * 9);
#pragma unroll
    for (int i = 0; i < 9; ++i) Ald[ln][d + 32 * i] = Arow[d + 32 * i] * sc;
    __syncthreads();

    float A2[9];
#pragma unroll
    for (int m = 0; m < 9; ++m) {
        const int l = (m == 0) ? 0 : ((m < 4) ? 1 : 2);
        float acc = 0.f;
#pragma unroll
        for (int cch = 0; cch < CC; ++cch)
            acc = fmaf(Wmix[(l * CC + cch) * CC + d], Ald[ln][cch * 9 + m], acc);
        A2[m] = acc;
    }

    const float q0 = wquad[0], q1 = wquad[1], q2 = wquad[2];
    const float n0 = A2[0] * A2[0];
    const float n1 = A2[1] * A2[1] + A2[2] * A2[2] + A2[3] * A2[3];
    const float n2 = A2[4] * A2[4] + A2[5] * A2[5] + A2[6] * A2[6] + A2[7] * A2[7] + A2[8] * A2[8];
    const float B = A2[0] + n0 * q0 + n1 * q1 + n2 * q2;

    float v = B * Wread[d];
#pragma unroll
    for (int off = 16; off; off >>= 1) v += __shfl_xor(v, off, 32);

    if (d == 0) {
        float ne = v;
#pragma unroll
        for (int s = 0; s < NSPEC; ++s) ne += attrs[n * NSPEC + s] * ae[s];
        ne_s[ln] = ne;
        g_s[ln] = batch[n];
    }
    __syncthreads();
    if (t == 0) {  // batch sorted; merge runs, 1-2 atomics/block
        float acc = ne_s[0];
        int g = g_s[0];
#pragma unroll
        for (int i = 1; i < 8; ++i) {
            if (g_s[i] == g) acc += ne_s[i];
            else { atomicAdd(&out[g], acc); g = g_s[i]; acc = ne_s[i]; }
        }
        atomicAdd(&out[g], acc);
    }
}

extern "C" void kernel_launch(void* const* d_in, const int* in_sizes, int n_in,
                              void* d_out, int out_size, void* d_ws, size_t ws_size,
                              hipStream_t stream) {
    const float* attrs  = (const float*)d_in[0];
    const float* pos    = (const float*)d_in[1];
    const float* shifts = (const float*)d_in[2];
    const float* Wemb   = (const float*)d_in[3];
    const float* rW1    = (const float*)d_in[4];
    const float* rb1    = (const float*)d_in[5];
    const float* rW2    = (const float*)d_in[6];
    const float* rb2    = (const float*)d_in[7];
    const float* rW3    = (const float*)d_in[8];
    const float* Wmix   = (const float*)d_in[9];
    const float* wquad  = (const float*)d_in[10];
    const float* Wread  = (const float*)d_in[11];
    const float* ae     = (const float*)d_in[12];
    const int* eidx     = (const int*)d_in[13];
    const int* batch    = (const int*)d_in[14];
    float* out = (float*)d_out;

    // workspace layout; ~61.5 MB. rank aliases A (dead after scatter; only boundary rows re-zeroed).
    char* wsp = (char*)d_ws;
    float* A      = (float*)wsp;  wsp += (size_t)NNODES * CC * 9 * 4;  // 57.6 MB
    int* rank     = (int*)A;
    int* perm     = (int*)wsp;    wsp += (size_t)NEDGES * 4;           // 3.2 MB
    int* offsets  = (int*)wsp;    wsp += (size_t)SCAN_N * 4;
    int* counts   = (int*)wsp;    wsp += (size_t)SCAN_N * 4;
    int* species  = (int*)wsp;    wsp += (size_t)NNODES * 4;
    __hip_bfloat16* W1T = (__hip_bfloat16*)wsp; wsp += 64 * 32 * 2;
    __hip_bfloat16* W2T = (__hip_bfloat16*)wsp; wsp += 64 * 64 * 2;
    __hip_bfloat16* W3T = (__hip_bfloat16*)wsp; wsp += 96 * 64 * 2;

    hipMemsetAsync(counts, 0, (size_t)SCAN_N * sizeof(int), stream);
    hipMemsetAsync(out, 0, NGRAPHS * sizeof(float), stream);

    prep_hist_kernel<<<NEDGES / 256, 256, 0, stream>>>(attrs, eidx, rW1, rb1, rW2, rW3,
                                                       counts, rank, species, W1T, W2T, W3T);
    scan_kernel<<<1, 1024, 0, stream>>>(counts, offsets);
    scatter_kernel<<<NEDGES / 256, 256, 0, stream>>>(eidx, offsets, rank, perm);
    zero_bounds_kernel<<<NCHUNK, 576, 0, stream>>>(perm, eidx, A);

    edge_kernel<<<NCHUNK, EBLK, 0, stream>>>(pos, shifts, eidx, perm,
                                             W1T, W2T, W3T, rb2, species, Wemb, A);
    node_kernel<<<NNODES / 8, 256, 0, stream>>>(A, Wmix, wquad, Wread, attrs, ae, batch,
                                                counts, out);
}